// Round 3
// baseline (2375.238 us; speedup 1.0000x reference)
//
#include <hip/hip_runtime.h>

#define H 64
#define CIN 32
#define TWOH 128
#define NGRAPH 64

typedef unsigned short bfraw;

__device__ __forceinline__ float bf2f(bfraw u) {
    return __uint_as_float(((unsigned)u) << 16);
}
__device__ __forceinline__ bfraw f2bf(float f) {
    unsigned u = __float_as_uint(f);
    unsigned r = (u + 0x7fffu + ((u >> 16) & 1u)) >> 16;  // RNE
    return (bfraw)r;
}

// ---------------- input GEMM: x0[N,64] = x[N,32] @ Win + bin ----------------
extern "C" __global__ void __launch_bounds__(256) k_input_gemm(
    const float* __restrict__ x, const float* __restrict__ Win,
    const float* __restrict__ bin, float* __restrict__ x0,
    bfraw* __restrict__ xb, int N)
{
    __shared__ float Wl[CIN * H]; // 8 KB
    for (int i = threadIdx.x; i < CIN * H; i += blockDim.x) Wl[i] = Win[i];
    __syncthreads();
    const int lane = threadIdx.x & 63;
    const int wpb = blockDim.x >> 6;
    int w = blockIdx.x * wpb + (threadIdx.x >> 6);
    const int wstride = gridDim.x * wpb;
    const float bv = bin[lane];
    for (int n = w; n < N; n += wstride) {
        float in = (lane < CIN) ? x[n * CIN + lane] : 0.f;
        float acc = bv;
        #pragma unroll
        for (int k = 0; k < CIN; ++k)
            acc += __shfl(in, k) * Wl[k * H + lane];
        x0[(size_t)n * H + lane] = acc;
        xb[(size_t)n * H + lane] = f2bf(acc);
    }
}

// ---------------- CSR build ----------------
extern "C" __global__ void k_hist(const int* __restrict__ dst,
    unsigned* __restrict__ deg, int E)
{
    int i = blockIdx.x * blockDim.x + threadIdx.x;
    const int st = gridDim.x * blockDim.x;
    const int E4 = E >> 2;
    const int4* d4 = (const int4*)dst;
    for (int j = i; j < E4; j += st) {
        const int4 v = d4[j];
        atomicAdd(&deg[v.x], 1u);
        atomicAdd(&deg[v.y], 1u);
        atomicAdd(&deg[v.z], 1u);
        atomicAdd(&deg[v.w], 1u);
    }
    for (int j = (E4 << 2) + i; j < E; j += st) atomicAdd(&deg[dst[j]], 1u);
}

extern "C" __global__ void k_scan1(const unsigned* __restrict__ deg,
    unsigned* __restrict__ indptr, unsigned* __restrict__ bsum, int N)
{
    __shared__ unsigned s[256];
    const int tid = threadIdx.x;
    const int base = blockIdx.x * 1024 + tid * 4;
    unsigned d[4];
    #pragma unroll
    for (int j = 0; j < 4; ++j) d[j] = (base + j < N) ? deg[base + j] : 0u;
    unsigned t = d[0] + d[1] + d[2] + d[3];
    s[tid] = t;
    __syncthreads();
    for (int o = 1; o < 256; o <<= 1) {
        unsigned v = (tid >= o) ? s[tid - o] : 0u;
        __syncthreads();
        s[tid] += v;
        __syncthreads();
    }
    unsigned run = (tid == 0) ? 0u : s[tid - 1];
    if (tid == 255) bsum[blockIdx.x] = s[255];
    #pragma unroll
    for (int j = 0; j < 4; ++j) {
        if (base + j < N) indptr[base + j] = run;
        run += d[j];
    }
}

extern "C" __global__ void k_scan2(unsigned* bsum, int nb)
{
    if (threadIdx.x == 0) {
        unsigned run = 0;
        for (int i = 0; i < nb; ++i) { unsigned v = bsum[i]; bsum[i] = run; run += v; }
    }
}

extern "C" __global__ void k_scan3(unsigned* __restrict__ indptr,
    const unsigned* __restrict__ bsum, unsigned* __restrict__ cursor, int N)
{
    const int base = blockIdx.x * 1024 + threadIdx.x * 4;
    const unsigned boff = bsum[blockIdx.x];
    #pragma unroll
    for (int j = 0; j < 4; ++j) {
        const int idx = base + j;
        if (idx < N) {
            const unsigned v = indptr[idx] + boff;
            indptr[idx] = v;
            cursor[idx] = v;
        }
    }
}

extern "C" __global__ void k_csr(const int* __restrict__ src,
    const int* __restrict__ dst, unsigned* __restrict__ cursor,
    int* __restrict__ esrc, int E)
{
    int i = blockIdx.x * blockDim.x + threadIdx.x;
    const int st = gridDim.x * blockDim.x;
    const int E4 = E >> 2;
    const int4* s4 = (const int4*)src;
    const int4* d4 = (const int4*)dst;
    for (int j = i; j < E4; j += st) {
        const int4 sv = s4[j];
        const int4 dv = d4[j];
        esrc[atomicAdd(&cursor[dv.x], 1u)] = sv.x;
        esrc[atomicAdd(&cursor[dv.y], 1u)] = sv.y;
        esrc[atomicAdd(&cursor[dv.z], 1u)] = sv.z;
        esrc[atomicAdd(&cursor[dv.w], 1u)] = sv.w;
    }
    for (int j = (E4 << 2) + i; j < E; j += st) {
        esrc[atomicAdd(&cursor[dst[j]], 1u)] = src[j];
    }
}

// ------------- fused: aggregate + (1+eps)x + GEMM1 + BN stats -------------
extern "C" __global__ void __launch_bounds__(256, 4) k_agg_gemm1(
    const float* __restrict__ x0, const bfraw* __restrict__ xb,
    const int* __restrict__ esrc,
    const unsigned* __restrict__ indptr, const unsigned* __restrict__ deg,
    const float* __restrict__ W1, const float* __restrict__ b1,
    const float* __restrict__ epsp, float* __restrict__ h1,
    double* __restrict__ gsum, double* __restrict__ gsq, int N)
{
    __shared__ float Wl[H * TWOH];        // 32 KB
    __shared__ float ss[TWOH], sq[TWOH];  // 1 KB
    for (int i = threadIdx.x; i < H * TWOH; i += blockDim.x) Wl[i] = W1[i];
    if (threadIdx.x < TWOH) { ss[threadIdx.x] = 0.f; sq[threadIdx.x] = 0.f; }
    __syncthreads();
    const int lane = threadIdx.x & 63;
    const int wpb = blockDim.x >> 6;
    int w = blockIdx.x * wpb + (threadIdx.x >> 6);
    const int wstride = gridDim.x * wpb;
    const float ep = 1.f + epsp[0];
    const float b0 = b1[lane], bb = b1[H + lane];
    float s0 = 0.f, s1 = 0.f, q0 = 0.f, q1 = 0.f;
    for (int n = w; n < N; n += wstride) {
        const unsigned st0 = indptr[n];
        const unsigned cnt = deg[n];
        float acc = 0.f;
        unsigned e = 0;
        for (; e + 8 <= cnt; e += 8) {
            const int i0 = esrc[st0 + e];
            const int i1 = esrc[st0 + e + 1];
            const int i2 = esrc[st0 + e + 2];
            const int i3 = esrc[st0 + e + 3];
            const int i4 = esrc[st0 + e + 4];
            const int i5 = esrc[st0 + e + 5];
            const int i6 = esrc[st0 + e + 6];
            const int i7 = esrc[st0 + e + 7];
            const float v0 = bf2f(xb[(size_t)i0 * H + lane]);
            const float v1 = bf2f(xb[(size_t)i1 * H + lane]);
            const float v2 = bf2f(xb[(size_t)i2 * H + lane]);
            const float v3 = bf2f(xb[(size_t)i3 * H + lane]);
            const float v4 = bf2f(xb[(size_t)i4 * H + lane]);
            const float v5 = bf2f(xb[(size_t)i5 * H + lane]);
            const float v6 = bf2f(xb[(size_t)i6 * H + lane]);
            const float v7 = bf2f(xb[(size_t)i7 * H + lane]);
            acc += fmaxf(v0, 0.f) + fmaxf(v1, 0.f) + fmaxf(v2, 0.f) + fmaxf(v3, 0.f)
                 + fmaxf(v4, 0.f) + fmaxf(v5, 0.f) + fmaxf(v6, 0.f) + fmaxf(v7, 0.f);
        }
        for (; e < cnt; ++e) {
            const float v = bf2f(xb[(size_t)esrc[st0 + e] * H + lane]);
            acc += fmaxf(v, 0.f);
        }
        const float h = ep * x0[(size_t)n * H + lane] + acc;
        float c0 = b0, c1 = bb;
        #pragma unroll
        for (int k = 0; k < H; ++k) {
            const float a = __shfl(h, k);
            c0 += a * Wl[k * TWOH + lane];
            c1 += a * Wl[k * TWOH + H + lane];
        }
        h1[(size_t)n * TWOH + lane] = c0;
        h1[(size_t)n * TWOH + H + lane] = c1;
        s0 += c0; s1 += c1; q0 += c0 * c0; q1 += c1 * c1;
    }
    atomicAdd(&ss[lane], s0); atomicAdd(&ss[H + lane], s1);
    atomicAdd(&sq[lane], q0); atomicAdd(&sq[H + lane], q1);
    __syncthreads();
    if (threadIdx.x < TWOH) {
        atomicAdd(&gsum[threadIdx.x], (double)ss[threadIdx.x]);
        atomicAdd(&gsq[threadIdx.x], (double)sq[threadIdx.x]);
    }
}

// ---------------- BN finalize: scale/shift ----------------
extern "C" __global__ void k_bnfin(const double* __restrict__ gsum,
    const double* __restrict__ gsq, const float* __restrict__ gamma,
    const float* __restrict__ beta, float* __restrict__ scsh, int N)
{
    const int j = threadIdx.x;
    if (j < TWOH) {
        const double mu = gsum[j] / N;
        const double var = gsq[j] / N - mu * mu;
        const float sc = gamma[j] * rsqrtf(fmaxf((float)var, 0.f) + 1e-5f);
        scsh[j] = sc;
        scsh[TWOH + j] = beta[j] - (float)mu * sc;
    }
}

// ------------- fused: BN apply + ReLU + GEMM2 + residual -------------
extern "C" __global__ void __launch_bounds__(256) k_gemm2(
    const float* __restrict__ h1, const float* __restrict__ scsh,
    const float* __restrict__ W2, const float* __restrict__ b2,
    float* __restrict__ x0, bfraw* __restrict__ xb, int N)
{
    __shared__ float Wl[TWOH * H];  // 32 KB
    __shared__ float sc[2 * TWOH];
    for (int i = threadIdx.x; i < TWOH * H; i += blockDim.x) Wl[i] = W2[i];
    for (int i = threadIdx.x; i < 2 * TWOH; i += blockDim.x) sc[i] = scsh[i];
    __syncthreads();
    const int lane = threadIdx.x & 63;
    const int wpb = blockDim.x >> 6;
    int w = blockIdx.x * wpb + (threadIdx.x >> 6);
    const int wstride = gridDim.x * wpb;
    const float bv = b2[lane];
    const float sc0 = sc[lane], sh0 = sc[TWOH + lane];
    const float sc1 = sc[H + lane], sh1 = sc[TWOH + H + lane];
    for (int n = w; n < N; n += wstride) {
        const float y0 = fmaxf(h1[(size_t)n * TWOH + lane] * sc0 + sh0, 0.f);
        const float y1 = fmaxf(h1[(size_t)n * TWOH + H + lane] * sc1 + sh1, 0.f);
        float acc = bv;
        #pragma unroll
        for (int k = 0; k < H; ++k)
            acc += __shfl(y0, k) * Wl[k * H + lane];
        #pragma unroll
        for (int k = 0; k < H; ++k)
            acc += __shfl(y1, k) * Wl[(H + k) * H + lane];
        const float xn = x0[(size_t)n * H + lane] + acc;
        x0[(size_t)n * H + lane] = xn;
        xb[(size_t)n * H + lane] = f2bf(xn);
    }
}

// ---------------- pooling + output ----------------
extern "C" __global__ void k_initout(const float* __restrict__ bout,
    float* __restrict__ out)
{
    if (threadIdx.x < NGRAPH) out[threadIdx.x] = bout[0];
}

extern "C" __global__ void __launch_bounds__(256) k_pool(
    const float* __restrict__ x0, const int* __restrict__ batch,
    const float* __restrict__ Wout, float* __restrict__ out, int N)
{
    __shared__ float pl[NGRAPH];
    if (threadIdx.x < NGRAPH) pl[threadIdx.x] = 0.f;
    __syncthreads();
    const int lane = threadIdx.x & 63;
    const int wpb = blockDim.x >> 6;
    int w = blockIdx.x * wpb + (threadIdx.x >> 6);
    const int wstride = gridDim.x * wpb;
    const float wv = Wout[lane];
    for (int n = w; n < N; n += wstride) {
        float v = x0[(size_t)n * H + lane] * wv;
        #pragma unroll
        for (int o = 32; o > 0; o >>= 1) v += __shfl_down(v, o);
        if (lane == 0) atomicAdd(&pl[batch[n]], v);
    }
    __syncthreads();
    if (threadIdx.x < NGRAPH) {
        const float v = pl[threadIdx.x];
        if (v != 0.f) atomicAdd(&out[threadIdx.x], v);
    }
}

// ---------------- host driver ----------------
extern "C" void kernel_launch(void* const* d_in, const int* in_sizes, int n_in,
                              void* d_out, int out_size, void* d_ws, size_t ws_size,
                              hipStream_t stream)
{
    const float* x     = (const float*)d_in[0];
    const int*   ei    = (const int*)d_in[1];   // int32 per harness conversion
    const int*   batch = (const int*)d_in[2];   // int32 per harness conversion
    const float* Win   = (const float*)d_in[3];
    const float* bin   = (const float*)d_in[4];
    const float* W1s   = (const float*)d_in[5];
    const float* b1s   = (const float*)d_in[6];
    const float* gam   = (const float*)d_in[7];
    const float* bet   = (const float*)d_in[8];
    const float* W2s   = (const float*)d_in[9];
    const float* b2s   = (const float*)d_in[10];
    const float* epss  = (const float*)d_in[11];
    const float* Wout  = (const float*)d_in[12];
    const float* bout  = (const float*)d_in[13];

    const int N = in_sizes[0] / CIN;
    const int E = in_sizes[1] / 2;
    const int L = in_sizes[11];
    const int* src = ei;
    const int* dst = ei + E;

    // workspace layout
    char* ws = (char*)d_ws;
    size_t off = 0;
    auto take = [&](size_t bytes) {
        void* p = ws + off;
        off += (bytes + 255) & ~(size_t)255;
        return p;
    };
    float*    x0     = (float*)take((size_t)N * H * 4);
    bfraw*    xb     = (bfraw*)take((size_t)N * H * 2);
    float*    h1     = (float*)take((size_t)N * TWOH * 4);
    unsigned* deg    = (unsigned*)take((size_t)N * 4);
    unsigned* indptr = (unsigned*)take((size_t)N * 4);
    unsigned* cursor = (unsigned*)take((size_t)N * 4);
    int*      esrc   = (int*)take((size_t)E * 4);
    unsigned* bsum   = (unsigned*)take(4096);
    double*   gsum   = (double*)take(TWOH * 8 * 2); // gsum + gsq contiguous
    double*   gsq    = gsum + TWOH;
    float*    scsh   = (float*)take(2 * TWOH * 4);
    (void)ws_size; (void)n_in; (void)out_size;

    hipMemsetAsync(deg, 0, (size_t)N * 4, stream);
    k_input_gemm<<<1024, 256, 0, stream>>>(x, Win, bin, x0, xb, N);
    k_hist<<<2048, 256, 0, stream>>>(dst, deg, E);
    const int nb = (N + 1023) / 1024;
    k_scan1<<<nb, 256, 0, stream>>>(deg, indptr, bsum, N);
    k_scan2<<<1, 64, 0, stream>>>(bsum, nb);
    k_scan3<<<nb, 256, 0, stream>>>(indptr, bsum, cursor, N);
    k_csr<<<2048, 256, 0, stream>>>(src, dst, cursor, esrc, E);

    for (int l = 0; l < L; ++l) {
        hipMemsetAsync(gsum, 0, TWOH * 8 * 2, stream);
        k_agg_gemm1<<<2048, 256, 0, stream>>>(x0, xb, esrc, indptr, deg,
            W1s + (size_t)l * H * TWOH, b1s + (size_t)l * TWOH, epss + l,
            h1, gsum, gsq, N);
        k_bnfin<<<1, 128, 0, stream>>>(gsum, gsq, gam + (size_t)l * TWOH,
            bet + (size_t)l * TWOH, scsh, N);
        k_gemm2<<<2048, 256, 0, stream>>>(h1, scsh,
            W2s + (size_t)l * TWOH * H, b2s + (size_t)l * H, x0, xb, N);
    }

    k_initout<<<1, 64, 0, stream>>>(bout, (float*)d_out);
    k_pool<<<512, 256, 0, stream>>>(x0, batch, Wout, (float*)d_out, N);
}

// Round 4
// 1677.476 us; speedup vs baseline: 1.4160x; 1.4160x over previous
//
#include <hip/hip_runtime.h>

#define H 64
#define CIN 32
#define TWOH 128
#define NGRAPH 64

typedef unsigned short bfraw;

__device__ __forceinline__ float bf2f(bfraw u) {
    return __uint_as_float(((unsigned)u) << 16);
}
__device__ __forceinline__ bfraw f2bf(float f) {
    unsigned u = __float_as_uint(f);
    unsigned r = (u + 0x7fffu + ((u >> 16) & 1u)) >> 16;  // RNE
    return (bfraw)r;
}

// ---------------- input GEMM: x0[N,64] = x[N,32] @ Win + bin ----------------
extern "C" __global__ void __launch_bounds__(256) k_input_gemm(
    const float* __restrict__ x, const float* __restrict__ Win,
    const float* __restrict__ bin, float* __restrict__ x0,
    bfraw* __restrict__ xb, int N)
{
    __shared__ float Wl[CIN * H]; // 8 KB
    for (int i = threadIdx.x; i < CIN * H; i += blockDim.x) Wl[i] = Win[i];
    __syncthreads();
    const int lane = threadIdx.x & 63;
    const int wpb = blockDim.x >> 6;
    int w = blockIdx.x * wpb + (threadIdx.x >> 6);
    const int wstride = gridDim.x * wpb;
    const float bv = bin[lane];
    for (int n = w; n < N; n += wstride) {
        float in = (lane < CIN) ? x[n * CIN + lane] : 0.f;
        float acc = bv;
        #pragma unroll
        for (int k = 0; k < CIN; ++k)
            acc += __shfl(in, k) * Wl[k * H + lane];
        x0[(size_t)n * H + lane] = acc;
        xb[(size_t)n * H + lane] = f2bf(acc);
    }
}

// ---------------- CSR build (padded to degree multiple of 4) ----------------
extern "C" __global__ void k_hist(const int* __restrict__ dst,
    unsigned* __restrict__ deg, int E)
{
    int i = blockIdx.x * blockDim.x + threadIdx.x;
    const int st = gridDim.x * blockDim.x;
    const int E4 = E >> 2;
    const int4* d4 = (const int4*)dst;
    for (int j = i; j < E4; j += st) {
        const int4 v = d4[j];
        atomicAdd(&deg[v.x], 1u);
        atomicAdd(&deg[v.y], 1u);
        atomicAdd(&deg[v.z], 1u);
        atomicAdd(&deg[v.w], 1u);
    }
    for (int j = (E4 << 2) + i; j < E; j += st) atomicAdd(&deg[dst[j]], 1u);
}

extern "C" __global__ void k_scan1(const unsigned* __restrict__ deg,
    unsigned* __restrict__ indptr, unsigned* __restrict__ bsum, int N)
{
    __shared__ unsigned s[256];
    const int tid = threadIdx.x;
    const int base = blockIdx.x * 1024 + tid * 4;
    unsigned d[4];
    #pragma unroll
    for (int j = 0; j < 4; ++j)
        d[j] = (base + j < N) ? ((deg[base + j] + 3u) & ~3u) : 0u;  // padded
    unsigned t = d[0] + d[1] + d[2] + d[3];
    s[tid] = t;
    __syncthreads();
    for (int o = 1; o < 256; o <<= 1) {
        unsigned v = (tid >= o) ? s[tid - o] : 0u;
        __syncthreads();
        s[tid] += v;
        __syncthreads();
    }
    unsigned run = (tid == 0) ? 0u : s[tid - 1];
    if (tid == 255) bsum[blockIdx.x] = s[255];
    #pragma unroll
    for (int j = 0; j < 4; ++j) {
        if (base + j < N) indptr[base + j] = run;
        run += d[j];
    }
}

extern "C" __global__ void k_scan2(unsigned* bsum, int nb,
    unsigned* __restrict__ indptr, int N)
{
    if (threadIdx.x == 0) {
        unsigned run = 0;
        for (int i = 0; i < nb; ++i) { unsigned v = bsum[i]; bsum[i] = run; run += v; }
        indptr[N] = run;  // total padded edges
    }
}

extern "C" __global__ void k_scan3(unsigned* __restrict__ indptr,
    const unsigned* __restrict__ bsum, unsigned* __restrict__ cursor, int N)
{
    const int base = blockIdx.x * 1024 + threadIdx.x * 4;
    const unsigned boff = bsum[blockIdx.x];
    #pragma unroll
    for (int j = 0; j < 4; ++j) {
        const int idx = base + j;
        if (idx < N) {
            const unsigned v = indptr[idx] + boff;
            indptr[idx] = v;
            cursor[idx] = v;
        }
    }
}

extern "C" __global__ void k_csr(const int* __restrict__ src,
    const int* __restrict__ dst, unsigned* __restrict__ cursor,
    int* __restrict__ esrc, int E)
{
    int i = blockIdx.x * blockDim.x + threadIdx.x;
    const int st = gridDim.x * blockDim.x;
    const int E4 = E >> 2;
    const int4* s4 = (const int4*)src;
    const int4* d4 = (const int4*)dst;
    for (int j = i; j < E4; j += st) {
        const int4 sv = s4[j];
        const int4 dv = d4[j];
        esrc[atomicAdd(&cursor[dv.x], 1u)] = sv.x;
        esrc[atomicAdd(&cursor[dv.y], 1u)] = sv.y;
        esrc[atomicAdd(&cursor[dv.z], 1u)] = sv.z;
        esrc[atomicAdd(&cursor[dv.w], 1u)] = sv.w;
    }
    for (int j = (E4 << 2) + i; j < E; j += st) {
        esrc[atomicAdd(&cursor[dst[j]], 1u)] = src[j];
    }
}

// fill padded slots with sentinel N (zero row)
extern "C" __global__ void k_pad(const unsigned* __restrict__ cursor,
    const unsigned* __restrict__ indptr, int* __restrict__ esrc, int N)
{
    int n = blockIdx.x * blockDim.x + threadIdx.x;
    const int st = gridDim.x * blockDim.x;
    for (; n < N; n += st) {
        const unsigned end = indptr[n + 1];
        for (unsigned p = cursor[n]; p < end; ++p) esrc[p] = N;
    }
}

// ------- gather/aggregate: hpre[n,:] = (1+eps)*x0[n,:] + sum relu(xb[src]) -------
// 16 lanes per row (ushort4 each), 4 edges per wave-instruction.
extern "C" __global__ void __launch_bounds__(256) k_agg(
    const float* __restrict__ x0, const bfraw* __restrict__ xb,
    const int* __restrict__ esrc, const unsigned* __restrict__ indptr,
    const float* __restrict__ epsp, float* __restrict__ hpre, int N)
{
    const int lane = threadIdx.x & 63;
    const int sub = lane >> 4;          // 0..3 : which edge of the group
    const int fi = (lane & 15) << 2;    // feature base (4 features)
    const int wpb = blockDim.x >> 6;
    int w = blockIdx.x * wpb + (threadIdx.x >> 6);
    const int wstride = gridDim.x * wpb;
    const float ep = 1.f + epsp[0];
    for (int n = w; n < N; n += wstride) {
        const unsigned s0 = indptr[n];
        const unsigned s1 = indptr[n + 1];   // padded: (s1-s0)%4==0
        float a0 = 0.f, a1 = 0.f, a2 = 0.f, a3 = 0.f;
        unsigned e = s0;
        for (; e + 16 <= s1; e += 16) {
            const int i0 = esrc[e + sub];
            const int i1 = esrc[e + 4 + sub];
            const int i2 = esrc[e + 8 + sub];
            const int i3 = esrc[e + 12 + sub];
            const ushort4 r0 = *(const ushort4*)&xb[(size_t)i0 * H + fi];
            const ushort4 r1 = *(const ushort4*)&xb[(size_t)i1 * H + fi];
            const ushort4 r2 = *(const ushort4*)&xb[(size_t)i2 * H + fi];
            const ushort4 r3 = *(const ushort4*)&xb[(size_t)i3 * H + fi];
            a0 += fmaxf(bf2f(r0.x), 0.f) + fmaxf(bf2f(r1.x), 0.f)
                + fmaxf(bf2f(r2.x), 0.f) + fmaxf(bf2f(r3.x), 0.f);
            a1 += fmaxf(bf2f(r0.y), 0.f) + fmaxf(bf2f(r1.y), 0.f)
                + fmaxf(bf2f(r2.y), 0.f) + fmaxf(bf2f(r3.y), 0.f);
            a2 += fmaxf(bf2f(r0.z), 0.f) + fmaxf(bf2f(r1.z), 0.f)
                + fmaxf(bf2f(r2.z), 0.f) + fmaxf(bf2f(r3.z), 0.f);
            a3 += fmaxf(bf2f(r0.w), 0.f) + fmaxf(bf2f(r1.w), 0.f)
                + fmaxf(bf2f(r2.w), 0.f) + fmaxf(bf2f(r3.w), 0.f);
        }
        for (; e < s1; e += 4) {
            const int i0 = esrc[e + sub];
            const ushort4 r0 = *(const ushort4*)&xb[(size_t)i0 * H + fi];
            a0 += fmaxf(bf2f(r0.x), 0.f);
            a1 += fmaxf(bf2f(r0.y), 0.f);
            a2 += fmaxf(bf2f(r0.z), 0.f);
            a3 += fmaxf(bf2f(r0.w), 0.f);
        }
        #pragma unroll
        for (int o = 16; o < 64; o <<= 1) {
            a0 += __shfl_xor(a0, o);
            a1 += __shfl_xor(a1, o);
            a2 += __shfl_xor(a2, o);
            a3 += __shfl_xor(a3, o);
        }
        if (sub == 0) {
            const float4 self = *(const float4*)&x0[(size_t)n * H + fi];
            float4 o;
            o.x = ep * self.x + a0;
            o.y = ep * self.y + a1;
            o.z = ep * self.z + a2;
            o.w = ep * self.w + a3;
            *(float4*)&hpre[(size_t)n * H + fi] = o;
        }
    }
}

// ------------- fused: GEMM1 + BN stats (h1 = hpre @ W1 + b1) -------------
extern "C" __global__ void __launch_bounds__(256) k_gemm1(
    const float* __restrict__ hpre,
    const float* __restrict__ W1, const float* __restrict__ b1,
    float* __restrict__ h1,
    double* __restrict__ gsum, double* __restrict__ gsq, int N)
{
    __shared__ float Wl[H * TWOH];        // 32 KB
    __shared__ float ss[TWOH], sq[TWOH];  // 1 KB
    for (int i = threadIdx.x; i < H * TWOH; i += blockDim.x) Wl[i] = W1[i];
    if (threadIdx.x < TWOH) { ss[threadIdx.x] = 0.f; sq[threadIdx.x] = 0.f; }
    __syncthreads();
    const int lane = threadIdx.x & 63;
    const int wpb = blockDim.x >> 6;
    int w = blockIdx.x * wpb + (threadIdx.x >> 6);
    const int wstride = gridDim.x * wpb;
    const float b0 = b1[lane], bb = b1[H + lane];
    float s0 = 0.f, s1 = 0.f, q0 = 0.f, q1 = 0.f;
    for (int n = w; n < N; n += wstride) {
        const float h = hpre[(size_t)n * H + lane];
        float c0a = b0, c0b = 0.f, c1a = bb, c1b = 0.f;
        #pragma unroll
        for (int k = 0; k < H; k += 2) {
            const float va = __shfl(h, k);
            const float vb = __shfl(h, k + 1);
            c0a += va * Wl[k * TWOH + lane];
            c1a += va * Wl[k * TWOH + H + lane];
            c0b += vb * Wl[(k + 1) * TWOH + lane];
            c1b += vb * Wl[(k + 1) * TWOH + H + lane];
        }
        const float c0 = c0a + c0b;
        const float c1 = c1a + c1b;
        h1[(size_t)n * TWOH + lane] = c0;
        h1[(size_t)n * TWOH + H + lane] = c1;
        s0 += c0; s1 += c1; q0 += c0 * c0; q1 += c1 * c1;
    }
    atomicAdd(&ss[lane], s0); atomicAdd(&ss[H + lane], s1);
    atomicAdd(&sq[lane], q0); atomicAdd(&sq[H + lane], q1);
    __syncthreads();
    if (threadIdx.x < TWOH) {
        atomicAdd(&gsum[threadIdx.x], (double)ss[threadIdx.x]);
        atomicAdd(&gsq[threadIdx.x], (double)sq[threadIdx.x]);
    }
}

// ---------------- BN finalize: scale/shift ----------------
extern "C" __global__ void k_bnfin(const double* __restrict__ gsum,
    const double* __restrict__ gsq, const float* __restrict__ gamma,
    const float* __restrict__ beta, float* __restrict__ scsh, int N)
{
    const int j = threadIdx.x;
    if (j < TWOH) {
        const double mu = gsum[j] / N;
        const double var = gsq[j] / N - mu * mu;
        const float sc = gamma[j] * rsqrtf(fmaxf((float)var, 0.f) + 1e-5f);
        scsh[j] = sc;
        scsh[TWOH + j] = beta[j] - (float)mu * sc;
    }
}

// ------------- fused: BN apply + ReLU + GEMM2 + residual -------------
extern "C" __global__ void __launch_bounds__(256) k_gemm2(
    const float* __restrict__ h1, const float* __restrict__ scsh,
    const float* __restrict__ W2, const float* __restrict__ b2,
    float* __restrict__ x0, bfraw* __restrict__ xb, int N)
{
    __shared__ float Wl[TWOH * H];  // 32 KB
    __shared__ float sc[2 * TWOH];
    for (int i = threadIdx.x; i < TWOH * H; i += blockDim.x) Wl[i] = W2[i];
    for (int i = threadIdx.x; i < 2 * TWOH; i += blockDim.x) sc[i] = scsh[i];
    __syncthreads();
    const int lane = threadIdx.x & 63;
    const int wpb = blockDim.x >> 6;
    int w = blockIdx.x * wpb + (threadIdx.x >> 6);
    const int wstride = gridDim.x * wpb;
    const float bv = b2[lane];
    const float sc0 = sc[lane], sh0 = sc[TWOH + lane];
    const float sc1 = sc[H + lane], sh1 = sc[TWOH + H + lane];
    for (int n = w; n < N; n += wstride) {
        const float y0 = fmaxf(h1[(size_t)n * TWOH + lane] * sc0 + sh0, 0.f);
        const float y1 = fmaxf(h1[(size_t)n * TWOH + H + lane] * sc1 + sh1, 0.f);
        float acca = bv, accb = 0.f;
        #pragma unroll
        for (int k = 0; k < H; k += 2) {
            acca += __shfl(y0, k) * Wl[k * H + lane];
            accb += __shfl(y0, k + 1) * Wl[(k + 1) * H + lane];
        }
        #pragma unroll
        for (int k = 0; k < H; k += 2) {
            acca += __shfl(y1, k) * Wl[(H + k) * H + lane];
            accb += __shfl(y1, k + 1) * Wl[(H + k + 1) * H + lane];
        }
        const float xn = x0[(size_t)n * H + lane] + acca + accb;
        x0[(size_t)n * H + lane] = xn;
        xb[(size_t)n * H + lane] = f2bf(xn);
    }
}

// ---------------- pooling + output ----------------
extern "C" __global__ void k_initout(const float* __restrict__ bout,
    float* __restrict__ out)
{
    if (threadIdx.x < NGRAPH) out[threadIdx.x] = bout[0];
}

extern "C" __global__ void __launch_bounds__(256) k_pool(
    const float* __restrict__ x0, const int* __restrict__ batch,
    const float* __restrict__ Wout, float* __restrict__ out, int N)
{
    __shared__ float pl[NGRAPH];
    if (threadIdx.x < NGRAPH) pl[threadIdx.x] = 0.f;
    __syncthreads();
    const int lane = threadIdx.x & 63;
    const int wpb = blockDim.x >> 6;
    int w = blockIdx.x * wpb + (threadIdx.x >> 6);
    const int wstride = gridDim.x * wpb;
    const float wv = Wout[lane];
    for (int n = w; n < N; n += wstride) {
        float v = x0[(size_t)n * H + lane] * wv;
        #pragma unroll
        for (int o = 32; o > 0; o >>= 1) v += __shfl_down(v, o);
        if (lane == 0) atomicAdd(&pl[batch[n]], v);
    }
    __syncthreads();
    if (threadIdx.x < NGRAPH) {
        const float v = pl[threadIdx.x];
        if (v != 0.f) atomicAdd(&out[threadIdx.x], v);
    }
}

// ---------------- host driver ----------------
extern "C" void kernel_launch(void* const* d_in, const int* in_sizes, int n_in,
                              void* d_out, int out_size, void* d_ws, size_t ws_size,
                              hipStream_t stream)
{
    const float* x     = (const float*)d_in[0];
    const int*   ei    = (const int*)d_in[1];   // int32 per harness conversion
    const int*   batch = (const int*)d_in[2];   // int32 per harness conversion
    const float* Win   = (const float*)d_in[3];
    const float* bin   = (const float*)d_in[4];
    const float* W1s   = (const float*)d_in[5];
    const float* b1s   = (const float*)d_in[6];
    const float* gam   = (const float*)d_in[7];
    const float* bet   = (const float*)d_in[8];
    const float* W2s   = (const float*)d_in[9];
    const float* b2s   = (const float*)d_in[10];
    const float* epss  = (const float*)d_in[11];
    const float* Wout  = (const float*)d_in[12];
    const float* bout  = (const float*)d_in[13];

    const int N = in_sizes[0] / CIN;
    const int E = in_sizes[1] / 2;
    const int L = in_sizes[11];
    const int* src = ei;
    const int* dst = ei + E;

    // workspace layout
    char* ws = (char*)d_ws;
    size_t off = 0;
    auto take = [&](size_t bytes) {
        void* p = ws + off;
        off += (bytes + 255) & ~(size_t)255;
        return p;
    };
    float*    x0     = (float*)take((size_t)N * H * 4);
    bfraw*    xb     = (bfraw*)take((size_t)(N + 1) * H * 2);  // +1 zero row
    float*    hpre   = (float*)take((size_t)N * H * 4);
    float*    h1     = (float*)take((size_t)N * TWOH * 4);
    unsigned* deg    = (unsigned*)take((size_t)N * 4);
    unsigned* indptr = (unsigned*)take((size_t)(N + 1) * 4);
    unsigned* cursor = (unsigned*)take((size_t)N * 4);
    int*      esrc   = (int*)take((size_t)(E + 4 * (N + 1)) * 4);  // padded
    unsigned* bsum   = (unsigned*)take(4096);
    double*   gsum   = (double*)take(TWOH * 8 * 2); // gsum + gsq contiguous
    double*   gsq    = gsum + TWOH;
    float*    scsh   = (float*)take(2 * TWOH * 4);
    (void)ws_size; (void)n_in; (void)out_size;

    hipMemsetAsync(deg, 0, (size_t)N * 4, stream);
    hipMemsetAsync(xb + (size_t)N * H, 0, H * 2, stream);  // sentinel zero row
    k_input_gemm<<<1024, 256, 0, stream>>>(x, Win, bin, x0, xb, N);
    k_hist<<<2048, 256, 0, stream>>>(dst, deg, E);
    const int nb = (N + 1023) / 1024;
    k_scan1<<<nb, 256, 0, stream>>>(deg, indptr, bsum, N);
    k_scan2<<<1, 64, 0, stream>>>(bsum, nb, indptr, N);
    k_scan3<<<nb, 256, 0, stream>>>(indptr, bsum, cursor, N);
    k_csr<<<2048, 256, 0, stream>>>(src, dst, cursor, esrc, E);
    k_pad<<<512, 256, 0, stream>>>(cursor, indptr, esrc, N);

    for (int l = 0; l < L; ++l) {
        hipMemsetAsync(gsum, 0, TWOH * 8 * 2, stream);
        k_agg<<<4096, 256, 0, stream>>>(x0, xb, esrc, indptr, epss + l, hpre, N);
        k_gemm1<<<2048, 256, 0, stream>>>(hpre,
            W1s + (size_t)l * H * TWOH, b1s + (size_t)l * TWOH,
            h1, gsum, gsq, N);
        k_bnfin<<<1, 128, 0, stream>>>(gsum, gsq, gam + (size_t)l * TWOH,
            bet + (size_t)l * TWOH, scsh, N);
        k_gemm2<<<2048, 256, 0, stream>>>(h1, scsh,
            W2s + (size_t)l * TWOH * H, b2s + (size_t)l * H, x0, xb, N);
    }

    k_initout<<<1, 64, 0, stream>>>(bout, (float*)d_out);
    k_pool<<<512, 256, 0, stream>>>(x0, batch, Wout, (float*)d_out, N);
}

// Round 6
// 796.851 us; speedup vs baseline: 2.9808x; 2.1051x over previous
//
#include <hip/hip_runtime.h>

#define H 64
#define CIN 32
#define TWOH 128
#define NGRAPH 64

typedef unsigned short bfraw;
typedef short v8s __attribute__((ext_vector_type(8)));
typedef float v4f __attribute__((ext_vector_type(4)));

__device__ __forceinline__ float bf2f(bfraw u) {
    return __uint_as_float(((unsigned)u) << 16);
}
__device__ __forceinline__ bfraw f2bf(float f) {
    unsigned u = __float_as_uint(f);
    unsigned r = (u + 0x7fffu + ((u >> 16) & 1u)) >> 16;  // RNE
    return (bfraw)r;
}
// split fp32 -> hi + lo bf16 (combined rel err ~2^-17)
__device__ __forceinline__ void f2bf2(float f, bfraw& hi, bfraw& lo) {
    hi = f2bf(f);
    lo = f2bf(f - bf2f(hi));
}

// ---------------- input GEMM: x0[N,64] = x[N,32] @ Win + bin ----------------
extern "C" __global__ void __launch_bounds__(256) k_input_gemm(
    const float* __restrict__ x, const float* __restrict__ Win,
    const float* __restrict__ bin, float* __restrict__ x0,
    bfraw* __restrict__ xb, int N)
{
    __shared__ float Wl[CIN * H]; // 8 KB
    for (int i = threadIdx.x; i < CIN * H; i += blockDim.x) Wl[i] = Win[i];
    __syncthreads();
    const int lane = threadIdx.x & 63;
    const int wpb = blockDim.x >> 6;
    int w = blockIdx.x * wpb + (threadIdx.x >> 6);
    const int wstride = gridDim.x * wpb;
    const float bv = bin[lane];
    for (int n = w; n < N; n += wstride) {
        float in = (lane < CIN) ? x[n * CIN + lane] : 0.f;
        float acc = bv;
        #pragma unroll
        for (int k = 0; k < CIN; ++k)
            acc += __shfl(in, k) * Wl[k * H + lane];
        x0[(size_t)n * H + lane] = acc;
        xb[(size_t)n * H + lane] = f2bf(acc);
    }
}

// ---------------- weight conversion to split bf16 (all layers, once) ----------------
extern "C" __global__ void k_cvtw(const float* __restrict__ W1s,
    const float* __restrict__ W2s, bfraw* __restrict__ W1hi,
    bfraw* __restrict__ W1lo, bfraw* __restrict__ W2hi,
    bfraw* __restrict__ W2lo, int total)  // total = L*H*TWOH
{
    int i = blockIdx.x * blockDim.x + threadIdx.x;
    const int st = gridDim.x * blockDim.x;
    for (; i < total; i += st) {
        bfraw h, l;
        f2bf2(W1s[i], h, l); W1hi[i] = h; W1lo[i] = l;
        f2bf2(W2s[i], h, l); W2hi[i] = h; W2lo[i] = l;
    }
}

// ---------------- CSR build (padded to degree multiple of 4) ----------------
extern "C" __global__ void k_hist(const int* __restrict__ dst,
    unsigned* __restrict__ deg, int E)
{
    int i = blockIdx.x * blockDim.x + threadIdx.x;
    const int st = gridDim.x * blockDim.x;
    const int E4 = E >> 2;
    const int4* d4 = (const int4*)dst;
    for (int j = i; j < E4; j += st) {
        const int4 v = d4[j];
        atomicAdd(&deg[v.x], 1u);
        atomicAdd(&deg[v.y], 1u);
        atomicAdd(&deg[v.z], 1u);
        atomicAdd(&deg[v.w], 1u);
    }
    for (int j = (E4 << 2) + i; j < E; j += st) atomicAdd(&deg[dst[j]], 1u);
}

extern "C" __global__ void k_scan1(const unsigned* __restrict__ deg,
    unsigned* __restrict__ indptr, unsigned* __restrict__ bsum, int N)
{
    __shared__ unsigned s[256];
    const int tid = threadIdx.x;
    const int base = blockIdx.x * 1024 + tid * 4;
    unsigned d[4];
    #pragma unroll
    for (int j = 0; j < 4; ++j)
        d[j] = (base + j < N) ? ((deg[base + j] + 3u) & ~3u) : 0u;  // padded
    unsigned t = d[0] + d[1] + d[2] + d[3];
    s[tid] = t;
    __syncthreads();
    for (int o = 1; o < 256; o <<= 1) {
        unsigned v = (tid >= o) ? s[tid - o] : 0u;
        __syncthreads();
        s[tid] += v;
        __syncthreads();
    }
    unsigned run = (tid == 0) ? 0u : s[tid - 1];
    if (tid == 255) bsum[blockIdx.x] = s[255];
    #pragma unroll
    for (int j = 0; j < 4; ++j) {
        if (base + j < N) indptr[base + j] = run;
        run += d[j];
    }
}

extern "C" __global__ void k_scan2(unsigned* bsum, int nb,
    unsigned* __restrict__ indptr, int N)
{
    if (threadIdx.x == 0) {
        unsigned run = 0;
        for (int i = 0; i < nb; ++i) { unsigned v = bsum[i]; bsum[i] = run; run += v; }
        indptr[N] = run;  // total padded edges
    }
}

extern "C" __global__ void k_scan3(unsigned* __restrict__ indptr,
    const unsigned* __restrict__ bsum, unsigned* __restrict__ cursor, int N)
{
    const int base = blockIdx.x * 1024 + threadIdx.x * 4;
    const unsigned boff = bsum[blockIdx.x];
    #pragma unroll
    for (int j = 0; j < 4; ++j) {
        const int idx = base + j;
        if (idx < N) {
            const unsigned v = indptr[idx] + boff;
            indptr[idx] = v;
            cursor[idx] = v;
        }
    }
}

extern "C" __global__ void k_csr(const int* __restrict__ src,
    const int* __restrict__ dst, unsigned* __restrict__ cursor,
    int* __restrict__ esrc, int E)
{
    int i = blockIdx.x * blockDim.x + threadIdx.x;
    const int st = gridDim.x * blockDim.x;
    const int E4 = E >> 2;
    const int4* s4 = (const int4*)src;
    const int4* d4 = (const int4*)dst;
    for (int j = i; j < E4; j += st) {
        const int4 sv = s4[j];
        const int4 dv = d4[j];
        esrc[atomicAdd(&cursor[dv.x], 1u)] = sv.x;
        esrc[atomicAdd(&cursor[dv.y], 1u)] = sv.y;
        esrc[atomicAdd(&cursor[dv.z], 1u)] = sv.z;
        esrc[atomicAdd(&cursor[dv.w], 1u)] = sv.w;
    }
    for (int j = (E4 << 2) + i; j < E; j += st) {
        esrc[atomicAdd(&cursor[dst[j]], 1u)] = src[j];
    }
}

// fill padded slots with sentinel N (zero row)
extern "C" __global__ void k_pad(const unsigned* __restrict__ cursor,
    const unsigned* __restrict__ indptr, int* __restrict__ esrc, int N)
{
    int n = blockIdx.x * blockDim.x + threadIdx.x;
    const int st = gridDim.x * blockDim.x;
    for (; n < N; n += st) {
        const unsigned end = indptr[n + 1];
        for (unsigned p = cursor[n]; p < end; ++p) esrc[p] = N;
    }
}

// ------- gather: hpre = (1+eps)*x0 + sum relu(xb[src]); store split bf16 -------
extern "C" __global__ void __launch_bounds__(256) k_agg(
    const float* __restrict__ x0, const bfraw* __restrict__ xb,
    const int* __restrict__ esrc, const unsigned* __restrict__ indptr,
    const float* __restrict__ epsp, bfraw* __restrict__ hprehi,
    bfraw* __restrict__ hprelo, int N)
{
    const int lane = threadIdx.x & 63;
    const int sub = lane >> 4;          // 0..3 : which edge of the group
    const int fi = (lane & 15) << 2;    // feature base (4 features)
    const int wpb = blockDim.x >> 6;
    int w = blockIdx.x * wpb + (threadIdx.x >> 6);
    const int wstride = gridDim.x * wpb;
    const float ep = 1.f + epsp[0];
    for (int n = w; n < N; n += wstride) {
        const unsigned s0 = indptr[n];
        const unsigned s1 = indptr[n + 1];   // padded: (s1-s0)%4==0
        float a0 = 0.f, a1 = 0.f, a2 = 0.f, a3 = 0.f;
        unsigned e = s0;
        for (; e + 16 <= s1; e += 16) {
            const int i0 = esrc[e + sub];
            const int i1 = esrc[e + 4 + sub];
            const int i2 = esrc[e + 8 + sub];
            const int i3 = esrc[e + 12 + sub];
            const ushort4 r0 = *(const ushort4*)&xb[(size_t)i0 * H + fi];
            const ushort4 r1 = *(const ushort4*)&xb[(size_t)i1 * H + fi];
            const ushort4 r2 = *(const ushort4*)&xb[(size_t)i2 * H + fi];
            const ushort4 r3 = *(const ushort4*)&xb[(size_t)i3 * H + fi];
            a0 += fmaxf(bf2f(r0.x), 0.f) + fmaxf(bf2f(r1.x), 0.f)
                + fmaxf(bf2f(r2.x), 0.f) + fmaxf(bf2f(r3.x), 0.f);
            a1 += fmaxf(bf2f(r0.y), 0.f) + fmaxf(bf2f(r1.y), 0.f)
                + fmaxf(bf2f(r2.y), 0.f) + fmaxf(bf2f(r3.y), 0.f);
            a2 += fmaxf(bf2f(r0.z), 0.f) + fmaxf(bf2f(r1.z), 0.f)
                + fmaxf(bf2f(r2.z), 0.f) + fmaxf(bf2f(r3.z), 0.f);
            a3 += fmaxf(bf2f(r0.w), 0.f) + fmaxf(bf2f(r1.w), 0.f)
                + fmaxf(bf2f(r2.w), 0.f) + fmaxf(bf2f(r3.w), 0.f);
        }
        for (; e < s1; e += 4) {
            const int i0 = esrc[e + sub];
            const ushort4 r0 = *(const ushort4*)&xb[(size_t)i0 * H + fi];
            a0 += fmaxf(bf2f(r0.x), 0.f);
            a1 += fmaxf(bf2f(r0.y), 0.f);
            a2 += fmaxf(bf2f(r0.z), 0.f);
            a3 += fmaxf(bf2f(r0.w), 0.f);
        }
        #pragma unroll
        for (int o = 16; o < 64; o <<= 1) {
            a0 += __shfl_xor(a0, o);
            a1 += __shfl_xor(a1, o);
            a2 += __shfl_xor(a2, o);
            a3 += __shfl_xor(a3, o);
        }
        if (sub == 0) {
            const float4 self = *(const float4*)&x0[(size_t)n * H + fi];
            const float h0 = ep * self.x + a0;
            const float h1v = ep * self.y + a1;
            const float h2 = ep * self.z + a2;
            const float h3 = ep * self.w + a3;
            ushort4 ohi, olo;
            f2bf2(h0, ohi.x, olo.x);
            f2bf2(h1v, ohi.y, olo.y);
            f2bf2(h2, ohi.z, olo.z);
            f2bf2(h3, ohi.w, olo.w);
            *(ushort4*)&hprehi[(size_t)n * H + fi] = ohi;
            *(ushort4*)&hprelo[(size_t)n * H + fi] = olo;
        }
    }
}

// ------------- MFMA GEMM1 + BN stats: h1[N,128] = hpre @ W1 + b1 -------------
// split precision: C = Ahi*Whi + Ahi*Wlo + Alo*Whi. Each wave: half the cols.
extern "C" __global__ void __launch_bounds__(256) k_gemm1(
    const bfraw* __restrict__ hprehi, const bfraw* __restrict__ hprelo,
    const bfraw* __restrict__ W1hi, const bfraw* __restrict__ W1lo,
    const float* __restrict__ b1, float* __restrict__ h1,
    double* __restrict__ gsum, double* __restrict__ gsq, int N)
{
    __shared__ float ss[TWOH], sq[TWOH];
    if (threadIdx.x < TWOH) { ss[threadIdx.x] = 0.f; sq[threadIdx.x] = 0.f; }
    __syncthreads();
    const int lane = threadIdx.x & 63;
    const int row = lane & 15;   // A row / B col / D col
    const int kg  = lane >> 4;   // k-group
    const int wpb = blockDim.x >> 6;
    const int wid = blockIdx.x * wpb + (threadIdx.x >> 6);
    const int wstride = gridDim.x * wpb;
    const int half = wid & 1;          // which 64 of the 128 cols
    const int cb = half * 4;           // col-tile base
    // preload B fragments: 2 k-chunks x 4 col-tiles, hi+lo
    v8s bhi[2][4], blo[2][4];
    #pragma unroll
    for (int kc = 0; kc < 2; ++kc)
        #pragma unroll
        for (int ct = 0; ct < 4; ++ct) {
            v8s bh, bl;
            #pragma unroll
            for (int i = 0; i < 8; ++i) {
                const int idx = (kc * 32 + kg * 8 + i) * TWOH + (cb + ct) * 16 + row;
                bh[i] = (short)W1hi[idx];
                bl[i] = (short)W1lo[idx];
            }
            bhi[kc][ct] = bh; blo[kc][ct] = bl;
        }
    float bcol[4];
    #pragma unroll
    for (int ct = 0; ct < 4; ++ct) bcol[ct] = b1[(cb + ct) * 16 + row];

    const int tiles = (N + 15) >> 4;
    const int tstride = wstride >> 1;
    float sacc[4], qacc[4];
    #pragma unroll
    for (int ct = 0; ct < 4; ++ct) { sacc[ct] = 0.f; qacc[ct] = 0.f; }

    for (int t = wid >> 1; t < tiles; t += tstride) {
        const int tb = t << 4;
        int nA = tb + row; if (nA >= N) nA = N - 1;
        const v8s a0h = *(const v8s*)&hprehi[(size_t)nA * H + kg * 8];
        const v8s a1h = *(const v8s*)&hprehi[(size_t)nA * H + 32 + kg * 8];
        const v8s a0l = *(const v8s*)&hprelo[(size_t)nA * H + kg * 8];
        const v8s a1l = *(const v8s*)&hprelo[(size_t)nA * H + 32 + kg * 8];
        v4f c[4];
        #pragma unroll
        for (int ct = 0; ct < 4; ++ct) {
            v4f cc = (v4f){0.f, 0.f, 0.f, 0.f};
            cc = __builtin_amdgcn_mfma_f32_16x16x32_bf16(a0h, bhi[0][ct], cc, 0, 0, 0);
            cc = __builtin_amdgcn_mfma_f32_16x16x32_bf16(a1h, bhi[1][ct], cc, 0, 0, 0);
            cc = __builtin_amdgcn_mfma_f32_16x16x32_bf16(a0h, blo[0][ct], cc, 0, 0, 0);
            cc = __builtin_amdgcn_mfma_f32_16x16x32_bf16(a1h, blo[1][ct], cc, 0, 0, 0);
            cc = __builtin_amdgcn_mfma_f32_16x16x32_bf16(a0l, bhi[0][ct], cc, 0, 0, 0);
            cc = __builtin_amdgcn_mfma_f32_16x16x32_bf16(a1l, bhi[1][ct], cc, 0, 0, 0);
            c[ct] = cc;
        }
        #pragma unroll
        for (int ct = 0; ct < 4; ++ct) {
            #pragma unroll
            for (int r = 0; r < 4; ++r) {
                const int node = tb + kg * 4 + r;  // D row
                if (node < N) {
                    const float v = c[ct][r] + bcol[ct];
                    h1[(size_t)node * TWOH + (cb + ct) * 16 + row] = v;
                    sacc[ct] += v;
                    qacc[ct] += v * v;
                }
            }
        }
    }
    #pragma unroll
    for (int ct = 0; ct < 4; ++ct) {
        float s = sacc[ct];
        s += __shfl_xor(s, 16); s += __shfl_xor(s, 32);
        float q = qacc[ct];
        q += __shfl_xor(q, 16); q += __shfl_xor(q, 32);
        if (kg == 0) {
            atomicAdd(&ss[(cb + ct) * 16 + row], s);
            atomicAdd(&sq[(cb + ct) * 16 + row], q);
        }
    }
    __syncthreads();
    if (threadIdx.x < TWOH) {
        atomicAdd(&gsum[threadIdx.x], (double)ss[threadIdx.x]);
        atomicAdd(&gsq[threadIdx.x], (double)sq[threadIdx.x]);
    }
}

// ---------------- BN finalize: scale/shift ----------------
extern "C" __global__ void k_bnfin(const double* __restrict__ gsum,
    const double* __restrict__ gsq, const float* __restrict__ gamma,
    const float* __restrict__ beta, float* __restrict__ scsh, int N)
{
    const int j = threadIdx.x;
    if (j < TWOH) {
        const double mu = gsum[j] / N;
        const double var = gsq[j] / N - mu * mu;
        const float sc = gamma[j] * rsqrtf(fmaxf((float)var, 0.f) + 1e-5f);
        scsh[j] = sc;
        scsh[TWOH + j] = beta[j] - (float)mu * sc;
    }
}

// ---------------- BN apply + ReLU -> split bf16 y ----------------
extern "C" __global__ void __launch_bounds__(256) k_bnrelu(
    const float* __restrict__ h1, const float* __restrict__ scsh,
    bfraw* __restrict__ yhi, bfraw* __restrict__ ylo, int total4)
{
    int i = blockIdx.x * blockDim.x + threadIdx.x;
    const int st = gridDim.x * blockDim.x;
    for (; i < total4; i += st) {
        const int f = (i << 2) & (TWOH - 1);
        const float4 h = *(const float4*)&h1[(size_t)i << 2];
        const float4 sc = *(const float4*)&scsh[f];
        const float4 sh = *(const float4*)&scsh[TWOH + f];
        ushort4 ohi, olo;
        f2bf2(fmaxf(h.x * sc.x + sh.x, 0.f), ohi.x, olo.x);
        f2bf2(fmaxf(h.y * sc.y + sh.y, 0.f), ohi.y, olo.y);
        f2bf2(fmaxf(h.z * sc.z + sh.z, 0.f), ohi.z, olo.z);
        f2bf2(fmaxf(h.w * sc.w + sh.w, 0.f), ohi.w, olo.w);
        *(ushort4*)&yhi[(size_t)i << 2] = ohi;
        *(ushort4*)&ylo[(size_t)i << 2] = olo;
    }
}

// ------------- MFMA GEMM2 + residual: x0 += y @ W2 + b2 -------------
extern "C" __global__ void __launch_bounds__(256) k_gemm2(
    const bfraw* __restrict__ yhi, const bfraw* __restrict__ ylo,
    const bfraw* __restrict__ W2hi, const bfraw* __restrict__ W2lo,
    const float* __restrict__ b2, float* __restrict__ x0,
    bfraw* __restrict__ xb, int N)
{
    const int lane = threadIdx.x & 63;
    const int row = lane & 15;
    const int kg  = lane >> 4;
    const int wpb = blockDim.x >> 6;
    const int wid = blockIdx.x * wpb + (threadIdx.x >> 6);
    const int wstride = gridDim.x * wpb;
    const int half = wid & 1;       // which 32 of the 64 cols
    const int cb = half * 2;        // col-tile base
    // preload B fragments: 4 k-chunks x 2 col-tiles, hi+lo
    v8s bhi[4][2], blo[4][2];
    #pragma unroll
    for (int kc = 0; kc < 4; ++kc)
        #pragma unroll
        for (int ct = 0; ct < 2; ++ct) {
            v8s bh, bl;
            #pragma unroll
            for (int i = 0; i < 8; ++i) {
                const int idx = (kc * 32 + kg * 8 + i) * H + (cb + ct) * 16 + row;
                bh[i] = (short)W2hi[idx];
                bl[i] = (short)W2lo[idx];
            }
            bhi[kc][ct] = bh; blo[kc][ct] = bl;
        }
    float bcol[2];
    #pragma unroll
    for (int ct = 0; ct < 2; ++ct) bcol[ct] = b2[(cb + ct) * 16 + row];

    const int tiles = (N + 15) >> 4;
    const int tstride = wstride >> 1;

    for (int t = wid >> 1; t < tiles; t += tstride) {
        const int tb = t << 4;
        int nA = tb + row; if (nA >= N) nA = N - 1;
        v8s ah[4], al[4];
        #pragma unroll
        for (int kc = 0; kc < 4; ++kc) {
            ah[kc] = *(const v8s*)&yhi[(size_t)nA * TWOH + kc * 32 + kg * 8];
            al[kc] = *(const v8s*)&ylo[(size_t)nA * TWOH + kc * 32 + kg * 8];
        }
        v4f c[2];
        #pragma unroll
        for (int ct = 0; ct < 2; ++ct) {
            v4f cc = (v4f){0.f, 0.f, 0.f, 0.f};
            #pragma unroll
            for (int kc = 0; kc < 4; ++kc) {
                cc = __builtin_amdgcn_mfma_f32_16x16x32_bf16(ah[kc], bhi[kc][ct], cc, 0, 0, 0);
                cc = __builtin_amdgcn_mfma_f32_16x16x32_bf16(ah[kc], blo[kc][ct], cc, 0, 0, 0);
                cc = __builtin_amdgcn_mfma_f32_16x16x32_bf16(al[kc], bhi[kc][ct], cc, 0, 0, 0);
            }
            c[ct] = cc;
        }
        #pragma unroll
        for (int ct = 0; ct < 2; ++ct) {
            #pragma unroll
            for (int r = 0; r < 4; ++r) {
                const int node = tb + kg * 4 + r;
                if (node < N) {
                    const size_t idx = (size_t)node * H + (cb + ct) * 16 + row;
                    const float v = x0[idx] + c[ct][r] + bcol[ct];
                    x0[idx] = v;
                    xb[idx] = f2bf(v);
                }
            }
        }
    }
}

// ---------------- pooling + output ----------------
extern "C" __global__ void k_initout(const float* __restrict__ bout,
    float* __restrict__ out)
{
    if (threadIdx.x < NGRAPH) out[threadIdx.x] = bout[0];
}

extern "C" __global__ void __launch_bounds__(256) k_pool(
    const float* __restrict__ x0, const int* __restrict__ batch,
    const float* __restrict__ Wout, float* __restrict__ out, int N)
{
    __shared__ float pl[NGRAPH];
    if (threadIdx.x < NGRAPH) pl[threadIdx.x] = 0.f;
    __syncthreads();
    const int lane = threadIdx.x & 63;
    const int wpb = blockDim.x >> 6;
    int w = blockIdx.x * wpb + (threadIdx.x >> 6);
    const int wstride = gridDim.x * wpb;
    const float wv = Wout[lane];
    for (int n = w; n < N; n += wstride) {
        float v = x0[(size_t)n * H + lane] * wv;
        #pragma unroll
        for (int o = 32; o > 0; o >>= 1) v += __shfl_down(v, o);
        if (lane == 0) atomicAdd(&pl[batch[n]], v);
    }
    __syncthreads();
    if (threadIdx.x < NGRAPH) {
        const float v = pl[threadIdx.x];
        if (v != 0.f) atomicAdd(&out[threadIdx.x], v);
    }
}

// ---------------- host driver ----------------
extern "C" void kernel_launch(void* const* d_in, const int* in_sizes, int n_in,
                              void* d_out, int out_size, void* d_ws, size_t ws_size,
                              hipStream_t stream)
{
    const float* x     = (const float*)d_in[0];
    const int*   ei    = (const int*)d_in[1];   // int32 per harness conversion
    const int*   batch = (const int*)d_in[2];   // int32 per harness conversion
    const float* Win   = (const float*)d_in[3];
    const float* bin   = (const float*)d_in[4];
    const float* W1s   = (const float*)d_in[5];
    const float* b1s   = (const float*)d_in[6];
    const float* gam   = (const float*)d_in[7];
    const float* bet   = (const float*)d_in[8];
    const float* W2s   = (const float*)d_in[9];
    const float* b2s   = (const float*)d_in[10];
    const float* epss  = (const float*)d_in[11];
    const float* Wout  = (const float*)d_in[12];
    const float* bout  = (const float*)d_in[13];

    const int N = in_sizes[0] / CIN;
    const int E = in_sizes[1] / 2;
    const int L = in_sizes[11];
    const int* src = ei;
    const int* dst = ei + E;

    // workspace layout (~177 MB)
    char* ws = (char*)d_ws;
    size_t off = 0;
    auto take = [&](size_t bytes) {
        void* p = ws + off;
        off += (bytes + 255) & ~(size_t)255;
        return p;
    };
    float*    x0     = (float*)take((size_t)N * H * 4);
    bfraw*    xb     = (bfraw*)take((size_t)(N + 1) * H * 2);  // +1 zero row
    bfraw*    hprehi = (bfraw*)take((size_t)N * H * 2);
    bfraw*    hprelo = (bfraw*)take((size_t)N * H * 2);
    float*    h1     = (float*)take((size_t)N * TWOH * 4);
    bfraw*    yhi    = (bfraw*)take((size_t)N * TWOH * 2);
    bfraw*    ylo    = (bfraw*)take((size_t)N * TWOH * 2);
    unsigned* deg    = (unsigned*)take((size_t)N * 4);
    unsigned* indptr = (unsigned*)take((size_t)(N + 1) * 4);
    unsigned* cursor = (unsigned*)take((size_t)N * 4);
    int*      esrc   = (int*)take((size_t)(E + 4 * (N + 1)) * 4);  // padded
    unsigned* bsum   = (unsigned*)take(4096);
    double*   gsum   = (double*)take(TWOH * 8 * 2); // gsum + gsq contiguous
    double*   gsq    = gsum + TWOH;
    float*    scsh   = (float*)take(2 * TWOH * 4);
    bfraw*    W1hi   = (bfraw*)take((size_t)L * H * TWOH * 2);
    bfraw*    W1lo   = (bfraw*)take((size_t)L * H * TWOH * 2);
    bfraw*    W2hi   = (bfraw*)take((size_t)L * TWOH * H * 2);
    bfraw*    W2lo   = (bfraw*)take((size_t)L * TWOH * H * 2);
    (void)ws_size; (void)n_in; (void)out_size;

    hipMemsetAsync(deg, 0, (size_t)N * 4, stream);
    hipMemsetAsync(xb + (size_t)N * H, 0, H * 2, stream);  // sentinel zero row
    k_input_gemm<<<1024, 256, 0, stream>>>(x, Win, bin, x0, xb, N);
    k_cvtw<<<256, 256, 0, stream>>>(W1s, W2s, W1hi, W1lo, W2hi, W2lo, L * H * TWOH);
    k_hist<<<2048, 256, 0, stream>>>(dst, deg, E);
    const int nb = (N + 1023) / 1024;
    k_scan1<<<nb, 256, 0, stream>>>(deg, indptr, bsum, N);
    k_scan2<<<1, 64, 0, stream>>>(bsum, nb, indptr, N);
    k_scan3<<<nb, 256, 0, stream>>>(indptr, bsum, cursor, N);
    k_csr<<<2048, 256, 0, stream>>>(src, dst, cursor, esrc, E);
    k_pad<<<512, 256, 0, stream>>>(cursor, indptr, esrc, N);

    for (int l = 0; l < L; ++l) {
        hipMemsetAsync(gsum, 0, TWOH * 8 * 2, stream);
        k_agg<<<4096, 256, 0, stream>>>(x0, xb, esrc, indptr, epss + l,
            hprehi, hprelo, N);
        k_gemm1<<<512, 256, 0, stream>>>(hprehi, hprelo,
            W1hi + (size_t)l * H * TWOH, W1lo + (size_t)l * H * TWOH,
            b1s + (size_t)l * TWOH, h1, gsum, gsq, N);
        k_bnfin<<<1, 128, 0, stream>>>(gsum, gsq, gam + (size_t)l * TWOH,
            bet + (size_t)l * TWOH, scsh, N);
        k_bnrelu<<<2048, 256, 0, stream>>>(h1, scsh, yhi, ylo, N * TWOH / 4);
        k_gemm2<<<512, 256, 0, stream>>>(yhi, ylo,
            W2hi + (size_t)l * TWOH * H, W2lo + (size_t)l * TWOH * H,
            b2s + (size_t)l * H, x0, xb, N);
    }

    k_initout<<<1, 64, 0, stream>>>(bout, (float*)d_out);
    k_pool<<<512, 256, 0, stream>>>(x0, batch, Wout, (float*)d_out, N);
}

// Round 7
// 736.669 us; speedup vs baseline: 3.2243x; 1.0817x over previous
//
#include <hip/hip_runtime.h>

#define H 64
#define CIN 32
#define TWOH 128
#define NGRAPH 64

typedef unsigned short bfraw;
typedef short v8s __attribute__((ext_vector_type(8)));
typedef float v4f __attribute__((ext_vector_type(4)));

__device__ __forceinline__ float bf2f(bfraw u) {
    return __uint_as_float(((unsigned)u) << 16);
}
__device__ __forceinline__ bfraw f2bf(float f) {
    unsigned u = __float_as_uint(f);
    unsigned r = (u + 0x7fffu + ((u >> 16) & 1u)) >> 16;  // RNE
    return (bfraw)r;
}
// split fp32 -> hi + lo bf16 (combined rel err ~2^-17)
__device__ __forceinline__ void f2bf2(float f, bfraw& hi, bfraw& lo) {
    hi = f2bf(f);
    lo = f2bf(f - bf2f(hi));
}

// ---------------- input GEMM: x0[N,64] = x[N,32] @ Win + bin ----------------
extern "C" __global__ void __launch_bounds__(256) k_input_gemm(
    const float* __restrict__ x, const float* __restrict__ Win,
    const float* __restrict__ bin, float* __restrict__ x0,
    bfraw* __restrict__ xb, int N)
{
    __shared__ float Wl[CIN * H]; // 8 KB
    for (int i = threadIdx.x; i < CIN * H; i += blockDim.x) Wl[i] = Win[i];
    __syncthreads();
    const int lane = threadIdx.x & 63;
    const int wpb = blockDim.x >> 6;
    int w = blockIdx.x * wpb + (threadIdx.x >> 6);
    const int wstride = gridDim.x * wpb;
    const float bv = bin[lane];
    for (int n = w; n < N; n += wstride) {
        float in = (lane < CIN) ? x[n * CIN + lane] : 0.f;
        float acc = bv;
        #pragma unroll
        for (int k = 0; k < CIN; ++k)
            acc += __shfl(in, k) * Wl[k * H + lane];
        x0[(size_t)n * H + lane] = acc;
        xb[(size_t)n * H + lane] = f2bf(acc);
    }
}

// ---------------- weight conversion to split bf16 (all layers, once) ----------------
extern "C" __global__ void k_cvtw(const float* __restrict__ W1s,
    const float* __restrict__ W2s, bfraw* __restrict__ W1hi,
    bfraw* __restrict__ W1lo, bfraw* __restrict__ W2hi,
    bfraw* __restrict__ W2lo, int total)  // total = L*H*TWOH
{
    int i = blockIdx.x * blockDim.x + threadIdx.x;
    const int st = gridDim.x * blockDim.x;
    for (; i < total; i += st) {
        bfraw h, l;
        f2bf2(W1s[i], h, l); W1hi[i] = h; W1lo[i] = l;
        f2bf2(W2s[i], h, l); W2hi[i] = h; W2lo[i] = l;
    }
}

// ---------------- CSR build (padded to degree multiple of 4) ----------------
extern "C" __global__ void k_hist(const int* __restrict__ dst,
    unsigned* __restrict__ deg, int E)
{
    int i = blockIdx.x * blockDim.x + threadIdx.x;
    const int st = gridDim.x * blockDim.x;
    const int E4 = E >> 2;
    const int4* d4 = (const int4*)dst;
    for (int j = i; j < E4; j += st) {
        const int4 v = d4[j];
        atomicAdd(&deg[v.x], 1u);
        atomicAdd(&deg[v.y], 1u);
        atomicAdd(&deg[v.z], 1u);
        atomicAdd(&deg[v.w], 1u);
    }
    for (int j = (E4 << 2) + i; j < E; j += st) atomicAdd(&deg[dst[j]], 1u);
}

extern "C" __global__ void k_scan1(const unsigned* __restrict__ deg,
    unsigned* __restrict__ indptr, unsigned* __restrict__ bsum, int N)
{
    __shared__ unsigned s[256];
    const int tid = threadIdx.x;
    const int base = blockIdx.x * 1024 + tid * 4;
    unsigned d[4];
    #pragma unroll
    for (int j = 0; j < 4; ++j)
        d[j] = (base + j < N) ? ((deg[base + j] + 3u) & ~3u) : 0u;  // padded
    unsigned t = d[0] + d[1] + d[2] + d[3];
    s[tid] = t;
    __syncthreads();
    for (int o = 1; o < 256; o <<= 1) {
        unsigned v = (tid >= o) ? s[tid - o] : 0u;
        __syncthreads();
        s[tid] += v;
        __syncthreads();
    }
    unsigned run = (tid == 0) ? 0u : s[tid - 1];
    if (tid == 255) bsum[blockIdx.x] = s[255];
    #pragma unroll
    for (int j = 0; j < 4; ++j) {
        if (base + j < N) indptr[base + j] = run;
        run += d[j];
    }
}

extern "C" __global__ void k_scan2(unsigned* bsum, int nb,
    unsigned* __restrict__ indptr, int N)
{
    if (threadIdx.x == 0) {
        unsigned run = 0;
        for (int i = 0; i < nb; ++i) { unsigned v = bsum[i]; bsum[i] = run; run += v; }
        indptr[N] = run;  // total padded edges
    }
}

extern "C" __global__ void k_scan3(unsigned* __restrict__ indptr,
    const unsigned* __restrict__ bsum, unsigned* __restrict__ cursor, int N)
{
    const int base = blockIdx.x * 1024 + threadIdx.x * 4;
    const unsigned boff = bsum[blockIdx.x];
    #pragma unroll
    for (int j = 0; j < 4; ++j) {
        const int idx = base + j;
        if (idx < N) {
            const unsigned v = indptr[idx] + boff;
            indptr[idx] = v;
            cursor[idx] = v;
        }
    }
}

extern "C" __global__ void k_csr(const int* __restrict__ src,
    const int* __restrict__ dst, unsigned* __restrict__ cursor,
    int* __restrict__ esrc, int E)
{
    int i = blockIdx.x * blockDim.x + threadIdx.x;
    const int st = gridDim.x * blockDim.x;
    const int E4 = E >> 2;
    const int4* s4 = (const int4*)src;
    const int4* d4 = (const int4*)dst;
    for (int j = i; j < E4; j += st) {
        const int4 sv = s4[j];
        const int4 dv = d4[j];
        esrc[atomicAdd(&cursor[dv.x], 1u)] = sv.x;
        esrc[atomicAdd(&cursor[dv.y], 1u)] = sv.y;
        esrc[atomicAdd(&cursor[dv.z], 1u)] = sv.z;
        esrc[atomicAdd(&cursor[dv.w], 1u)] = sv.w;
    }
    for (int j = (E4 << 2) + i; j < E; j += st) {
        esrc[atomicAdd(&cursor[dst[j]], 1u)] = src[j];
    }
}

// fill padded slots with sentinel N (zero row)
extern "C" __global__ void k_pad(const unsigned* __restrict__ cursor,
    const unsigned* __restrict__ indptr, int* __restrict__ esrc, int N)
{
    int n = blockIdx.x * blockDim.x + threadIdx.x;
    const int st = gridDim.x * blockDim.x;
    for (; n < N; n += st) {
        const unsigned end = indptr[n + 1];
        for (unsigned p = cursor[n]; p < end; ++p) esrc[p] = N;
    }
}

// ------- gather: hpre = (1+eps)*x0 + sum relu(xb[src]); store split bf16 -------
extern "C" __global__ void __launch_bounds__(256) k_agg(
    const float* __restrict__ x0, const bfraw* __restrict__ xb,
    const int* __restrict__ esrc, const unsigned* __restrict__ indptr,
    const float* __restrict__ epsp, bfraw* __restrict__ hprehi,
    bfraw* __restrict__ hprelo, int N)
{
    const int lane = threadIdx.x & 63;
    const int sub = lane >> 4;          // 0..3 : which edge of the group
    const int fi = (lane & 15) << 2;    // feature base (4 features)
    const int wpb = blockDim.x >> 6;
    int w = blockIdx.x * wpb + (threadIdx.x >> 6);
    const int wstride = gridDim.x * wpb;
    const float ep = 1.f + epsp[0];
    for (int n = w; n < N; n += wstride) {
        const unsigned s0 = indptr[n];
        const unsigned s1 = indptr[n + 1];   // padded: (s1-s0)%4==0
        float a0 = 0.f, a1 = 0.f, a2 = 0.f, a3 = 0.f;
        unsigned e = s0;
        for (; e + 16 <= s1; e += 16) {
            const int i0 = esrc[e + sub];
            const int i1 = esrc[e + 4 + sub];
            const int i2 = esrc[e + 8 + sub];
            const int i3 = esrc[e + 12 + sub];
            const ushort4 r0 = *(const ushort4*)&xb[(size_t)i0 * H + fi];
            const ushort4 r1 = *(const ushort4*)&xb[(size_t)i1 * H + fi];
            const ushort4 r2 = *(const ushort4*)&xb[(size_t)i2 * H + fi];
            const ushort4 r3 = *(const ushort4*)&xb[(size_t)i3 * H + fi];
            a0 += fmaxf(bf2f(r0.x), 0.f) + fmaxf(bf2f(r1.x), 0.f)
                + fmaxf(bf2f(r2.x), 0.f) + fmaxf(bf2f(r3.x), 0.f);
            a1 += fmaxf(bf2f(r0.y), 0.f) + fmaxf(bf2f(r1.y), 0.f)
                + fmaxf(bf2f(r2.y), 0.f) + fmaxf(bf2f(r3.y), 0.f);
            a2 += fmaxf(bf2f(r0.z), 0.f) + fmaxf(bf2f(r1.z), 0.f)
                + fmaxf(bf2f(r2.z), 0.f) + fmaxf(bf2f(r3.z), 0.f);
            a3 += fmaxf(bf2f(r0.w), 0.f) + fmaxf(bf2f(r1.w), 0.f)
                + fmaxf(bf2f(r2.w), 0.f) + fmaxf(bf2f(r3.w), 0.f);
        }
        for (; e < s1; e += 4) {
            const int i0 = esrc[e + sub];
            const ushort4 r0 = *(const ushort4*)&xb[(size_t)i0 * H + fi];
            a0 += fmaxf(bf2f(r0.x), 0.f);
            a1 += fmaxf(bf2f(r0.y), 0.f);
            a2 += fmaxf(bf2f(r0.z), 0.f);
            a3 += fmaxf(bf2f(r0.w), 0.f);
        }
        #pragma unroll
        for (int o = 16; o < 64; o <<= 1) {
            a0 += __shfl_xor(a0, o);
            a1 += __shfl_xor(a1, o);
            a2 += __shfl_xor(a2, o);
            a3 += __shfl_xor(a3, o);
        }
        if (sub == 0) {
            const float4 self = *(const float4*)&x0[(size_t)n * H + fi];
            const float h0 = ep * self.x + a0;
            const float h1v = ep * self.y + a1;
            const float h2 = ep * self.z + a2;
            const float h3 = ep * self.w + a3;
            ushort4 ohi, olo;
            f2bf2(h0, ohi.x, olo.x);
            f2bf2(h1v, ohi.y, olo.y);
            f2bf2(h2, ohi.z, olo.z);
            f2bf2(h3, ohi.w, olo.w);
            *(ushort4*)&hprehi[(size_t)n * H + fi] = ohi;
            *(ushort4*)&hprelo[(size_t)n * H + fi] = olo;
        }
    }
}

// ------------- MFMA GEMM1 + BN stats: h1[N,128] = hpre @ W1 + b1 -------------
// split precision: C = Ahi*Whi + Ahi*Wlo + Alo*Whi. Each wave: half the cols.
extern "C" __global__ void __launch_bounds__(256) k_gemm1(
    const bfraw* __restrict__ hprehi, const bfraw* __restrict__ hprelo,
    const bfraw* __restrict__ W1hi, const bfraw* __restrict__ W1lo,
    const float* __restrict__ b1, float* __restrict__ h1,
    double* __restrict__ gsum, double* __restrict__ gsq, int N)
{
    __shared__ float ss[TWOH], sq[TWOH];
    if (threadIdx.x < TWOH) { ss[threadIdx.x] = 0.f; sq[threadIdx.x] = 0.f; }
    __syncthreads();
    const int lane = threadIdx.x & 63;
    const int row = lane & 15;   // A row / B col / D col
    const int kg  = lane >> 4;   // k-group
    const int wpb = blockDim.x >> 6;
    const int wid = blockIdx.x * wpb + (threadIdx.x >> 6);
    const int wstride = gridDim.x * wpb;
    const int half = wid & 1;          // which 64 of the 128 cols
    const int cb = half * 4;           // col-tile base
    // preload B fragments: 2 k-chunks x 4 col-tiles, hi+lo
    v8s bhi[2][4], blo[2][4];
    #pragma unroll
    for (int kc = 0; kc < 2; ++kc)
        #pragma unroll
        for (int ct = 0; ct < 4; ++ct) {
            v8s bh, bl;
            #pragma unroll
            for (int i = 0; i < 8; ++i) {
                const int idx = (kc * 32 + kg * 8 + i) * TWOH + (cb + ct) * 16 + row;
                bh[i] = (short)W1hi[idx];
                bl[i] = (short)W1lo[idx];
            }
            bhi[kc][ct] = bh; blo[kc][ct] = bl;
        }
    float bcol[4];
    #pragma unroll
    for (int ct = 0; ct < 4; ++ct) bcol[ct] = b1[(cb + ct) * 16 + row];

    const int tiles = (N + 15) >> 4;
    const int tstride = wstride >> 1;
    float sacc[4], qacc[4];
    #pragma unroll
    for (int ct = 0; ct < 4; ++ct) { sacc[ct] = 0.f; qacc[ct] = 0.f; }

    for (int t = wid >> 1; t < tiles; t += tstride) {
        const int tb = t << 4;
        int nA = tb + row; if (nA >= N) nA = N - 1;
        const v8s a0h = *(const v8s*)&hprehi[(size_t)nA * H + kg * 8];
        const v8s a1h = *(const v8s*)&hprehi[(size_t)nA * H + 32 + kg * 8];
        const v8s a0l = *(const v8s*)&hprelo[(size_t)nA * H + kg * 8];
        const v8s a1l = *(const v8s*)&hprelo[(size_t)nA * H + 32 + kg * 8];
        v4f c[4];
        #pragma unroll
        for (int ct = 0; ct < 4; ++ct) {
            v4f cc = (v4f){0.f, 0.f, 0.f, 0.f};
            cc = __builtin_amdgcn_mfma_f32_16x16x32_bf16(a0h, bhi[0][ct], cc, 0, 0, 0);
            cc = __builtin_amdgcn_mfma_f32_16x16x32_bf16(a1h, bhi[1][ct], cc, 0, 0, 0);
            cc = __builtin_amdgcn_mfma_f32_16x16x32_bf16(a0h, blo[0][ct], cc, 0, 0, 0);
            cc = __builtin_amdgcn_mfma_f32_16x16x32_bf16(a1h, blo[1][ct], cc, 0, 0, 0);
            cc = __builtin_amdgcn_mfma_f32_16x16x32_bf16(a0l, bhi[0][ct], cc, 0, 0, 0);
            cc = __builtin_amdgcn_mfma_f32_16x16x32_bf16(a1l, bhi[1][ct], cc, 0, 0, 0);
            c[ct] = cc;
        }
        #pragma unroll
        for (int ct = 0; ct < 4; ++ct) {
            #pragma unroll
            for (int r = 0; r < 4; ++r) {
                const int node = tb + kg * 4 + r;  // D row
                if (node < N) {
                    const float v = c[ct][r] + bcol[ct];
                    h1[(size_t)node * TWOH + (cb + ct) * 16 + row] = v;
                    sacc[ct] += v;
                    qacc[ct] += v * v;
                }
            }
        }
    }
    #pragma unroll
    for (int ct = 0; ct < 4; ++ct) {
        float s = sacc[ct];
        s += __shfl_xor(s, 16); s += __shfl_xor(s, 32);
        float q = qacc[ct];
        q += __shfl_xor(q, 16); q += __shfl_xor(q, 32);
        if (kg == 0) {
            atomicAdd(&ss[(cb + ct) * 16 + row], s);
            atomicAdd(&sq[(cb + ct) * 16 + row], q);
        }
    }
    __syncthreads();
    if (threadIdx.x < TWOH) {
        atomicAdd(&gsum[threadIdx.x], (double)ss[threadIdx.x]);
        atomicAdd(&gsq[threadIdx.x], (double)sq[threadIdx.x]);
    }
}

// ---------------- BN finalize: scale/shift ----------------
extern "C" __global__ void k_bnfin(const double* __restrict__ gsum,
    const double* __restrict__ gsq, const float* __restrict__ gamma,
    const float* __restrict__ beta, float* __restrict__ scsh, int N)
{
    const int j = threadIdx.x;
    if (j < TWOH) {
        const double mu = gsum[j] / N;
        const double var = gsq[j] / N - mu * mu;
        const float sc = gamma[j] * rsqrtf(fmaxf((float)var, 0.f) + 1e-5f);
        scsh[j] = sc;
        scsh[TWOH + j] = beta[j] - (float)mu * sc;
    }
}

// --- MFMA GEMM2 + fused BN/ReLU + residual: x0 += relu(h1*sc+sh) @ W2 + b2 ---
extern "C" __global__ void __launch_bounds__(256) k_gemm2(
    const float* __restrict__ h1, const float* __restrict__ scsh,
    const bfraw* __restrict__ W2hi, const bfraw* __restrict__ W2lo,
    const float* __restrict__ b2, float* __restrict__ x0,
    bfraw* __restrict__ xb, int N)
{
    __shared__ float scl[TWOH], shl[TWOH];  // 1 KB
    for (int i = threadIdx.x; i < TWOH; i += blockDim.x) {
        scl[i] = scsh[i];
        shl[i] = scsh[TWOH + i];
    }
    __syncthreads();
    const int lane = threadIdx.x & 63;
    const int row = lane & 15;
    const int kg  = lane >> 4;
    const int wpb = blockDim.x >> 6;
    const int wid = blockIdx.x * wpb + (threadIdx.x >> 6);
    const int wstride = gridDim.x * wpb;
    const int half = wid & 1;       // which 32 of the 64 cols
    const int cb = half * 2;        // col-tile base
    // preload B fragments: 4 k-chunks x 2 col-tiles, hi+lo
    v8s bhi[4][2], blo[4][2];
    #pragma unroll
    for (int kc = 0; kc < 4; ++kc)
        #pragma unroll
        for (int ct = 0; ct < 2; ++ct) {
            v8s bh, bl;
            #pragma unroll
            for (int i = 0; i < 8; ++i) {
                const int idx = (kc * 32 + kg * 8 + i) * H + (cb + ct) * 16 + row;
                bh[i] = (short)W2hi[idx];
                bl[i] = (short)W2lo[idx];
            }
            bhi[kc][ct] = bh; blo[kc][ct] = bl;
        }
    float bcol[2];
    #pragma unroll
    for (int ct = 0; ct < 2; ++ct) bcol[ct] = b2[(cb + ct) * 16 + row];
    // per-lane BN constants for this lane's 32 features (8 per k-chunk)
    float lsc[4][8], lsh[4][8];
    #pragma unroll
    for (int kc = 0; kc < 4; ++kc) {
        const int fb = kc * 32 + kg * 8;
        #pragma unroll
        for (int i = 0; i < 8; ++i) { lsc[kc][i] = scl[fb + i]; lsh[kc][i] = shl[fb + i]; }
    }

    const int tiles = (N + 15) >> 4;
    const int tstride = wstride >> 1;

    for (int t = wid >> 1; t < tiles; t += tstride) {
        const int tb = t << 4;
        int nA = tb + row; if (nA >= N) nA = N - 1;
        v8s ah[4], al[4];
        #pragma unroll
        for (int kc = 0; kc < 4; ++kc) {
            const int fb = kc * 32 + kg * 8;
            const float4 h0 = *(const float4*)&h1[(size_t)nA * TWOH + fb];
            const float4 h4 = *(const float4*)&h1[(size_t)nA * TWOH + fb + 4];
            float yv[8] = {h0.x, h0.y, h0.z, h0.w, h4.x, h4.y, h4.z, h4.w};
            v8s vh, vl;
            #pragma unroll
            for (int i = 0; i < 8; ++i) {
                const float y = fmaxf(yv[i] * lsc[kc][i] + lsh[kc][i], 0.f);
                bfraw hi, lo;
                f2bf2(y, hi, lo);
                vh[i] = (short)hi;
                vl[i] = (short)lo;
            }
            ah[kc] = vh; al[kc] = vl;
        }
        v4f c[2];
        #pragma unroll
        for (int ct = 0; ct < 2; ++ct) {
            v4f cc = (v4f){0.f, 0.f, 0.f, 0.f};
            #pragma unroll
            for (int kc = 0; kc < 4; ++kc) {
                cc = __builtin_amdgcn_mfma_f32_16x16x32_bf16(ah[kc], bhi[kc][ct], cc, 0, 0, 0);
                cc = __builtin_amdgcn_mfma_f32_16x16x32_bf16(ah[kc], blo[kc][ct], cc, 0, 0, 0);
                cc = __builtin_amdgcn_mfma_f32_16x16x32_bf16(al[kc], bhi[kc][ct], cc, 0, 0, 0);
            }
            c[ct] = cc;
        }
        #pragma unroll
        for (int ct = 0; ct < 2; ++ct) {
            #pragma unroll
            for (int r = 0; r < 4; ++r) {
                const int node = tb + kg * 4 + r;
                if (node < N) {
                    const size_t idx = (size_t)node * H + (cb + ct) * 16 + row;
                    const float v = x0[idx] + c[ct][r] + bcol[ct];
                    x0[idx] = v;
                    xb[idx] = f2bf(v);
                }
            }
        }
    }
}

// ---------------- pooling + output ----------------
extern "C" __global__ void k_initout(const float* __restrict__ bout,
    float* __restrict__ out)
{
    if (threadIdx.x < NGRAPH) out[threadIdx.x] = bout[0];
}

extern "C" __global__ void __launch_bounds__(256) k_pool(
    const float* __restrict__ x0, const int* __restrict__ batch,
    const float* __restrict__ Wout, float* __restrict__ out, int N)
{
    __shared__ float pl[NGRAPH];
    if (threadIdx.x < NGRAPH) pl[threadIdx.x] = 0.f;
    __syncthreads();
    const int lane = threadIdx.x & 63;
    const int wpb = blockDim.x >> 6;
    int w = blockIdx.x * wpb + (threadIdx.x >> 6);
    const int wstride = gridDim.x * wpb;
    const float wv = Wout[lane];
    for (int n = w; n < N; n += wstride) {
        float v = x0[(size_t)n * H + lane] * wv;
        #pragma unroll
        for (int o = 32; o > 0; o >>= 1) v += __shfl_down(v, o);
        if (lane == 0) atomicAdd(&pl[batch[n]], v);
    }
    __syncthreads();
    if (threadIdx.x < NGRAPH) {
        const float v = pl[threadIdx.x];
        if (v != 0.f) atomicAdd(&out[threadIdx.x], v);
    }
}

// ---------------- host driver ----------------
extern "C" void kernel_launch(void* const* d_in, const int* in_sizes, int n_in,
                              void* d_out, int out_size, void* d_ws, size_t ws_size,
                              hipStream_t stream)
{
    const float* x     = (const float*)d_in[0];
    const int*   ei    = (const int*)d_in[1];   // int32 per harness conversion
    const int*   batch = (const int*)d_in[2];   // int32 per harness conversion
    const float* Win   = (const float*)d_in[3];
    const float* bin   = (const float*)d_in[4];
    const float* W1s   = (const float*)d_in[5];
    const float* b1s   = (const float*)d_in[6];
    const float* gam   = (const float*)d_in[7];
    const float* bet   = (const float*)d_in[8];
    const float* W2s   = (const float*)d_in[9];
    const float* b2s   = (const float*)d_in[10];
    const float* epss  = (const float*)d_in[11];
    const float* Wout  = (const float*)d_in[12];
    const float* bout  = (const float*)d_in[13];

    const int N = in_sizes[0] / CIN;
    const int E = in_sizes[1] / 2;
    const int L = in_sizes[11];
    const int* src = ei;
    const int* dst = ei + E;

    // workspace layout
    char* ws = (char*)d_ws;
    size_t off = 0;
    auto take = [&](size_t bytes) {
        void* p = ws + off;
        off += (bytes + 255) & ~(size_t)255;
        return p;
    };
    float*    x0     = (float*)take((size_t)N * H * 4);
    bfraw*    xb     = (bfraw*)take((size_t)(N + 1) * H * 2);  // +1 zero row
    bfraw*    hprehi = (bfraw*)take((size_t)N * H * 2);
    bfraw*    hprelo = (bfraw*)take((size_t)N * H * 2);
    float*    h1     = (float*)take((size_t)N * TWOH * 4);
    unsigned* deg    = (unsigned*)take((size_t)N * 4);
    unsigned* indptr = (unsigned*)take((size_t)(N + 1) * 4);
    unsigned* cursor = (unsigned*)take((size_t)N * 4);
    int*      esrc   = (int*)take((size_t)(E + 4 * (N + 1)) * 4);  // padded
    unsigned* bsum   = (unsigned*)take(4096);
    double*   gsum   = (double*)take(TWOH * 8 * 2); // gsum + gsq contiguous
    double*   gsq    = gsum + TWOH;
    float*    scsh   = (float*)take(2 * TWOH * 4);
    bfraw*    W1hi   = (bfraw*)take((size_t)L * H * TWOH * 2);
    bfraw*    W1lo   = (bfraw*)take((size_t)L * H * TWOH * 2);
    bfraw*    W2hi   = (bfraw*)take((size_t)L * TWOH * H * 2);
    bfraw*    W2lo   = (bfraw*)take((size_t)L * TWOH * H * 2);
    (void)ws_size; (void)n_in; (void)out_size;

    hipMemsetAsync(deg, 0, (size_t)N * 4, stream);
    hipMemsetAsync(xb + (size_t)N * H, 0, H * 2, stream);  // sentinel zero row
    k_input_gemm<<<1024, 256, 0, stream>>>(x, Win, bin, x0, xb, N);
    k_cvtw<<<256, 256, 0, stream>>>(W1s, W2s, W1hi, W1lo, W2hi, W2lo, L * H * TWOH);
    k_hist<<<2048, 256, 0, stream>>>(dst, deg, E);
    const int nb = (N + 1023) / 1024;
    k_scan1<<<nb, 256, 0, stream>>>(deg, indptr, bsum, N);
    k_scan2<<<1, 64, 0, stream>>>(bsum, nb, indptr, N);
    k_scan3<<<nb, 256, 0, stream>>>(indptr, bsum, cursor, N);
    k_csr<<<2048, 256, 0, stream>>>(src, dst, cursor, esrc, E);
    k_pad<<<512, 256, 0, stream>>>(cursor, indptr, esrc, N);

    for (int l = 0; l < L; ++l) {
        hipMemsetAsync(gsum, 0, TWOH * 8 * 2, stream);
        k_agg<<<4096, 256, 0, stream>>>(x0, xb, esrc, indptr, epss + l,
            hprehi, hprelo, N);
        k_gemm1<<<512, 256, 0, stream>>>(hprehi, hprelo,
            W1hi + (size_t)l * H * TWOH, W1lo + (size_t)l * H * TWOH,
            b1s + (size_t)l * TWOH, h1, gsum, gsq, N);
        k_bnfin<<<1, 128, 0, stream>>>(gsum, gsq, gam + (size_t)l * TWOH,
            bet + (size_t)l * TWOH, scsh, N);
        k_gemm2<<<512, 256, 0, stream>>>(h1, scsh,
            W2hi + (size_t)l * TWOH * H, W2lo + (size_t)l * TWOH * H,
            b2s + (size_t)l * H, x0, xb, N);
    }

    k_initout<<<1, 64, 0, stream>>>(bout, (float*)d_out);
    k_pool<<<512, 256, 0, stream>>>(x0, batch, Wout, (float*)d_out, N);
}

// Round 8
// 646.357 us; speedup vs baseline: 3.6748x; 1.1397x over previous
//
#include <hip/hip_runtime.h>

#define H 64
#define CIN 32
#define TWOH 128
#define NGRAPH 64

// bucketed CSR build
#define BSH 7
#define BNODE 128
#define NSUB 8
#define BCAP_SUB 512
#define OCAP 65536

typedef unsigned short bfraw;
typedef short v8s __attribute__((ext_vector_type(8)));
typedef float v4f __attribute__((ext_vector_type(4)));

__device__ __forceinline__ float bf2f(bfraw u) {
    return __uint_as_float(((unsigned)u) << 16);
}
__device__ __forceinline__ bfraw f2bf(float f) {
    unsigned u = __float_as_uint(f);
    unsigned r = (u + 0x7fffu + ((u >> 16) & 1u)) >> 16;  // RNE
    return (bfraw)r;
}
// split fp32 -> hi + lo bf16 (combined rel err ~2^-17)
__device__ __forceinline__ void f2bf2(float f, bfraw& hi, bfraw& lo) {
    hi = f2bf(f);
    lo = f2bf(f - bf2f(hi));
}

// ---------------- input GEMM: x0[N,64] = x[N,32] @ Win + bin ----------------
extern "C" __global__ void __launch_bounds__(256) k_input_gemm(
    const float* __restrict__ x, const float* __restrict__ Win,
    const float* __restrict__ bin, float* __restrict__ x0,
    bfraw* __restrict__ xb, int N)
{
    __shared__ float Wl[CIN * H]; // 8 KB
    for (int i = threadIdx.x; i < CIN * H; i += blockDim.x) Wl[i] = Win[i];
    __syncthreads();
    const int lane = threadIdx.x & 63;
    const int wpb = blockDim.x >> 6;
    int w = blockIdx.x * wpb + (threadIdx.x >> 6);
    const int wstride = gridDim.x * wpb;
    const float bv = bin[lane];
    for (int n = w; n < N; n += wstride) {
        float in = (lane < CIN) ? x[n * CIN + lane] : 0.f;
        float acc = bv;
        #pragma unroll
        for (int k = 0; k < CIN; ++k)
            acc += __shfl(in, k) * Wl[k * H + lane];
        x0[(size_t)n * H + lane] = acc;
        xb[(size_t)n * H + lane] = f2bf(acc);
    }
}

// ---------------- weight conversion to split bf16 (all layers, once) ----------------
extern "C" __global__ void k_cvtw(const float* __restrict__ W1s,
    const float* __restrict__ W2s, bfraw* __restrict__ W1hi,
    bfraw* __restrict__ W1lo, bfraw* __restrict__ W2hi,
    bfraw* __restrict__ W2lo, int total)  // total = L*H*TWOH
{
    int i = blockIdx.x * blockDim.x + threadIdx.x;
    const int st = gridDim.x * blockDim.x;
    for (; i < total; i += st) {
        bfraw h, l;
        f2bf2(W1s[i], h, l); W1hi[i] = h; W1lo[i] = l;
        f2bf2(W2s[i], h, l); W2hi[i] = h; W2lo[i] = l;
    }
}

// ---------------- bucketed edge partition (pass A) ----------------
__device__ __forceinline__ void bput(int s, int d,
    unsigned* __restrict__ bcnt, unsigned* __restrict__ btmp,
    unsigned* __restrict__ deg, int* __restrict__ oflow,
    unsigned* __restrict__ ocnt, int sub)
{
    const unsigned slot = (unsigned)((d >> BSH) * NSUB + sub);
    const unsigned pos = atomicAdd(&bcnt[slot], 1u);
    if (pos < BCAP_SUB) {
        btmp[slot * BCAP_SUB + pos] = (unsigned)s | ((unsigned)(d & (BNODE - 1)) << 20);
    } else {
        const unsigned o = atomicAdd(ocnt, 1u);
        if (o < OCAP) {
            oflow[2 * o] = s; oflow[2 * o + 1] = d;
            atomicAdd(&deg[d], 1u);
        }
    }
}

extern "C" __global__ void __launch_bounds__(256) k_bucket(
    const int* __restrict__ src, const int* __restrict__ dst,
    unsigned* __restrict__ bcnt, unsigned* __restrict__ btmp,
    unsigned* __restrict__ deg, int* __restrict__ oflow,
    unsigned* __restrict__ ocnt, int E)
{
    const int tid0 = blockIdx.x * blockDim.x + threadIdx.x;
    const int st = gridDim.x * blockDim.x;
    const int sub = (blockIdx.x ^ (threadIdx.x >> 5)) & (NSUB - 1);
    const int E4 = E >> 2;
    const int4* s4 = (const int4*)src;
    const int4* d4 = (const int4*)dst;
    for (int j = tid0; j < E4; j += st) {
        const int4 sv = s4[j];
        const int4 dv = d4[j];
        bput(sv.x, dv.x, bcnt, btmp, deg, oflow, ocnt, sub);
        bput(sv.y, dv.y, bcnt, btmp, deg, oflow, ocnt, sub);
        bput(sv.z, dv.z, bcnt, btmp, deg, oflow, ocnt, sub);
        bput(sv.w, dv.w, bcnt, btmp, deg, oflow, ocnt, sub);
    }
    for (int j = (E4 << 2) + tid0; j < E; j += st)
        bput(src[j], dst[j], bcnt, btmp, deg, oflow, ocnt, sub);
}

// ---------------- per-bucket degree histogram (replaces k_hist) ----------------
extern "C" __global__ void __launch_bounds__(256) k_bhist(
    const unsigned* __restrict__ bcnt, const unsigned* __restrict__ btmp,
    unsigned* __restrict__ deg, int N)
{
    __shared__ unsigned hist[BNODE];
    const int b = blockIdx.x;
    for (int i = threadIdx.x; i < BNODE; i += blockDim.x) hist[i] = 0u;
    __syncthreads();
    #pragma unroll
    for (int s = 0; s < NSUB; ++s) {
        const unsigned slot = (unsigned)(b * NSUB + s);
        unsigned cnt = bcnt[slot]; if (cnt > BCAP_SUB) cnt = BCAP_SUB;
        for (unsigned j = threadIdx.x; j < cnt; j += blockDim.x)
            atomicAdd(&hist[btmp[slot * BCAP_SUB + j] >> 20], 1u);
    }
    __syncthreads();
    const int base = b << BSH;
    for (int i = threadIdx.x; i < BNODE; i += blockDim.x)
        if (base + i < N) {
            const unsigned h = hist[i];
            if (h) atomicAdd(&deg[base + i], h);
        }
}

extern "C" __global__ void k_scan1(const unsigned* __restrict__ deg,
    unsigned* __restrict__ indptr, unsigned* __restrict__ bsum, int N)
{
    __shared__ unsigned s[256];
    const int tid = threadIdx.x;
    const int base = blockIdx.x * 1024 + tid * 4;
    unsigned d[4];
    #pragma unroll
    for (int j = 0; j < 4; ++j)
        d[j] = (base + j < N) ? ((deg[base + j] + 3u) & ~3u) : 0u;  // padded
    unsigned t = d[0] + d[1] + d[2] + d[3];
    s[tid] = t;
    __syncthreads();
    for (int o = 1; o < 256; o <<= 1) {
        unsigned v = (tid >= o) ? s[tid - o] : 0u;
        __syncthreads();
        s[tid] += v;
        __syncthreads();
    }
    unsigned run = (tid == 0) ? 0u : s[tid - 1];
    if (tid == 255) bsum[blockIdx.x] = s[255];
    #pragma unroll
    for (int j = 0; j < 4; ++j) {
        if (base + j < N) indptr[base + j] = run;
        run += d[j];
    }
}

extern "C" __global__ void k_scan2(unsigned* bsum, int nb,
    unsigned* __restrict__ indptr, int N)
{
    if (threadIdx.x == 0) {
        unsigned run = 0;
        for (int i = 0; i < nb; ++i) { unsigned v = bsum[i]; bsum[i] = run; run += v; }
        indptr[N] = run;  // total padded edges
    }
}

extern "C" __global__ void k_scan3(unsigned* __restrict__ indptr,
    const unsigned* __restrict__ bsum, unsigned* __restrict__ cursor, int N)
{
    const int base = blockIdx.x * 1024 + threadIdx.x * 4;
    const unsigned boff = bsum[blockIdx.x];
    #pragma unroll
    for (int j = 0; j < 4; ++j) {
        const int idx = base + j;
        if (idx < N) {
            const unsigned v = indptr[idx] + boff;
            indptr[idx] = v;
            cursor[idx] = v;
        }
    }
}

// ---------------- per-bucket scatter to final CSR (pass B) ----------------
extern "C" __global__ void __launch_bounds__(256) k_bscat(
    const unsigned* __restrict__ bcnt, const unsigned* __restrict__ btmp,
    const unsigned* __restrict__ indptr, unsigned* __restrict__ cursor,
    int* __restrict__ esrc, int N)
{
    __shared__ unsigned lcur[BNODE];
    const int b = blockIdx.x;
    const int base = b << BSH;
    for (int i = threadIdx.x; i < BNODE; i += blockDim.x)
        lcur[i] = (base + i < N) ? indptr[base + i] : 0u;
    __syncthreads();
    #pragma unroll
    for (int s = 0; s < NSUB; ++s) {
        const unsigned slot = (unsigned)(b * NSUB + s);
        unsigned cnt = bcnt[slot]; if (cnt > BCAP_SUB) cnt = BCAP_SUB;
        for (unsigned j = threadIdx.x; j < cnt; j += blockDim.x) {
            const unsigned e = btmp[slot * BCAP_SUB + j];
            const unsigned pos = atomicAdd(&lcur[e >> 20], 1u);
            esrc[pos] = (int)(e & 0xFFFFFu);
        }
    }
    __syncthreads();
    for (int i = threadIdx.x; i < BNODE; i += blockDim.x)
        if (base + i < N) cursor[base + i] = lcur[i];
}

// overflow edges (expected none) via global cursor
extern "C" __global__ void k_over(const int* __restrict__ oflow,
    const unsigned* __restrict__ ocnt, unsigned* __restrict__ cursor,
    int* __restrict__ esrc)
{
    unsigned n = *ocnt; if (n > OCAP) n = OCAP;
    int i = blockIdx.x * blockDim.x + threadIdx.x;
    const int st = gridDim.x * blockDim.x;
    for (; (unsigned)i < n; i += st) {
        const int s = oflow[2 * i], d = oflow[2 * i + 1];
        const unsigned pos = atomicAdd(&cursor[d], 1u);
        esrc[pos] = s;
    }
}

// fill padded slots with sentinel N (zero row)
extern "C" __global__ void k_pad(const unsigned* __restrict__ cursor,
    const unsigned* __restrict__ indptr, int* __restrict__ esrc, int N)
{
    int n = blockIdx.x * blockDim.x + threadIdx.x;
    const int st = gridDim.x * blockDim.x;
    for (; n < N; n += st) {
        const unsigned end = indptr[n + 1];
        for (unsigned p = cursor[n]; p < end; ++p) esrc[p] = N;
    }
}

// ------- gather: hpre = (1+eps)*x0 + sum relu(xb[src]); store split bf16 -------
extern "C" __global__ void __launch_bounds__(256) k_agg(
    const float* __restrict__ x0, const bfraw* __restrict__ xb,
    const int* __restrict__ esrc, const unsigned* __restrict__ indptr,
    const float* __restrict__ epsp, bfraw* __restrict__ hprehi,
    bfraw* __restrict__ hprelo, int N)
{
    const int lane = threadIdx.x & 63;
    const int sub = lane >> 4;          // 0..3 : which edge of the group
    const int fi = (lane & 15) << 2;    // feature base (4 features)
    const int wpb = blockDim.x >> 6;
    int w = blockIdx.x * wpb + (threadIdx.x >> 6);
    const int wstride = gridDim.x * wpb;
    const float ep = 1.f + epsp[0];
    for (int n = w; n < N; n += wstride) {
        const unsigned s0 = indptr[n];
        const unsigned s1 = indptr[n + 1];   // padded: (s1-s0)%4==0
        float a0 = 0.f, a1 = 0.f, a2 = 0.f, a3 = 0.f;
        unsigned e = s0;
        for (; e + 16 <= s1; e += 16) {
            const int i0 = esrc[e + sub];
            const int i1 = esrc[e + 4 + sub];
            const int i2 = esrc[e + 8 + sub];
            const int i3 = esrc[e + 12 + sub];
            const ushort4 r0 = *(const ushort4*)&xb[(size_t)i0 * H + fi];
            const ushort4 r1 = *(const ushort4*)&xb[(size_t)i1 * H + fi];
            const ushort4 r2 = *(const ushort4*)&xb[(size_t)i2 * H + fi];
            const ushort4 r3 = *(const ushort4*)&xb[(size_t)i3 * H + fi];
            a0 += fmaxf(bf2f(r0.x), 0.f) + fmaxf(bf2f(r1.x), 0.f)
                + fmaxf(bf2f(r2.x), 0.f) + fmaxf(bf2f(r3.x), 0.f);
            a1 += fmaxf(bf2f(r0.y), 0.f) + fmaxf(bf2f(r1.y), 0.f)
                + fmaxf(bf2f(r2.y), 0.f) + fmaxf(bf2f(r3.y), 0.f);
            a2 += fmaxf(bf2f(r0.z), 0.f) + fmaxf(bf2f(r1.z), 0.f)
                + fmaxf(bf2f(r2.z), 0.f) + fmaxf(bf2f(r3.z), 0.f);
            a3 += fmaxf(bf2f(r0.w), 0.f) + fmaxf(bf2f(r1.w), 0.f)
                + fmaxf(bf2f(r2.w), 0.f) + fmaxf(bf2f(r3.w), 0.f);
        }
        for (; e < s1; e += 4) {
            const int i0 = esrc[e + sub];
            const ushort4 r0 = *(const ushort4*)&xb[(size_t)i0 * H + fi];
            a0 += fmaxf(bf2f(r0.x), 0.f);
            a1 += fmaxf(bf2f(r0.y), 0.f);
            a2 += fmaxf(bf2f(r0.z), 0.f);
            a3 += fmaxf(bf2f(r0.w), 0.f);
        }
        #pragma unroll
        for (int o = 16; o < 64; o <<= 1) {
            a0 += __shfl_xor(a0, o);
            a1 += __shfl_xor(a1, o);
            a2 += __shfl_xor(a2, o);
            a3 += __shfl_xor(a3, o);
        }
        if (sub == 0) {
            const float4 self = *(const float4*)&x0[(size_t)n * H + fi];
            const float h0 = ep * self.x + a0;
            const float h1v = ep * self.y + a1;
            const float h2 = ep * self.z + a2;
            const float h3 = ep * self.w + a3;
            ushort4 ohi, olo;
            f2bf2(h0, ohi.x, olo.x);
            f2bf2(h1v, ohi.y, olo.y);
            f2bf2(h2, ohi.z, olo.z);
            f2bf2(h3, ohi.w, olo.w);
            *(ushort4*)&hprehi[(size_t)n * H + fi] = ohi;
            *(ushort4*)&hprelo[(size_t)n * H + fi] = olo;
        }
    }
}

// ------------- MFMA GEMM1 + BN stats: h1[N,128] = hpre @ W1 + b1 -------------
// split precision: C = Ahi*Whi + Ahi*Wlo + Alo*Whi. Each wave: half the cols.
extern "C" __global__ void __launch_bounds__(256) k_gemm1(
    const bfraw* __restrict__ hprehi, const bfraw* __restrict__ hprelo,
    const bfraw* __restrict__ W1hi, const bfraw* __restrict__ W1lo,
    const float* __restrict__ b1, float* __restrict__ h1,
    double* __restrict__ gsum, double* __restrict__ gsq, int N)
{
    __shared__ float ss[TWOH], sq[TWOH];
    if (threadIdx.x < TWOH) { ss[threadIdx.x] = 0.f; sq[threadIdx.x] = 0.f; }
    __syncthreads();
    const int lane = threadIdx.x & 63;
    const int row = lane & 15;   // A row / B col / D col
    const int kg  = lane >> 4;   // k-group
    const int wpb = blockDim.x >> 6;
    const int wid = blockIdx.x * wpb + (threadIdx.x >> 6);
    const int wstride = gridDim.x * wpb;
    const int half = wid & 1;          // which 64 of the 128 cols
    const int cb = half * 4;           // col-tile base
    // preload B fragments: 2 k-chunks x 4 col-tiles, hi+lo
    v8s bhi[2][4], blo[2][4];
    #pragma unroll
    for (int kc = 0; kc < 2; ++kc)
        #pragma unroll
        for (int ct = 0; ct < 4; ++ct) {
            v8s bh, bl;
            #pragma unroll
            for (int i = 0; i < 8; ++i) {
                const int idx = (kc * 32 + kg * 8 + i) * TWOH + (cb + ct) * 16 + row;
                bh[i] = (short)W1hi[idx];
                bl[i] = (short)W1lo[idx];
            }
            bhi[kc][ct] = bh; blo[kc][ct] = bl;
        }
    float bcol[4];
    #pragma unroll
    for (int ct = 0; ct < 4; ++ct) bcol[ct] = b1[(cb + ct) * 16 + row];

    const int tiles = (N + 15) >> 4;
    const int tstride = wstride >> 1;
    float sacc[4], qacc[4];
    #pragma unroll
    for (int ct = 0; ct < 4; ++ct) { sacc[ct] = 0.f; qacc[ct] = 0.f; }

    for (int t = wid >> 1; t < tiles; t += tstride) {
        const int tb = t << 4;
        int nA = tb + row; if (nA >= N) nA = N - 1;
        const v8s a0h = *(const v8s*)&hprehi[(size_t)nA * H + kg * 8];
        const v8s a1h = *(const v8s*)&hprehi[(size_t)nA * H + 32 + kg * 8];
        const v8s a0l = *(const v8s*)&hprelo[(size_t)nA * H + kg * 8];
        const v8s a1l = *(const v8s*)&hprelo[(size_t)nA * H + 32 + kg * 8];
        v4f c[4];
        #pragma unroll
        for (int ct = 0; ct < 4; ++ct) {
            v4f cc = (v4f){0.f, 0.f, 0.f, 0.f};
            cc = __builtin_amdgcn_mfma_f32_16x16x32_bf16(a0h, bhi[0][ct], cc, 0, 0, 0);
            cc = __builtin_amdgcn_mfma_f32_16x16x32_bf16(a1h, bhi[1][ct], cc, 0, 0, 0);
            cc = __builtin_amdgcn_mfma_f32_16x16x32_bf16(a0h, blo[0][ct], cc, 0, 0, 0);
            cc = __builtin_amdgcn_mfma_f32_16x16x32_bf16(a1h, blo[1][ct], cc, 0, 0, 0);
            cc = __builtin_amdgcn_mfma_f32_16x16x32_bf16(a0l, bhi[0][ct], cc, 0, 0, 0);
            cc = __builtin_amdgcn_mfma_f32_16x16x32_bf16(a1l, bhi[1][ct], cc, 0, 0, 0);
            c[ct] = cc;
        }
        #pragma unroll
        for (int ct = 0; ct < 4; ++ct) {
            #pragma unroll
            for (int r = 0; r < 4; ++r) {
                const int node = tb + kg * 4 + r;  // D row
                if (node < N) {
                    const float v = c[ct][r] + bcol[ct];
                    h1[(size_t)node * TWOH + (cb + ct) * 16 + row] = v;
                    sacc[ct] += v;
                    qacc[ct] += v * v;
                }
            }
        }
    }
    #pragma unroll
    for (int ct = 0; ct < 4; ++ct) {
        float s = sacc[ct];
        s += __shfl_xor(s, 16); s += __shfl_xor(s, 32);
        float q = qacc[ct];
        q += __shfl_xor(q, 16); q += __shfl_xor(q, 32);
        if (kg == 0) {
            atomicAdd(&ss[(cb + ct) * 16 + row], s);
            atomicAdd(&sq[(cb + ct) * 16 + row], q);
        }
    }
    __syncthreads();
    if (threadIdx.x < TWOH) {
        atomicAdd(&gsum[threadIdx.x], (double)ss[threadIdx.x]);
        atomicAdd(&gsq[threadIdx.x], (double)sq[threadIdx.x]);
    }
}

// ---------------- BN finalize: scale/shift ----------------
extern "C" __global__ void k_bnfin(const double* __restrict__ gsum,
    const double* __restrict__ gsq, const float* __restrict__ gamma,
    const float* __restrict__ beta, float* __restrict__ scsh, int N)
{
    const int j = threadIdx.x;
    if (j < TWOH) {
        const double mu = gsum[j] / N;
        const double var = gsq[j] / N - mu * mu;
        const float sc = gamma[j] * rsqrtf(fmaxf((float)var, 0.f) + 1e-5f);
        scsh[j] = sc;
        scsh[TWOH + j] = beta[j] - (float)mu * sc;
    }
}

// --- MFMA GEMM2 + fused BN/ReLU + residual: x0 += relu(h1*sc+sh) @ W2 + b2 ---
extern "C" __global__ void __launch_bounds__(256) k_gemm2(
    const float* __restrict__ h1, const float* __restrict__ scsh,
    const bfraw* __restrict__ W2hi, const bfraw* __restrict__ W2lo,
    const float* __restrict__ b2, float* __restrict__ x0,
    bfraw* __restrict__ xb, int N)
{
    __shared__ float scl[TWOH], shl[TWOH];  // 1 KB
    for (int i = threadIdx.x; i < TWOH; i += blockDim.x) {
        scl[i] = scsh[i];
        shl[i] = scsh[TWOH + i];
    }
    __syncthreads();
    const int lane = threadIdx.x & 63;
    const int row = lane & 15;
    const int kg  = lane >> 4;
    const int wpb = blockDim.x >> 6;
    const int wid = blockIdx.x * wpb + (threadIdx.x >> 6);
    const int wstride = gridDim.x * wpb;
    const int half = wid & 1;       // which 32 of the 64 cols
    const int cb = half * 2;        // col-tile base
    // preload B fragments: 4 k-chunks x 2 col-tiles, hi+lo
    v8s bhi[4][2], blo[4][2];
    #pragma unroll
    for (int kc = 0; kc < 4; ++kc)
        #pragma unroll
        for (int ct = 0; ct < 2; ++ct) {
            v8s bh, bl;
            #pragma unroll
            for (int i = 0; i < 8; ++i) {
                const int idx = (kc * 32 + kg * 8 + i) * H + (cb + ct) * 16 + row;
                bh[i] = (short)W2hi[idx];
                bl[i] = (short)W2lo[idx];
            }
            bhi[kc][ct] = bh; blo[kc][ct] = bl;
        }
    float bcol[2];
    #pragma unroll
    for (int ct = 0; ct < 2; ++ct) bcol[ct] = b2[(cb + ct) * 16 + row];
    // per-lane BN constants for this lane's 32 features (8 per k-chunk)
    float lsc[4][8], lsh[4][8];
    #pragma unroll
    for (int kc = 0; kc < 4; ++kc) {
        const int fb = kc * 32 + kg * 8;
        #pragma unroll
        for (int i = 0; i < 8; ++i) { lsc[kc][i] = scl[fb + i]; lsh[kc][i] = shl[fb + i]; }
    }

    const int tiles = (N + 15) >> 4;
    const int tstride = wstride >> 1;

    for (int t = wid >> 1; t < tiles; t += tstride) {
        const int tb = t << 4;
        int nA = tb + row; if (nA >= N) nA = N - 1;
        v8s ah[4], al[4];
        #pragma unroll
        for (int kc = 0; kc < 4; ++kc) {
            const int fb = kc * 32 + kg * 8;
            const float4 h0 = *(const float4*)&h1[(size_t)nA * TWOH + fb];
            const float4 h4 = *(const float4*)&h1[(size_t)nA * TWOH + fb + 4];
            float yv[8] = {h0.x, h0.y, h0.z, h0.w, h4.x, h4.y, h4.z, h4.w};
            v8s vh, vl;
            #pragma unroll
            for (int i = 0; i < 8; ++i) {
                const float y = fmaxf(yv[i] * lsc[kc][i] + lsh[kc][i], 0.f);
                bfraw hi, lo;
                f2bf2(y, hi, lo);
                vh[i] = (short)hi;
                vl[i] = (short)lo;
            }
            ah[kc] = vh; al[kc] = vl;
        }
        v4f c[2];
        #pragma unroll
        for (int ct = 0; ct < 2; ++ct) {
            v4f cc = (v4f){0.f, 0.f, 0.f, 0.f};
            #pragma unroll
            for (int kc = 0; kc < 4; ++kc) {
                cc = __builtin_amdgcn_mfma_f32_16x16x32_bf16(ah[kc], bhi[kc][ct], cc, 0, 0, 0);
                cc = __builtin_amdgcn_mfma_f32_16x16x32_bf16(ah[kc], blo[kc][ct], cc, 0, 0, 0);
                cc = __builtin_amdgcn_mfma_f32_16x16x32_bf16(al[kc], bhi[kc][ct], cc, 0, 0, 0);
            }
            c[ct] = cc;
        }
        #pragma unroll
        for (int ct = 0; ct < 2; ++ct) {
            #pragma unroll
            for (int r = 0; r < 4; ++r) {
                const int node = tb + kg * 4 + r;
                if (node < N) {
                    const size_t idx = (size_t)node * H + (cb + ct) * 16 + row;
                    const float v = x0[idx] + c[ct][r] + bcol[ct];
                    x0[idx] = v;
                    xb[idx] = f2bf(v);
                }
            }
        }
    }
}

// ---------------- pooling + output ----------------
extern "C" __global__ void k_initout(const float* __restrict__ bout,
    float* __restrict__ out)
{
    if (threadIdx.x < NGRAPH) out[threadIdx.x] = bout[0];
}

extern "C" __global__ void __launch_bounds__(256) k_pool(
    const float* __restrict__ x0, const int* __restrict__ batch,
    const float* __restrict__ Wout, float* __restrict__ out, int N)
{
    __shared__ float pl[NGRAPH];
    if (threadIdx.x < NGRAPH) pl[threadIdx.x] = 0.f;
    __syncthreads();
    const int lane = threadIdx.x & 63;
    const int wpb = blockDim.x >> 6;
    int w = blockIdx.x * wpb + (threadIdx.x >> 6);
    const int wstride = gridDim.x * wpb;
    const float wv = Wout[lane];
    for (int n = w; n < N; n += wstride) {
        float v = x0[(size_t)n * H + lane] * wv;
        #pragma unroll
        for (int o = 32; o > 0; o >>= 1) v += __shfl_down(v, o);
        if (lane == 0) atomicAdd(&pl[batch[n]], v);
    }
    __syncthreads();
    if (threadIdx.x < NGRAPH) {
        const float v = pl[threadIdx.x];
        if (v != 0.f) atomicAdd(&out[threadIdx.x], v);
    }
}

// ---------------- host driver ----------------
extern "C" void kernel_launch(void* const* d_in, const int* in_sizes, int n_in,
                              void* d_out, int out_size, void* d_ws, size_t ws_size,
                              hipStream_t stream)
{
    const float* x     = (const float*)d_in[0];
    const int*   ei    = (const int*)d_in[1];   // int32 per harness conversion
    const int*   batch = (const int*)d_in[2];   // int32 per harness conversion
    const float* Win   = (const float*)d_in[3];
    const float* bin   = (const float*)d_in[4];
    const float* W1s   = (const float*)d_in[5];
    const float* b1s   = (const float*)d_in[6];
    const float* gam   = (const float*)d_in[7];
    const float* bet   = (const float*)d_in[8];
    const float* W2s   = (const float*)d_in[9];
    const float* b2s   = (const float*)d_in[10];
    const float* epss  = (const float*)d_in[11];
    const float* Wout  = (const float*)d_in[12];
    const float* bout  = (const float*)d_in[13];

    const int N = in_sizes[0] / CIN;
    const int E = in_sizes[1] / 2;
    const int L = in_sizes[11];
    const int* src = ei;
    const int* dst = ei + E;
    const int NB = (N + BNODE - 1) >> BSH;

    // workspace layout
    char* ws = (char*)d_ws;
    size_t off = 0;
    auto take = [&](size_t bytes) {
        void* p = ws + off;
        off += (bytes + 255) & ~(size_t)255;
        return p;
    };
    float*    x0     = (float*)take((size_t)N * H * 4);
    bfraw*    xb     = (bfraw*)take((size_t)(N + 1) * H * 2);  // +1 zero row
    bfraw*    hprehi = (bfraw*)take((size_t)N * H * 2);
    bfraw*    hprelo = (bfraw*)take((size_t)N * H * 2);
    float*    h1     = (float*)take((size_t)N * TWOH * 4);
    unsigned* deg    = (unsigned*)take((size_t)N * 4);
    unsigned* indptr = (unsigned*)take((size_t)(N + 1) * 4);
    unsigned* cursor = (unsigned*)take((size_t)N * 4);
    int*      esrc   = (int*)take((size_t)(E + 4 * (N + 1)) * 4);  // padded
    unsigned* bsum   = (unsigned*)take(4096);
    double*   gsum   = (double*)take(TWOH * 8 * 2); // gsum + gsq contiguous
    double*   gsq    = gsum + TWOH;
    float*    scsh   = (float*)take(2 * TWOH * 4);
    bfraw*    W1hi   = (bfraw*)take((size_t)L * H * TWOH * 2);
    bfraw*    W1lo   = (bfraw*)take((size_t)L * H * TWOH * 2);
    bfraw*    W2hi   = (bfraw*)take((size_t)L * TWOH * H * 2);
    bfraw*    W2lo   = (bfraw*)take((size_t)L * TWOH * H * 2);
    unsigned* bcnt   = (unsigned*)take((size_t)NB * NSUB * 4);
    unsigned* btmp   = (unsigned*)take((size_t)NB * NSUB * BCAP_SUB * 4);
    int*      oflow  = (int*)take((size_t)OCAP * 2 * 4);
    unsigned* ocnt   = (unsigned*)take(256);
    (void)ws_size; (void)n_in; (void)out_size;

    hipMemsetAsync(deg, 0, (size_t)N * 4, stream);
    hipMemsetAsync(bcnt, 0, (size_t)NB * NSUB * 4, stream);
    hipMemsetAsync(ocnt, 0, 4, stream);
    hipMemsetAsync(xb + (size_t)N * H, 0, H * 2, stream);  // sentinel zero row
    k_input_gemm<<<1024, 256, 0, stream>>>(x, Win, bin, x0, xb, N);
    k_cvtw<<<256, 256, 0, stream>>>(W1s, W2s, W1hi, W1lo, W2hi, W2lo, L * H * TWOH);
    k_bucket<<<2048, 256, 0, stream>>>(src, dst, bcnt, btmp, deg, oflow, ocnt, E);
    k_bhist<<<NB, 256, 0, stream>>>(bcnt, btmp, deg, N);
    const int nb = (N + 1023) / 1024;
    k_scan1<<<nb, 256, 0, stream>>>(deg, indptr, bsum, N);
    k_scan2<<<1, 64, 0, stream>>>(bsum, nb, indptr, N);
    k_scan3<<<nb, 256, 0, stream>>>(indptr, bsum, cursor, N);
    k_bscat<<<NB, 256, 0, stream>>>(bcnt, btmp, indptr, cursor, esrc, N);
    k_over<<<32, 256, 0, stream>>>(oflow, ocnt, cursor, esrc);
    k_pad<<<512, 256, 0, stream>>>(cursor, indptr, esrc, N);

    for (int l = 0; l < L; ++l) {
        hipMemsetAsync(gsum, 0, TWOH * 8 * 2, stream);
        k_agg<<<4096, 256, 0, stream>>>(x0, xb, esrc, indptr, epss + l,
            hprehi, hprelo, N);
        k_gemm1<<<512, 256, 0, stream>>>(hprehi, hprelo,
            W1hi + (size_t)l * H * TWOH, W1lo + (size_t)l * H * TWOH,
            b1s + (size_t)l * TWOH, h1, gsum, gsq, N);
        k_bnfin<<<1, 128, 0, stream>>>(gsum, gsq, gam + (size_t)l * TWOH,
            bet + (size_t)l * TWOH, scsh, N);
        k_gemm2<<<512, 256, 0, stream>>>(h1, scsh,
            W2hi + (size_t)l * TWOH * H, W2lo + (size_t)l * TWOH * H,
            b2s + (size_t)l * H, x0, xb, N);
    }

    k_initout<<<1, 64, 0, stream>>>(bout, (float*)d_out);
    k_pool<<<512, 256, 0, stream>>>(x0, batch, Wout, (float*)d_out, N);
}

// Round 9
// 582.681 us; speedup vs baseline: 4.0764x; 1.1093x over previous
//
#include <hip/hip_runtime.h>

#define H 64
#define CIN 32
#define TWOH 128
#define NGRAPH 64

// bucketed CSR build
#define BSH 7
#define BNODE 128
#define NBLK_PART 256
#define BCAP 32
#define MAXNB 2048
#define OCAP 65536

typedef unsigned short bfraw;
typedef short v8s __attribute__((ext_vector_type(8)));
typedef float v4f __attribute__((ext_vector_type(4)));

__device__ __forceinline__ float bf2f(bfraw u) {
    return __uint_as_float(((unsigned)u) << 16);
}
__device__ __forceinline__ bfraw f2bf(float f) {
    unsigned u = __float_as_uint(f);
    unsigned r = (u + 0x7fffu + ((u >> 16) & 1u)) >> 16;  // RNE
    return (bfraw)r;
}
// split fp32 -> hi + lo bf16 (combined rel err ~2^-17)
__device__ __forceinline__ void f2bf2(float f, bfraw& hi, bfraw& lo) {
    hi = f2bf(f);
    lo = f2bf(f - bf2f(hi));
}

// ---------------- input GEMM: x0[N,64] = x[N,32] @ Win + bin ----------------
extern "C" __global__ void __launch_bounds__(256) k_input_gemm(
    const float* __restrict__ x, const float* __restrict__ Win,
    const float* __restrict__ bin, float* __restrict__ x0,
    bfraw* __restrict__ xb, int N)
{
    __shared__ float Wl[CIN * H]; // 8 KB
    for (int i = threadIdx.x; i < CIN * H; i += blockDim.x) Wl[i] = Win[i];
    __syncthreads();
    const int lane = threadIdx.x & 63;
    const int wpb = blockDim.x >> 6;
    int w = blockIdx.x * wpb + (threadIdx.x >> 6);
    const int wstride = gridDim.x * wpb;
    const float bv = bin[lane];
    for (int n = w; n < N; n += wstride) {
        float in = (lane < CIN) ? x[n * CIN + lane] : 0.f;
        float acc = bv;
        #pragma unroll
        for (int k = 0; k < CIN; ++k)
            acc += __shfl(in, k) * Wl[k * H + lane];
        x0[(size_t)n * H + lane] = acc;
        xb[(size_t)n * H + lane] = f2bf(acc);
    }
}

// ---------------- weight conversion to split bf16 (all layers, once) ----------------
extern "C" __global__ void k_cvtw(const float* __restrict__ W1s,
    const float* __restrict__ W2s, bfraw* __restrict__ W1hi,
    bfraw* __restrict__ W1lo, bfraw* __restrict__ W2hi,
    bfraw* __restrict__ W2lo, int total)  // total = L*H*TWOH
{
    int i = blockIdx.x * blockDim.x + threadIdx.x;
    const int st = gridDim.x * blockDim.x;
    for (; i < total; i += st) {
        bfraw h, l;
        f2bf2(W1s[i], h, l); W1hi[i] = h; W1lo[i] = l;
        f2bf2(W2s[i], h, l); W2hi[i] = h; W2lo[i] = l;
    }
}

// ---------------- block-private bucket partition (pass A) ----------------
// btmp layout: [blk][bucket][BCAP]  (block-exclusive 128B slots, line-aligned)
// bcnt layout: [blk][bucket]        (block-exclusive rows)
__device__ __forceinline__ void bput(int s, int d, unsigned* __restrict__ lcnt,
    unsigned* __restrict__ myTmp, unsigned* __restrict__ deg,
    int* __restrict__ oflow, unsigned* __restrict__ ocnt)
{
    const int b = d >> BSH;
    const unsigned pos = atomicAdd(&lcnt[b], 1u);   // LDS atomic
    if (pos < BCAP) {
        myTmp[b * BCAP + pos] = (unsigned)s | ((unsigned)(d & (BNODE - 1)) << 20);
    } else {
        const unsigned o = atomicAdd(ocnt, 1u);
        if (o < OCAP) {
            oflow[2 * o] = s; oflow[2 * o + 1] = d;
            atomicAdd(&deg[d], 1u);
        }
    }
}

extern "C" __global__ void __launch_bounds__(256) k_bucket(
    const int* __restrict__ src, const int* __restrict__ dst,
    unsigned* __restrict__ bcnt, unsigned* __restrict__ btmp,
    unsigned* __restrict__ deg, int* __restrict__ oflow,
    unsigned* __restrict__ ocnt, int E, int NBck)
{
    __shared__ unsigned lcnt[MAXNB];  // 8 KB (NBck <= 2048)
    for (int i = threadIdx.x; i < NBck; i += blockDim.x) lcnt[i] = 0u;
    __syncthreads();
    unsigned* __restrict__ myTmp = btmp + (size_t)blockIdx.x * NBck * BCAP;
    const int tid0 = blockIdx.x * blockDim.x + threadIdx.x;
    const int st = gridDim.x * blockDim.x;
    const int E4 = E >> 2;
    const int4* s4 = (const int4*)src;
    const int4* d4 = (const int4*)dst;
    for (int j = tid0; j < E4; j += st) {
        const int4 sv = s4[j];
        const int4 dv = d4[j];
        bput(sv.x, dv.x, lcnt, myTmp, deg, oflow, ocnt);
        bput(sv.y, dv.y, lcnt, myTmp, deg, oflow, ocnt);
        bput(sv.z, dv.z, lcnt, myTmp, deg, oflow, ocnt);
        bput(sv.w, dv.w, lcnt, myTmp, deg, oflow, ocnt);
    }
    for (int j = (E4 << 2) + tid0; j < E; j += st)
        bput(src[j], dst[j], lcnt, myTmp, deg, oflow, ocnt);
    __syncthreads();
    unsigned* __restrict__ myCnt = bcnt + (size_t)blockIdx.x * NBck;
    for (int i = threadIdx.x; i < NBck; i += blockDim.x) {
        const unsigned c = lcnt[i];
        myCnt[i] = (c < BCAP) ? c : BCAP;
    }
}

// ---------------- per-bucket degree histogram ----------------
extern "C" __global__ void __launch_bounds__(256) k_bhist(
    const unsigned* __restrict__ bcnt, const unsigned* __restrict__ btmp,
    unsigned* __restrict__ deg, int N, int NBck)
{
    __shared__ unsigned hist[BNODE];
    const int b = blockIdx.x;
    for (int i = threadIdx.x; i < BNODE; i += blockDim.x) hist[i] = 0u;
    __syncthreads();
    for (int blk = threadIdx.x; blk < NBLK_PART; blk += blockDim.x) {
        const unsigned cnt = bcnt[(size_t)blk * NBck + b];
        const unsigned* p = btmp + ((size_t)blk * NBck + b) * BCAP;
        for (unsigned j = 0; j < cnt; ++j)
            atomicAdd(&hist[p[j] >> 20], 1u);
    }
    __syncthreads();
    const int base = b << BSH;
    for (int i = threadIdx.x; i < BNODE; i += blockDim.x)
        if (base + i < N) {
            const unsigned h = hist[i];
            if (h) atomicAdd(&deg[base + i], h);
        }
}

extern "C" __global__ void k_scan1(const unsigned* __restrict__ deg,
    unsigned* __restrict__ indptr, unsigned* __restrict__ bsum, int N)
{
    __shared__ unsigned s[256];
    const int tid = threadIdx.x;
    const int base = blockIdx.x * 1024 + tid * 4;
    unsigned d[4];
    #pragma unroll
    for (int j = 0; j < 4; ++j)
        d[j] = (base + j < N) ? ((deg[base + j] + 3u) & ~3u) : 0u;  // padded
    unsigned t = d[0] + d[1] + d[2] + d[3];
    s[tid] = t;
    __syncthreads();
    for (int o = 1; o < 256; o <<= 1) {
        unsigned v = (tid >= o) ? s[tid - o] : 0u;
        __syncthreads();
        s[tid] += v;
        __syncthreads();
    }
    unsigned run = (tid == 0) ? 0u : s[tid - 1];
    if (tid == 255) bsum[blockIdx.x] = s[255];
    #pragma unroll
    for (int j = 0; j < 4; ++j) {
        if (base + j < N) indptr[base + j] = run;
        run += d[j];
    }
}

extern "C" __global__ void k_scan2(unsigned* bsum, int nb,
    unsigned* __restrict__ indptr, int N)
{
    if (threadIdx.x == 0) {
        unsigned run = 0;
        for (int i = 0; i < nb; ++i) { unsigned v = bsum[i]; bsum[i] = run; run += v; }
        indptr[N] = run;  // total padded edges
    }
}

extern "C" __global__ void k_scan3(unsigned* __restrict__ indptr,
    const unsigned* __restrict__ bsum, unsigned* __restrict__ cursor, int N)
{
    const int base = blockIdx.x * 1024 + threadIdx.x * 4;
    const unsigned boff = bsum[blockIdx.x];
    #pragma unroll
    for (int j = 0; j < 4; ++j) {
        const int idx = base + j;
        if (idx < N) {
            const unsigned v = indptr[idx] + boff;
            indptr[idx] = v;
            cursor[idx] = v;
        }
    }
}

// ---------------- per-bucket scatter to final CSR (pass B) ----------------
extern "C" __global__ void __launch_bounds__(256) k_bscat(
    const unsigned* __restrict__ bcnt, const unsigned* __restrict__ btmp,
    const unsigned* __restrict__ indptr, unsigned* __restrict__ cursor,
    int* __restrict__ esrc, int N, int NBck)
{
    __shared__ unsigned lcur[BNODE];
    const int b = blockIdx.x;
    const int base = b << BSH;
    for (int i = threadIdx.x; i < BNODE; i += blockDim.x)
        lcur[i] = (base + i < N) ? indptr[base + i] : 0u;
    __syncthreads();
    for (int blk = threadIdx.x; blk < NBLK_PART; blk += blockDim.x) {
        const unsigned cnt = bcnt[(size_t)blk * NBck + b];
        const unsigned* p = btmp + ((size_t)blk * NBck + b) * BCAP;
        for (unsigned j = 0; j < cnt; ++j) {
            const unsigned e = p[j];
            const unsigned pos = atomicAdd(&lcur[e >> 20], 1u);
            esrc[pos] = (int)(e & 0xFFFFFu);
        }
    }
    __syncthreads();
    for (int i = threadIdx.x; i < BNODE; i += blockDim.x)
        if (base + i < N) cursor[base + i] = lcur[i];
}

// overflow edges (expected none) via global cursor
extern "C" __global__ void k_over(const int* __restrict__ oflow,
    const unsigned* __restrict__ ocnt, unsigned* __restrict__ cursor,
    int* __restrict__ esrc)
{
    unsigned n = *ocnt; if (n > OCAP) n = OCAP;
    int i = blockIdx.x * blockDim.x + threadIdx.x;
    const int st = gridDim.x * blockDim.x;
    for (; (unsigned)i < n; i += st) {
        const int s = oflow[2 * i], d = oflow[2 * i + 1];
        const unsigned pos = atomicAdd(&cursor[d], 1u);
        esrc[pos] = s;
    }
}

// fill padded slots with sentinel N (zero row)
extern "C" __global__ void k_pad(const unsigned* __restrict__ cursor,
    const unsigned* __restrict__ indptr, int* __restrict__ esrc, int N)
{
    int n = blockIdx.x * blockDim.x + threadIdx.x;
    const int st = gridDim.x * blockDim.x;
    for (; n < N; n += st) {
        const unsigned end = indptr[n + 1];
        for (unsigned p = cursor[n]; p < end; ++p) esrc[p] = N;
    }
}

// ------- gather: hpre = (1+eps)*x0 + sum relu(xb[src]); store split bf16 -------
extern "C" __global__ void __launch_bounds__(256) k_agg(
    const float* __restrict__ x0, const bfraw* __restrict__ xb,
    const int* __restrict__ esrc, const unsigned* __restrict__ indptr,
    const float* __restrict__ epsp, bfraw* __restrict__ hprehi,
    bfraw* __restrict__ hprelo, int N)
{
    const int lane = threadIdx.x & 63;
    const int sub = lane >> 4;          // 0..3 : which edge of the group
    const int fi = (lane & 15) << 2;    // feature base (4 features)
    const int wpb = blockDim.x >> 6;
    int w = blockIdx.x * wpb + (threadIdx.x >> 6);
    const int wstride = gridDim.x * wpb;
    const float ep = 1.f + epsp[0];
    for (int n = w; n < N; n += wstride) {
        const unsigned s0 = indptr[n];
        const unsigned s1 = indptr[n + 1];   // padded: (s1-s0)%4==0
        float a0 = 0.f, a1 = 0.f, a2 = 0.f, a3 = 0.f;
        unsigned e = s0;
        for (; e + 16 <= s1; e += 16) {
            const int i0 = esrc[e + sub];
            const int i1 = esrc[e + 4 + sub];
            const int i2 = esrc[e + 8 + sub];
            const int i3 = esrc[e + 12 + sub];
            const ushort4 r0 = *(const ushort4*)&xb[(size_t)i0 * H + fi];
            const ushort4 r1 = *(const ushort4*)&xb[(size_t)i1 * H + fi];
            const ushort4 r2 = *(const ushort4*)&xb[(size_t)i2 * H + fi];
            const ushort4 r3 = *(const ushort4*)&xb[(size_t)i3 * H + fi];
            a0 += fmaxf(bf2f(r0.x), 0.f) + fmaxf(bf2f(r1.x), 0.f)
                + fmaxf(bf2f(r2.x), 0.f) + fmaxf(bf2f(r3.x), 0.f);
            a1 += fmaxf(bf2f(r0.y), 0.f) + fmaxf(bf2f(r1.y), 0.f)
                + fmaxf(bf2f(r2.y), 0.f) + fmaxf(bf2f(r3.y), 0.f);
            a2 += fmaxf(bf2f(r0.z), 0.f) + fmaxf(bf2f(r1.z), 0.f)
                + fmaxf(bf2f(r2.z), 0.f) + fmaxf(bf2f(r3.z), 0.f);
            a3 += fmaxf(bf2f(r0.w), 0.f) + fmaxf(bf2f(r1.w), 0.f)
                + fmaxf(bf2f(r2.w), 0.f) + fmaxf(bf2f(r3.w), 0.f);
        }
        for (; e < s1; e += 4) {
            const int i0 = esrc[e + sub];
            const ushort4 r0 = *(const ushort4*)&xb[(size_t)i0 * H + fi];
            a0 += fmaxf(bf2f(r0.x), 0.f);
            a1 += fmaxf(bf2f(r0.y), 0.f);
            a2 += fmaxf(bf2f(r0.z), 0.f);
            a3 += fmaxf(bf2f(r0.w), 0.f);
        }
        #pragma unroll
        for (int o = 16; o < 64; o <<= 1) {
            a0 += __shfl_xor(a0, o);
            a1 += __shfl_xor(a1, o);
            a2 += __shfl_xor(a2, o);
            a3 += __shfl_xor(a3, o);
        }
        if (sub == 0) {
            const float4 self = *(const float4*)&x0[(size_t)n * H + fi];
            const float h0 = ep * self.x + a0;
            const float h1v = ep * self.y + a1;
            const float h2 = ep * self.z + a2;
            const float h3 = ep * self.w + a3;
            ushort4 ohi, olo;
            f2bf2(h0, ohi.x, olo.x);
            f2bf2(h1v, ohi.y, olo.y);
            f2bf2(h2, ohi.z, olo.z);
            f2bf2(h3, ohi.w, olo.w);
            *(ushort4*)&hprehi[(size_t)n * H + fi] = ohi;
            *(ushort4*)&hprelo[(size_t)n * H + fi] = olo;
        }
    }
}

// ------------- MFMA GEMM1 + BN stats: h1[N,128] = hpre @ W1 + b1 -------------
// split precision: C = Ahi*Whi + Ahi*Wlo + Alo*Whi. Each wave: half the cols.
extern "C" __global__ void __launch_bounds__(256) k_gemm1(
    const bfraw* __restrict__ hprehi, const bfraw* __restrict__ hprelo,
    const bfraw* __restrict__ W1hi, const bfraw* __restrict__ W1lo,
    const float* __restrict__ b1, float* __restrict__ h1,
    double* __restrict__ gsum, double* __restrict__ gsq, int N)
{
    __shared__ float ss[TWOH], sq[TWOH];
    if (threadIdx.x < TWOH) { ss[threadIdx.x] = 0.f; sq[threadIdx.x] = 0.f; }
    __syncthreads();
    const int lane = threadIdx.x & 63;
    const int row = lane & 15;   // A row / B col / D col
    const int kg  = lane >> 4;   // k-group
    const int wpb = blockDim.x >> 6;
    const int wid = blockIdx.x * wpb + (threadIdx.x >> 6);
    const int wstride = gridDim.x * wpb;
    const int half = wid & 1;          // which 64 of the 128 cols
    const int cb = half * 4;           // col-tile base
    // preload B fragments: 2 k-chunks x 4 col-tiles, hi+lo
    v8s bhi[2][4], blo[2][4];
    #pragma unroll
    for (int kc = 0; kc < 2; ++kc)
        #pragma unroll
        for (int ct = 0; ct < 4; ++ct) {
            v8s bh, bl;
            #pragma unroll
            for (int i = 0; i < 8; ++i) {
                const int idx = (kc * 32 + kg * 8 + i) * TWOH + (cb + ct) * 16 + row;
                bh[i] = (short)W1hi[idx];
                bl[i] = (short)W1lo[idx];
            }
            bhi[kc][ct] = bh; blo[kc][ct] = bl;
        }
    float bcol[4];
    #pragma unroll
    for (int ct = 0; ct < 4; ++ct) bcol[ct] = b1[(cb + ct) * 16 + row];

    const int tiles = (N + 15) >> 4;
    const int tstride = wstride >> 1;
    float sacc[4], qacc[4];
    #pragma unroll
    for (int ct = 0; ct < 4; ++ct) { sacc[ct] = 0.f; qacc[ct] = 0.f; }

    for (int t = wid >> 1; t < tiles; t += tstride) {
        const int tb = t << 4;
        int nA = tb + row; if (nA >= N) nA = N - 1;
        const v8s a0h = *(const v8s*)&hprehi[(size_t)nA * H + kg * 8];
        const v8s a1h = *(const v8s*)&hprehi[(size_t)nA * H + 32 + kg * 8];
        const v8s a0l = *(const v8s*)&hprelo[(size_t)nA * H + kg * 8];
        const v8s a1l = *(const v8s*)&hprelo[(size_t)nA * H + 32 + kg * 8];
        v4f c[4];
        #pragma unroll
        for (int ct = 0; ct < 4; ++ct) {
            v4f cc = (v4f){0.f, 0.f, 0.f, 0.f};
            cc = __builtin_amdgcn_mfma_f32_16x16x32_bf16(a0h, bhi[0][ct], cc, 0, 0, 0);
            cc = __builtin_amdgcn_mfma_f32_16x16x32_bf16(a1h, bhi[1][ct], cc, 0, 0, 0);
            cc = __builtin_amdgcn_mfma_f32_16x16x32_bf16(a0h, blo[0][ct], cc, 0, 0, 0);
            cc = __builtin_amdgcn_mfma_f32_16x16x32_bf16(a1h, blo[1][ct], cc, 0, 0, 0);
            cc = __builtin_amdgcn_mfma_f32_16x16x32_bf16(a0l, bhi[0][ct], cc, 0, 0, 0);
            cc = __builtin_amdgcn_mfma_f32_16x16x32_bf16(a1l, bhi[1][ct], cc, 0, 0, 0);
            c[ct] = cc;
        }
        #pragma unroll
        for (int ct = 0; ct < 4; ++ct) {
            #pragma unroll
            for (int r = 0; r < 4; ++r) {
                const int node = tb + kg * 4 + r;  // D row
                if (node < N) {
                    const float v = c[ct][r] + bcol[ct];
                    h1[(size_t)node * TWOH + (cb + ct) * 16 + row] = v;
                    sacc[ct] += v;
                    qacc[ct] += v * v;
                }
            }
        }
    }
    #pragma unroll
    for (int ct = 0; ct < 4; ++ct) {
        float s = sacc[ct];
        s += __shfl_xor(s, 16); s += __shfl_xor(s, 32);
        float q = qacc[ct];
        q += __shfl_xor(q, 16); q += __shfl_xor(q, 32);
        if (kg == 0) {
            atomicAdd(&ss[(cb + ct) * 16 + row], s);
            atomicAdd(&sq[(cb + ct) * 16 + row], q);
        }
    }
    __syncthreads();
    if (threadIdx.x < TWOH) {
        atomicAdd(&gsum[threadIdx.x], (double)ss[threadIdx.x]);
        atomicAdd(&gsq[threadIdx.x], (double)sq[threadIdx.x]);
    }
}

// ---------------- BN finalize: scale/shift ----------------
extern "C" __global__ void k_bnfin(const double* __restrict__ gsum,
    const double* __restrict__ gsq, const float* __restrict__ gamma,
    const float* __restrict__ beta, float* __restrict__ scsh, int N)
{
    const int j = threadIdx.x;
    if (j < TWOH) {
        const double mu = gsum[j] / N;
        const double var = gsq[j] / N - mu * mu;
        const float sc = gamma[j] * rsqrtf(fmaxf((float)var, 0.f) + 1e-5f);
        scsh[j] = sc;
        scsh[TWOH + j] = beta[j] - (float)mu * sc;
    }
}

// --- MFMA GEMM2 + fused BN/ReLU + residual: x0 += relu(h1*sc+sh) @ W2 + b2 ---
extern "C" __global__ void __launch_bounds__(256) k_gemm2(
    const float* __restrict__ h1, const float* __restrict__ scsh,
    const bfraw* __restrict__ W2hi, const bfraw* __restrict__ W2lo,
    const float* __restrict__ b2, float* __restrict__ x0,
    bfraw* __restrict__ xb, int N)
{
    __shared__ float scl[TWOH], shl[TWOH];  // 1 KB
    for (int i = threadIdx.x; i < TWOH; i += blockDim.x) {
        scl[i] = scsh[i];
        shl[i] = scsh[TWOH + i];
    }
    __syncthreads();
    const int lane = threadIdx.x & 63;
    const int row = lane & 15;
    const int kg  = lane >> 4;
    const int wpb = blockDim.x >> 6;
    const int wid = blockIdx.x * wpb + (threadIdx.x >> 6);
    const int wstride = gridDim.x * wpb;
    const int half = wid & 1;       // which 32 of the 64 cols
    const int cb = half * 2;        // col-tile base
    // preload B fragments: 4 k-chunks x 2 col-tiles, hi+lo
    v8s bhi[4][2], blo[4][2];
    #pragma unroll
    for (int kc = 0; kc < 4; ++kc)
        #pragma unroll
        for (int ct = 0; ct < 2; ++ct) {
            v8s bh, bl;
            #pragma unroll
            for (int i = 0; i < 8; ++i) {
                const int idx = (kc * 32 + kg * 8 + i) * H + (cb + ct) * 16 + row;
                bh[i] = (short)W2hi[idx];
                bl[i] = (short)W2lo[idx];
            }
            bhi[kc][ct] = bh; blo[kc][ct] = bl;
        }
    float bcol[2];
    #pragma unroll
    for (int ct = 0; ct < 2; ++ct) bcol[ct] = b2[(cb + ct) * 16 + row];
    // per-lane BN constants for this lane's 32 features (8 per k-chunk)
    float lsc[4][8], lsh[4][8];
    #pragma unroll
    for (int kc = 0; kc < 4; ++kc) {
        const int fb = kc * 32 + kg * 8;
        #pragma unroll
        for (int i = 0; i < 8; ++i) { lsc[kc][i] = scl[fb + i]; lsh[kc][i] = shl[fb + i]; }
    }

    const int tiles = (N + 15) >> 4;
    const int tstride = wstride >> 1;

    for (int t = wid >> 1; t < tiles; t += tstride) {
        const int tb = t << 4;
        int nA = tb + row; if (nA >= N) nA = N - 1;
        v8s ah[4], al[4];
        #pragma unroll
        for (int kc = 0; kc < 4; ++kc) {
            const int fb = kc * 32 + kg * 8;
            const float4 h0 = *(const float4*)&h1[(size_t)nA * TWOH + fb];
            const float4 h4 = *(const float4*)&h1[(size_t)nA * TWOH + fb + 4];
            float yv[8] = {h0.x, h0.y, h0.z, h0.w, h4.x, h4.y, h4.z, h4.w};
            v8s vh, vl;
            #pragma unroll
            for (int i = 0; i < 8; ++i) {
                const float y = fmaxf(yv[i] * lsc[kc][i] + lsh[kc][i], 0.f);
                bfraw hi, lo;
                f2bf2(y, hi, lo);
                vh[i] = (short)hi;
                vl[i] = (short)lo;
            }
            ah[kc] = vh; al[kc] = vl;
        }
        v4f c[2];
        #pragma unroll
        for (int ct = 0; ct < 2; ++ct) {
            v4f cc = (v4f){0.f, 0.f, 0.f, 0.f};
            #pragma unroll
            for (int kc = 0; kc < 4; ++kc) {
                cc = __builtin_amdgcn_mfma_f32_16x16x32_bf16(ah[kc], bhi[kc][ct], cc, 0, 0, 0);
                cc = __builtin_amdgcn_mfma_f32_16x16x32_bf16(ah[kc], blo[kc][ct], cc, 0, 0, 0);
                cc = __builtin_amdgcn_mfma_f32_16x16x32_bf16(al[kc], bhi[kc][ct], cc, 0, 0, 0);
            }
            c[ct] = cc;
        }
        #pragma unroll
        for (int ct = 0; ct < 2; ++ct) {
            #pragma unroll
            for (int r = 0; r < 4; ++r) {
                const int node = tb + kg * 4 + r;
                if (node < N) {
                    const size_t idx = (size_t)node * H + (cb + ct) * 16 + row;
                    const float v = x0[idx] + c[ct][r] + bcol[ct];
                    x0[idx] = v;
                    xb[idx] = f2bf(v);
                }
            }
        }
    }
}

// ---------------- pooling + output ----------------
extern "C" __global__ void k_initout(const float* __restrict__ bout,
    float* __restrict__ out)
{
    if (threadIdx.x < NGRAPH) out[threadIdx.x] = bout[0];
}

extern "C" __global__ void __launch_bounds__(256) k_pool(
    const float* __restrict__ x0, const int* __restrict__ batch,
    const float* __restrict__ Wout, float* __restrict__ out, int N)
{
    __shared__ float pl[NGRAPH];
    if (threadIdx.x < NGRAPH) pl[threadIdx.x] = 0.f;
    __syncthreads();
    const int lane = threadIdx.x & 63;
    const int wpb = blockDim.x >> 6;
    int w = blockIdx.x * wpb + (threadIdx.x >> 6);
    const int wstride = gridDim.x * wpb;
    const float wv = Wout[lane];
    for (int n = w; n < N; n += wstride) {
        float v = x0[(size_t)n * H + lane] * wv;
        #pragma unroll
        for (int o = 32; o > 0; o >>= 1) v += __shfl_down(v, o);
        if (lane == 0) atomicAdd(&pl[batch[n]], v);
    }
    __syncthreads();
    if (threadIdx.x < NGRAPH) {
        const float v = pl[threadIdx.x];
        if (v != 0.f) atomicAdd(&out[threadIdx.x], v);
    }
}

// ---------------- host driver ----------------
extern "C" void kernel_launch(void* const* d_in, const int* in_sizes, int n_in,
                              void* d_out, int out_size, void* d_ws, size_t ws_size,
                              hipStream_t stream)
{
    const float* x     = (const float*)d_in[0];
    const int*   ei    = (const int*)d_in[1];   // int32 per harness conversion
    const int*   batch = (const int*)d_in[2];   // int32 per harness conversion
    const float* Win   = (const float*)d_in[3];
    const float* bin   = (const float*)d_in[4];
    const float* W1s   = (const float*)d_in[5];
    const float* b1s   = (const float*)d_in[6];
    const float* gam   = (const float*)d_in[7];
    const float* bet   = (const float*)d_in[8];
    const float* W2s   = (const float*)d_in[9];
    const float* b2s   = (const float*)d_in[10];
    const float* epss  = (const float*)d_in[11];
    const float* Wout  = (const float*)d_in[12];
    const float* bout  = (const float*)d_in[13];

    const int N = in_sizes[0] / CIN;
    const int E = in_sizes[1] / 2;
    const int L = in_sizes[11];
    const int* src = ei;
    const int* dst = ei + E;
    const int NB = (N + BNODE - 1) >> BSH;   // final buckets (<= MAXNB)

    // workspace layout
    char* ws = (char*)d_ws;
    size_t off = 0;
    auto take = [&](size_t bytes) {
        void* p = ws + off;
        off += (bytes + 255) & ~(size_t)255;
        return p;
    };
    float*    x0     = (float*)take((size_t)N * H * 4);
    bfraw*    xb     = (bfraw*)take((size_t)(N + 1) * H * 2);  // +1 zero row
    bfraw*    hprehi = (bfraw*)take((size_t)N * H * 2);
    bfraw*    hprelo = (bfraw*)take((size_t)N * H * 2);
    float*    h1     = (float*)take((size_t)N * TWOH * 4);
    unsigned* deg    = (unsigned*)take((size_t)N * 4);
    unsigned* indptr = (unsigned*)take((size_t)(N + 1) * 4);
    unsigned* cursor = (unsigned*)take((size_t)N * 4);
    int*      esrc   = (int*)take((size_t)(E + 4 * (N + 1)) * 4);  // padded
    unsigned* bsum   = (unsigned*)take(4096);
    double*   gsum   = (double*)take(TWOH * 8 * 2); // gsum + gsq contiguous
    double*   gsq    = gsum + TWOH;
    float*    scsh   = (float*)take(2 * TWOH * 4);
    bfraw*    W1hi   = (bfraw*)take((size_t)L * H * TWOH * 2);
    bfraw*    W1lo   = (bfraw*)take((size_t)L * H * TWOH * 2);
    bfraw*    W2hi   = (bfraw*)take((size_t)L * TWOH * H * 2);
    bfraw*    W2lo   = (bfraw*)take((size_t)L * TWOH * H * 2);
    unsigned* bcnt   = (unsigned*)take((size_t)NBLK_PART * NB * 4);
    unsigned* btmp   = (unsigned*)take((size_t)NBLK_PART * NB * BCAP * 4);
    int*      oflow  = (int*)take((size_t)OCAP * 2 * 4);
    unsigned* ocnt   = (unsigned*)take(256);
    (void)ws_size; (void)n_in; (void)out_size;

    hipMemsetAsync(deg, 0, (size_t)N * 4, stream);
    hipMemsetAsync(ocnt, 0, 4, stream);
    hipMemsetAsync(xb + (size_t)N * H, 0, H * 2, stream);  // sentinel zero row
    k_input_gemm<<<1024, 256, 0, stream>>>(x, Win, bin, x0, xb, N);
    k_cvtw<<<256, 256, 0, stream>>>(W1s, W2s, W1hi, W1lo, W2hi, W2lo, L * H * TWOH);
    k_bucket<<<NBLK_PART, 256, 0, stream>>>(src, dst, bcnt, btmp, deg, oflow, ocnt, E, NB);
    k_bhist<<<NB, 256, 0, stream>>>(bcnt, btmp, deg, N, NB);
    const int nb = (N + 1023) / 1024;
    k_scan1<<<nb, 256, 0, stream>>>(deg, indptr, bsum, N);
    k_scan2<<<1, 64, 0, stream>>>(bsum, nb, indptr, N);
    k_scan3<<<nb, 256, 0, stream>>>(indptr, bsum, cursor, N);
    k_bscat<<<NB, 256, 0, stream>>>(bcnt, btmp, indptr, cursor, esrc, N, NB);
    k_over<<<32, 256, 0, stream>>>(oflow, ocnt, cursor, esrc);
    k_pad<<<512, 256, 0, stream>>>(cursor, indptr, esrc, N);

    for (int l = 0; l < L; ++l) {
        hipMemsetAsync(gsum, 0, TWOH * 8 * 2, stream);
        k_agg<<<4096, 256, 0, stream>>>(x0, xb, esrc, indptr, epss + l,
            hprehi, hprelo, N);
        k_gemm1<<<512, 256, 0, stream>>>(hprehi, hprelo,
            W1hi + (size_t)l * H * TWOH, W1lo + (size_t)l * H * TWOH,
            b1s + (size_t)l * TWOH, h1, gsum, gsq, N);
        k_bnfin<<<1, 128, 0, stream>>>(gsum, gsq, gam + (size_t)l * TWOH,
            bet + (size_t)l * TWOH, scsh, N);
        k_gemm2<<<512, 256, 0, stream>>>(h1, scsh,
            W2hi + (size_t)l * TWOH * H, W2lo + (size_t)l * TWOH * H,
            b2s + (size_t)l * H, x0, xb, N);
    }

    k_initout<<<1, 64, 0, stream>>>(bout, (float*)d_out);
    k_pool<<<512, 256, 0, stream>>>(x0, batch, Wout, (float*)d_out, N);
}

// Round 10
// 572.255 us; speedup vs baseline: 4.1507x; 1.0182x over previous
//
#include <hip/hip_runtime.h>

#define H 64
#define CIN 32
#define TWOH 128
#define NGRAPH 64

// bucketed CSR build
#define BSH 7
#define BNODE 128
#define NBLK_PART 256
#define BCAP 32
#define MAXNB 2048
#define OCAP 65536

typedef unsigned short bfraw;
typedef short v8s __attribute__((ext_vector_type(8)));
typedef float v4f __attribute__((ext_vector_type(4)));

__device__ __forceinline__ float bf2f(bfraw u) {
    return __uint_as_float(((unsigned)u) << 16);
}
__device__ __forceinline__ bfraw f2bf(float f) {
    unsigned u = __float_as_uint(f);
    unsigned r = (u + 0x7fffu + ((u >> 16) & 1u)) >> 16;  // RNE
    return (bfraw)r;
}
// split fp32 -> hi + lo bf16 (combined rel err ~2^-17)
__device__ __forceinline__ void f2bf2(float f, bfraw& hi, bfraw& lo) {
    hi = f2bf(f);
    lo = f2bf(f - bf2f(hi));
}

// ---------------- input GEMM: x0[N,64] = x[N,32] @ Win + bin ----------------
extern "C" __global__ void __launch_bounds__(256) k_input_gemm(
    const float* __restrict__ x, const float* __restrict__ Win,
    const float* __restrict__ bin, float* __restrict__ x0,
    bfraw* __restrict__ xb, int N)
{
    __shared__ float Wl[CIN * H]; // 8 KB
    for (int i = threadIdx.x; i < CIN * H; i += blockDim.x) Wl[i] = Win[i];
    __syncthreads();
    const int lane = threadIdx.x & 63;
    const int wpb = blockDim.x >> 6;
    int w = blockIdx.x * wpb + (threadIdx.x >> 6);
    const int wstride = gridDim.x * wpb;
    const float bv = bin[lane];
    for (int n = w; n < N; n += wstride) {
        float in = (lane < CIN) ? x[n * CIN + lane] : 0.f;
        float acc = bv;
        #pragma unroll
        for (int k = 0; k < CIN; ++k)
            acc += __shfl(in, k) * Wl[k * H + lane];
        x0[(size_t)n * H + lane] = acc;
        xb[(size_t)n * H + lane] = f2bf(acc);
    }
}

// ---------------- weight conversion to split bf16 (all layers, once) ----------------
extern "C" __global__ void k_cvtw(const float* __restrict__ W1s,
    const float* __restrict__ W2s, bfraw* __restrict__ W1hi,
    bfraw* __restrict__ W1lo, bfraw* __restrict__ W2hi,
    bfraw* __restrict__ W2lo, int total)  // total = L*H*TWOH
{
    int i = blockIdx.x * blockDim.x + threadIdx.x;
    const int st = gridDim.x * blockDim.x;
    for (; i < total; i += st) {
        bfraw h, l;
        f2bf2(W1s[i], h, l); W1hi[i] = h; W1lo[i] = l;
        f2bf2(W2s[i], h, l); W2hi[i] = h; W2lo[i] = l;
    }
}

// ---------------- block-private bucket partition (pass A) ----------------
__device__ __forceinline__ void bput(int s, int d, unsigned* __restrict__ lcnt,
    unsigned* __restrict__ myTmp, unsigned* __restrict__ deg,
    int* __restrict__ oflow, unsigned* __restrict__ ocnt)
{
    const int b = d >> BSH;
    const unsigned pos = atomicAdd(&lcnt[b], 1u);   // LDS atomic
    if (pos < BCAP) {
        myTmp[b * BCAP + pos] = (unsigned)s | ((unsigned)(d & (BNODE - 1)) << 20);
    } else {
        const unsigned o = atomicAdd(ocnt, 1u);
        if (o < OCAP) {
            oflow[2 * o] = s; oflow[2 * o + 1] = d;
            atomicAdd(&deg[d], 1u);
        }
    }
}

extern "C" __global__ void __launch_bounds__(256) k_bucket(
    const int* __restrict__ src, const int* __restrict__ dst,
    unsigned* __restrict__ bcnt, unsigned* __restrict__ btmp,
    unsigned* __restrict__ deg, int* __restrict__ oflow,
    unsigned* __restrict__ ocnt, int E, int NBck)
{
    __shared__ unsigned lcnt[MAXNB];  // 8 KB (NBck <= 2048)
    for (int i = threadIdx.x; i < NBck; i += blockDim.x) lcnt[i] = 0u;
    __syncthreads();
    unsigned* __restrict__ myTmp = btmp + (size_t)blockIdx.x * NBck * BCAP;
    const int tid0 = blockIdx.x * blockDim.x + threadIdx.x;
    const int st = gridDim.x * blockDim.x;
    const int E4 = E >> 2;
    const int4* s4 = (const int4*)src;
    const int4* d4 = (const int4*)dst;
    for (int j = tid0; j < E4; j += st) {
        const int4 sv = s4[j];
        const int4 dv = d4[j];
        bput(sv.x, dv.x, lcnt, myTmp, deg, oflow, ocnt);
        bput(sv.y, dv.y, lcnt, myTmp, deg, oflow, ocnt);
        bput(sv.z, dv.z, lcnt, myTmp, deg, oflow, ocnt);
        bput(sv.w, dv.w, lcnt, myTmp, deg, oflow, ocnt);
    }
    for (int j = (E4 << 2) + tid0; j < E; j += st)
        bput(src[j], dst[j], lcnt, myTmp, deg, oflow, ocnt);
    __syncthreads();
    unsigned* __restrict__ myCnt = bcnt + (size_t)blockIdx.x * NBck;
    for (int i = threadIdx.x; i < NBck; i += blockDim.x) {
        const unsigned c = lcnt[i];
        myCnt[i] = (c < BCAP) ? c : BCAP;
    }
}

// ---------------- per-bucket degree histogram ----------------
extern "C" __global__ void __launch_bounds__(256) k_bhist(
    const unsigned* __restrict__ bcnt, const unsigned* __restrict__ btmp,
    unsigned* __restrict__ deg, int N, int NBck)
{
    __shared__ unsigned hist[BNODE];
    const int b = blockIdx.x;
    for (int i = threadIdx.x; i < BNODE; i += blockDim.x) hist[i] = 0u;
    __syncthreads();
    for (int blk = threadIdx.x; blk < NBLK_PART; blk += blockDim.x) {
        const unsigned cnt = bcnt[(size_t)blk * NBck + b];
        const unsigned* p = btmp + ((size_t)blk * NBck + b) * BCAP;
        for (unsigned j = 0; j < cnt; ++j)
            atomicAdd(&hist[p[j] >> 20], 1u);
    }
    __syncthreads();
    const int base = b << BSH;
    for (int i = threadIdx.x; i < BNODE; i += blockDim.x)
        if (base + i < N) {
            const unsigned h = hist[i];
            if (h) atomicAdd(&deg[base + i], h);
        }
}

extern "C" __global__ void k_scan1(const unsigned* __restrict__ deg,
    unsigned* __restrict__ indptr, unsigned* __restrict__ bsum, int N)
{
    __shared__ unsigned s[256];
    const int tid = threadIdx.x;
    const int base = blockIdx.x * 1024 + tid * 4;
    unsigned d[4];
    #pragma unroll
    for (int j = 0; j < 4; ++j)
        d[j] = (base + j < N) ? ((deg[base + j] + 3u) & ~3u) : 0u;  // padded
    unsigned t = d[0] + d[1] + d[2] + d[3];
    s[tid] = t;
    __syncthreads();
    for (int o = 1; o < 256; o <<= 1) {
        unsigned v = (tid >= o) ? s[tid - o] : 0u;
        __syncthreads();
        s[tid] += v;
        __syncthreads();
    }
    unsigned run = (tid == 0) ? 0u : s[tid - 1];
    if (tid == 255) bsum[blockIdx.x] = s[255];
    #pragma unroll
    for (int j = 0; j < 4; ++j) {
        if (base + j < N) indptr[base + j] = run;
        run += d[j];
    }
}

extern "C" __global__ void k_scan2(unsigned* bsum, int nb,
    unsigned* __restrict__ indptr, int N)
{
    if (threadIdx.x == 0) {
        unsigned run = 0;
        for (int i = 0; i < nb; ++i) { unsigned v = bsum[i]; bsum[i] = run; run += v; }
        indptr[N] = run;  // total padded edges
    }
}

extern "C" __global__ void k_scan3(unsigned* __restrict__ indptr,
    const unsigned* __restrict__ bsum, unsigned* __restrict__ cursor, int N)
{
    const int base = blockIdx.x * 1024 + threadIdx.x * 4;
    const unsigned boff = bsum[blockIdx.x];
    #pragma unroll
    for (int j = 0; j < 4; ++j) {
        const int idx = base + j;
        if (idx < N) {
            const unsigned v = indptr[idx] + boff;
            indptr[idx] = v;
            cursor[idx] = v;
        }
    }
}

// ---------------- per-bucket scatter to final CSR (pass B) ----------------
extern "C" __global__ void __launch_bounds__(256) k_bscat(
    const unsigned* __restrict__ bcnt, const unsigned* __restrict__ btmp,
    const unsigned* __restrict__ indptr, unsigned* __restrict__ cursor,
    int* __restrict__ esrc, int N, int NBck)
{
    __shared__ unsigned lcur[BNODE];
    const int b = blockIdx.x;
    const int base = b << BSH;
    for (int i = threadIdx.x; i < BNODE; i += blockDim.x)
        lcur[i] = (base + i < N) ? indptr[base + i] : 0u;
    __syncthreads();
    for (int blk = threadIdx.x; blk < NBLK_PART; blk += blockDim.x) {
        const unsigned cnt = bcnt[(size_t)blk * NBck + b];
        const unsigned* p = btmp + ((size_t)blk * NBck + b) * BCAP;
        for (unsigned j = 0; j < cnt; ++j) {
            const unsigned e = p[j];
            const unsigned pos = atomicAdd(&lcur[e >> 20], 1u);
            esrc[pos] = (int)(e & 0xFFFFFu);
        }
    }
    __syncthreads();
    for (int i = threadIdx.x; i < BNODE; i += blockDim.x)
        if (base + i < N) cursor[base + i] = lcur[i];
}

// overflow edges (expected none) via global cursor
extern "C" __global__ void k_over(const int* __restrict__ oflow,
    const unsigned* __restrict__ ocnt, unsigned* __restrict__ cursor,
    int* __restrict__ esrc)
{
    unsigned n = *ocnt; if (n > OCAP) n = OCAP;
    int i = blockIdx.x * blockDim.x + threadIdx.x;
    const int st = gridDim.x * blockDim.x;
    for (; (unsigned)i < n; i += st) {
        const int s = oflow[2 * i], d = oflow[2 * i + 1];
        const unsigned pos = atomicAdd(&cursor[d], 1u);
        esrc[pos] = s;
    }
}

// fill padded slots with sentinel N (zero row)
extern "C" __global__ void k_pad(const unsigned* __restrict__ cursor,
    const unsigned* __restrict__ indptr, int* __restrict__ esrc, int N)
{
    int n = blockIdx.x * blockDim.x + threadIdx.x;
    const int st = gridDim.x * blockDim.x;
    for (; n < N; n += st) {
        const unsigned end = indptr[n + 1];
        for (unsigned p = cursor[n]; p < end; ++p) esrc[p] = N;
    }
}

// ------- gather: hpre = (1+eps)*x0 + sum relu(xb[src]); store split bf16 -------
extern "C" __global__ void __launch_bounds__(256) k_agg(
    const float* __restrict__ x0, const bfraw* __restrict__ xb,
    const int* __restrict__ esrc, const unsigned* __restrict__ indptr,
    const float* __restrict__ epsp, bfraw* __restrict__ hprehi,
    bfraw* __restrict__ hprelo, int N)
{
    const int lane = threadIdx.x & 63;
    const int sub = lane >> 4;          // 0..3 : which edge of the group
    const int fi = (lane & 15) << 2;    // feature base (4 features)
    const int wpb = blockDim.x >> 6;
    int w = blockIdx.x * wpb + (threadIdx.x >> 6);
    const int wstride = gridDim.x * wpb;
    const float ep = 1.f + epsp[0];
    for (int n = w; n < N; n += wstride) {
        const unsigned s0 = indptr[n];
        const unsigned s1 = indptr[n + 1];   // padded: (s1-s0)%4==0
        float a0 = 0.f, a1 = 0.f, a2 = 0.f, a3 = 0.f;
        unsigned e = s0;
        for (; e + 16 <= s1; e += 16) {
            const int i0 = esrc[e + sub];
            const int i1 = esrc[e + 4 + sub];
            const int i2 = esrc[e + 8 + sub];
            const int i3 = esrc[e + 12 + sub];
            const ushort4 r0 = *(const ushort4*)&xb[(size_t)i0 * H + fi];
            const ushort4 r1 = *(const ushort4*)&xb[(size_t)i1 * H + fi];
            const ushort4 r2 = *(const ushort4*)&xb[(size_t)i2 * H + fi];
            const ushort4 r3 = *(const ushort4*)&xb[(size_t)i3 * H + fi];
            a0 += fmaxf(bf2f(r0.x), 0.f) + fmaxf(bf2f(r1.x), 0.f)
                + fmaxf(bf2f(r2.x), 0.f) + fmaxf(bf2f(r3.x), 0.f);
            a1 += fmaxf(bf2f(r0.y), 0.f) + fmaxf(bf2f(r1.y), 0.f)
                + fmaxf(bf2f(r2.y), 0.f) + fmaxf(bf2f(r3.y), 0.f);
            a2 += fmaxf(bf2f(r0.z), 0.f) + fmaxf(bf2f(r1.z), 0.f)
                + fmaxf(bf2f(r2.z), 0.f) + fmaxf(bf2f(r3.z), 0.f);
            a3 += fmaxf(bf2f(r0.w), 0.f) + fmaxf(bf2f(r1.w), 0.f)
                + fmaxf(bf2f(r2.w), 0.f) + fmaxf(bf2f(r3.w), 0.f);
        }
        for (; e < s1; e += 4) {
            const int i0 = esrc[e + sub];
            const ushort4 r0 = *(const ushort4*)&xb[(size_t)i0 * H + fi];
            a0 += fmaxf(bf2f(r0.x), 0.f);
            a1 += fmaxf(bf2f(r0.y), 0.f);
            a2 += fmaxf(bf2f(r0.z), 0.f);
            a3 += fmaxf(bf2f(r0.w), 0.f);
        }
        #pragma unroll
        for (int o = 16; o < 64; o <<= 1) {
            a0 += __shfl_xor(a0, o);
            a1 += __shfl_xor(a1, o);
            a2 += __shfl_xor(a2, o);
            a3 += __shfl_xor(a3, o);
        }
        if (sub == 0) {
            const float4 self = *(const float4*)&x0[(size_t)n * H + fi];
            const float h0 = ep * self.x + a0;
            const float h1v = ep * self.y + a1;
            const float h2 = ep * self.z + a2;
            const float h3 = ep * self.w + a3;
            ushort4 ohi, olo;
            f2bf2(h0, ohi.x, olo.x);
            f2bf2(h1v, ohi.y, olo.y);
            f2bf2(h2, ohi.z, olo.z);
            f2bf2(h3, ohi.w, olo.w);
            *(ushort4*)&hprehi[(size_t)n * H + fi] = ohi;
            *(ushort4*)&hprelo[(size_t)n * H + fi] = olo;
        }
    }
}

// ------------- MFMA GEMM1 + BN stats: h1[N,128] = hpre @ W1 + b1 -------------
// split precision: C = Ahi*Whi + Ahi*Wlo + Alo*Whi. Each wave: half the cols.
extern "C" __global__ void __launch_bounds__(256) k_gemm1(
    const bfraw* __restrict__ hprehi, const bfraw* __restrict__ hprelo,
    const bfraw* __restrict__ W1hi, const bfraw* __restrict__ W1lo,
    const float* __restrict__ b1, float* __restrict__ h1,
    double* __restrict__ gsum, double* __restrict__ gsq, int N)
{
    __shared__ float ss[TWOH], sq[TWOH];
    if (threadIdx.x < TWOH) { ss[threadIdx.x] = 0.f; sq[threadIdx.x] = 0.f; }
    __syncthreads();
    const int lane = threadIdx.x & 63;
    const int row = lane & 15;   // A row / B col / D col
    const int kg  = lane >> 4;   // k-group
    const int wpb = blockDim.x >> 6;
    const int wid = blockIdx.x * wpb + (threadIdx.x >> 6);
    const int wstride = gridDim.x * wpb;
    const int half = wid & 1;          // which 64 of the 128 cols
    const int cb = half * 4;           // col-tile base
    // preload B fragments: 2 k-chunks x 4 col-tiles, hi+lo
    v8s bhi[2][4], blo[2][4];
    #pragma unroll
    for (int kc = 0; kc < 2; ++kc)
        #pragma unroll
        for (int ct = 0; ct < 4; ++ct) {
            v8s bh, bl;
            #pragma unroll
            for (int i = 0; i < 8; ++i) {
                const int idx = (kc * 32 + kg * 8 + i) * TWOH + (cb + ct) * 16 + row;
                bh[i] = (short)W1hi[idx];
                bl[i] = (short)W1lo[idx];
            }
            bhi[kc][ct] = bh; blo[kc][ct] = bl;
        }
    float bcol[4];
    #pragma unroll
    for (int ct = 0; ct < 4; ++ct) bcol[ct] = b1[(cb + ct) * 16 + row];

    const int tiles = (N + 15) >> 4;
    const int tstride = wstride >> 1;
    float sacc[4], qacc[4];
    #pragma unroll
    for (int ct = 0; ct < 4; ++ct) { sacc[ct] = 0.f; qacc[ct] = 0.f; }

    for (int t = wid >> 1; t < tiles; t += tstride) {
        const int tb = t << 4;
        int nA = tb + row; if (nA >= N) nA = N - 1;
        const v8s a0h = *(const v8s*)&hprehi[(size_t)nA * H + kg * 8];
        const v8s a1h = *(const v8s*)&hprehi[(size_t)nA * H + 32 + kg * 8];
        const v8s a0l = *(const v8s*)&hprelo[(size_t)nA * H + kg * 8];
        const v8s a1l = *(const v8s*)&hprelo[(size_t)nA * H + 32 + kg * 8];
        v4f c[4];
        #pragma unroll
        for (int ct = 0; ct < 4; ++ct) {
            v4f cc = (v4f){0.f, 0.f, 0.f, 0.f};
            cc = __builtin_amdgcn_mfma_f32_16x16x32_bf16(a0h, bhi[0][ct], cc, 0, 0, 0);
            cc = __builtin_amdgcn_mfma_f32_16x16x32_bf16(a1h, bhi[1][ct], cc, 0, 0, 0);
            cc = __builtin_amdgcn_mfma_f32_16x16x32_bf16(a0h, blo[0][ct], cc, 0, 0, 0);
            cc = __builtin_amdgcn_mfma_f32_16x16x32_bf16(a1h, blo[1][ct], cc, 0, 0, 0);
            cc = __builtin_amdgcn_mfma_f32_16x16x32_bf16(a0l, bhi[0][ct], cc, 0, 0, 0);
            cc = __builtin_amdgcn_mfma_f32_16x16x32_bf16(a1l, bhi[1][ct], cc, 0, 0, 0);
            c[ct] = cc;
        }
        #pragma unroll
        for (int ct = 0; ct < 4; ++ct) {
            #pragma unroll
            for (int r = 0; r < 4; ++r) {
                const int node = tb + kg * 4 + r;  // D row
                if (node < N) {
                    const float v = c[ct][r] + bcol[ct];
                    h1[(size_t)node * TWOH + (cb + ct) * 16 + row] = v;
                    sacc[ct] += v;
                    qacc[ct] += v * v;
                }
            }
        }
    }
    #pragma unroll
    for (int ct = 0; ct < 4; ++ct) {
        float s = sacc[ct];
        s += __shfl_xor(s, 16); s += __shfl_xor(s, 32);
        float q = qacc[ct];
        q += __shfl_xor(q, 16); q += __shfl_xor(q, 32);
        if (kg == 0) {
            atomicAdd(&ss[(cb + ct) * 16 + row], s);
            atomicAdd(&sq[(cb + ct) * 16 + row], q);
        }
    }
    __syncthreads();
    if (threadIdx.x < TWOH) {
        atomicAdd(&gsum[threadIdx.x], (double)ss[threadIdx.x]);
        atomicAdd(&gsq[threadIdx.x], (double)sq[threadIdx.x]);
    }
}

// ---------------- BN finalize: scale/shift ----------------
extern "C" __global__ void k_bnfin(const double* __restrict__ gsum,
    const double* __restrict__ gsq, const float* __restrict__ gamma,
    const float* __restrict__ beta, float* __restrict__ scsh, int N)
{
    const int j = threadIdx.x;
    if (j < TWOH) {
        const double mu = gsum[j] / N;
        const double var = gsq[j] / N - mu * mu;
        const float sc = gamma[j] * rsqrtf(fmaxf((float)var, 0.f) + 1e-5f);
        scsh[j] = sc;
        scsh[TWOH + j] = beta[j] - (float)mu * sc;
    }
}

// --- MFMA GEMM2 + fused BN/ReLU + residual: x0 += relu(h1*sc+sh) @ W2 + b2 ---
extern "C" __global__ void __launch_bounds__(256) k_gemm2(
    const float* __restrict__ h1, const float* __restrict__ scsh,
    const bfraw* __restrict__ W2hi, const bfraw* __restrict__ W2lo,
    const float* __restrict__ b2, float* __restrict__ x0,
    bfraw* __restrict__ xb, int N)
{
    __shared__ float scl[TWOH], shl[TWOH];  // 1 KB
    for (int i = threadIdx.x; i < TWOH; i += blockDim.x) {
        scl[i] = scsh[i];
        shl[i] = scsh[TWOH + i];
    }
    __syncthreads();
    const int lane = threadIdx.x & 63;
    const int row = lane & 15;
    const int kg  = lane >> 4;
    const int wpb = blockDim.x >> 6;
    const int wid = blockIdx.x * wpb + (threadIdx.x >> 6);
    const int wstride = gridDim.x * wpb;
    const int half = wid & 1;       // which 32 of the 64 cols
    const int cb = half * 2;        // col-tile base
    // preload B fragments: 4 k-chunks x 2 col-tiles, hi+lo
    v8s bhi[4][2], blo[4][2];
    #pragma unroll
    for (int kc = 0; kc < 4; ++kc)
        #pragma unroll
        for (int ct = 0; ct < 2; ++ct) {
            v8s bh, bl;
            #pragma unroll
            for (int i = 0; i < 8; ++i) {
                const int idx = (kc * 32 + kg * 8 + i) * H + (cb + ct) * 16 + row;
                bh[i] = (short)W2hi[idx];
                bl[i] = (short)W2lo[idx];
            }
            bhi[kc][ct] = bh; blo[kc][ct] = bl;
        }
    float bcol[2];
    #pragma unroll
    for (int ct = 0; ct < 2; ++ct) bcol[ct] = b2[(cb + ct) * 16 + row];
    // per-lane BN constants for this lane's 32 features (8 per k-chunk)
    float lsc[4][8], lsh[4][8];
    #pragma unroll
    for (int kc = 0; kc < 4; ++kc) {
        const int fb = kc * 32 + kg * 8;
        #pragma unroll
        for (int i = 0; i < 8; ++i) { lsc[kc][i] = scl[fb + i]; lsh[kc][i] = shl[fb + i]; }
    }

    const int tiles = (N + 15) >> 4;
    const int tstride = wstride >> 1;

    for (int t = wid >> 1; t < tiles; t += tstride) {
        const int tb = t << 4;
        int nA = tb + row; if (nA >= N) nA = N - 1;
        v8s ah[4], al[4];
        #pragma unroll
        for (int kc = 0; kc < 4; ++kc) {
            const int fb = kc * 32 + kg * 8;
            const float4 h0 = *(const float4*)&h1[(size_t)nA * TWOH + fb];
            const float4 h4 = *(const float4*)&h1[(size_t)nA * TWOH + fb + 4];
            float yv[8] = {h0.x, h0.y, h0.z, h0.w, h4.x, h4.y, h4.z, h4.w};
            v8s vh, vl;
            #pragma unroll
            for (int i = 0; i < 8; ++i) {
                const float y = fmaxf(yv[i] * lsc[kc][i] + lsh[kc][i], 0.f);
                bfraw hi, lo;
                f2bf2(y, hi, lo);
                vh[i] = (short)hi;
                vl[i] = (short)lo;
            }
            ah[kc] = vh; al[kc] = vl;
        }
        v4f c[2];
        #pragma unroll
        for (int ct = 0; ct < 2; ++ct) {
            v4f cc = (v4f){0.f, 0.f, 0.f, 0.f};
            #pragma unroll
            for (int kc = 0; kc < 4; ++kc) {
                cc = __builtin_amdgcn_mfma_f32_16x16x32_bf16(ah[kc], bhi[kc][ct], cc, 0, 0, 0);
                cc = __builtin_amdgcn_mfma_f32_16x16x32_bf16(ah[kc], blo[kc][ct], cc, 0, 0, 0);
                cc = __builtin_amdgcn_mfma_f32_16x16x32_bf16(al[kc], bhi[kc][ct], cc, 0, 0, 0);
            }
            c[ct] = cc;
        }
        #pragma unroll
        for (int ct = 0; ct < 2; ++ct) {
            #pragma unroll
            for (int r = 0; r < 4; ++r) {
                const int node = tb + kg * 4 + r;
                if (node < N) {
                    const size_t idx = (size_t)node * H + (cb + ct) * 16 + row;
                    const float v = x0[idx] + c[ct][r] + bcol[ct];
                    x0[idx] = v;
                    xb[idx] = f2bf(v);
                }
            }
        }
    }
}

// ---------------- pooling + output ----------------
extern "C" __global__ void k_initout(const float* __restrict__ bout,
    float* __restrict__ out)
{
    if (threadIdx.x < NGRAPH) out[threadIdx.x] = bout[0];
}

// segment-sum pooling: batch is SORTED. Each wave owns a contiguous node slab;
// lane l accumulates feature l; flush (reduce+atomic) only at graph boundaries.
extern "C" __global__ void __launch_bounds__(256) k_pool(
    const float* __restrict__ x0, const int* __restrict__ batch,
    const float* __restrict__ Wout, float* __restrict__ out, int N)
{
    const int lane = threadIdx.x & 63;
    const int wpb = blockDim.x >> 6;
    const int gw = blockIdx.x * wpb + (threadIdx.x >> 6);
    const int nw = gridDim.x * wpb;
    const int per = (N + nw - 1) / nw;
    const int n0 = gw * per;
    int n1 = n0 + per; if (n1 > N) n1 = N;
    if (n0 >= N) return;
    const float wv = Wout[lane];
    int cur = batch[n0];
    float acc = 0.f;
    for (int n = n0; n < n1; ++n) {
        const int g = batch[n];
        if (g != cur) {
            float v = acc * wv;
            #pragma unroll
            for (int o = 32; o > 0; o >>= 1) v += __shfl_down(v, o);
            if (lane == 0) atomicAdd(&out[cur], v);
            cur = g;
            acc = 0.f;
        }
        acc += x0[(size_t)n * H + lane];
    }
    float v = acc * wv;
    #pragma unroll
    for (int o = 32; o > 0; o >>= 1) v += __shfl_down(v, o);
    if (lane == 0) atomicAdd(&out[cur], v);
}

// ---------------- host driver ----------------
extern "C" void kernel_launch(void* const* d_in, const int* in_sizes, int n_in,
                              void* d_out, int out_size, void* d_ws, size_t ws_size,
                              hipStream_t stream)
{
    const float* x     = (const float*)d_in[0];
    const int*   ei    = (const int*)d_in[1];   // int32 per harness conversion
    const int*   batch = (const int*)d_in[2];   // int32 per harness conversion
    const float* Win   = (const float*)d_in[3];
    const float* bin   = (const float*)d_in[4];
    const float* W1s   = (const float*)d_in[5];
    const float* b1s   = (const float*)d_in[6];
    const float* gam   = (const float*)d_in[7];
    const float* bet   = (const float*)d_in[8];
    const float* W2s   = (const float*)d_in[9];
    const float* b2s   = (const float*)d_in[10];
    const float* epss  = (const float*)d_in[11];
    const float* Wout  = (const float*)d_in[12];
    const float* bout  = (const float*)d_in[13];

    const int N = in_sizes[0] / CIN;
    const int E = in_sizes[1] / 2;
    const int L = in_sizes[11];
    const int* src = ei;
    const int* dst = ei + E;
    const int NB = (N + BNODE - 1) >> BSH;   // final buckets (<= MAXNB)

    // workspace layout
    char* ws = (char*)d_ws;
    size_t off = 0;
    auto take = [&](size_t bytes) {
        void* p = ws + off;
        off += (bytes + 255) & ~(size_t)255;
        return p;
    };
    float*    x0     = (float*)take((size_t)N * H * 4);
    bfraw*    xb     = (bfraw*)take((size_t)(N + 1) * H * 2);  // +1 zero row
    bfraw*    hprehi = (bfraw*)take((size_t)N * H * 2);
    bfraw*    hprelo = (bfraw*)take((size_t)N * H * 2);
    float*    h1     = (float*)take((size_t)N * TWOH * 4);
    unsigned* deg    = (unsigned*)take((size_t)N * 4);
    unsigned* indptr = (unsigned*)take((size_t)(N + 1) * 4);
    unsigned* cursor = (unsigned*)take((size_t)N * 4);
    int*      esrc   = (int*)take((size_t)(E + 4 * (N + 1)) * 4);  // padded
    unsigned* bsum   = (unsigned*)take(4096);
    double*   gsum   = (double*)take(TWOH * 8 * 2); // gsum + gsq contiguous
    double*   gsq    = gsum + TWOH;
    float*    scsh   = (float*)take(2 * TWOH * 4);
    bfraw*    W1hi   = (bfraw*)take((size_t)L * H * TWOH * 2);
    bfraw*    W1lo   = (bfraw*)take((size_t)L * H * TWOH * 2);
    bfraw*    W2hi   = (bfraw*)take((size_t)L * TWOH * H * 2);
    bfraw*    W2lo   = (bfraw*)take((size_t)L * TWOH * H * 2);
    unsigned* bcnt   = (unsigned*)take((size_t)NBLK_PART * NB * 4);
    unsigned* btmp   = (unsigned*)take((size_t)NBLK_PART * NB * BCAP * 4);
    int*      oflow  = (int*)take((size_t)OCAP * 2 * 4);
    unsigned* ocnt   = (unsigned*)take(256);
    (void)ws_size; (void)n_in; (void)out_size;

    hipMemsetAsync(deg, 0, (size_t)N * 4, stream);
    hipMemsetAsync(ocnt, 0, 4, stream);
    hipMemsetAsync(xb + (size_t)N * H, 0, H * 2, stream);  // sentinel zero row
    k_input_gemm<<<1024, 256, 0, stream>>>(x, Win, bin, x0, xb, N);
    k_cvtw<<<256, 256, 0, stream>>>(W1s, W2s, W1hi, W1lo, W2hi, W2lo, L * H * TWOH);
    k_bucket<<<NBLK_PART, 256, 0, stream>>>(src, dst, bcnt, btmp, deg, oflow, ocnt, E, NB);
    k_bhist<<<NB, 256, 0, stream>>>(bcnt, btmp, deg, N, NB);
    const int nb = (N + 1023) / 1024;
    k_scan1<<<nb, 256, 0, stream>>>(deg, indptr, bsum, N);
    k_scan2<<<1, 64, 0, stream>>>(bsum, nb, indptr, N);
    k_scan3<<<nb, 256, 0, stream>>>(indptr, bsum, cursor, N);
    k_bscat<<<NB, 256, 0, stream>>>(bcnt, btmp, indptr, cursor, esrc, N, NB);
    k_over<<<32, 256, 0, stream>>>(oflow, ocnt, cursor, esrc);
    k_pad<<<512, 256, 0, stream>>>(cursor, indptr, esrc, N);

    for (int l = 0; l < L; ++l) {
        hipMemsetAsync(gsum, 0, TWOH * 8 * 2, stream);
        k_agg<<<4096, 256, 0, stream>>>(x0, xb, esrc, indptr, epss + l,
            hprehi, hprelo, N);
        k_gemm1<<<512, 256, 0, stream>>>(hprehi, hprelo,
            W1hi + (size_t)l * H * TWOH, W1lo + (size_t)l * H * TWOH,
            b1s + (size_t)l * TWOH, h1, gsum, gsq, N);
        k_bnfin<<<1, 128, 0, stream>>>(gsum, gsq, gam + (size_t)l * TWOH,
            bet + (size_t)l * TWOH, scsh, N);
        k_gemm2<<<512, 256, 0, stream>>>(h1, scsh,
            W2hi + (size_t)l * TWOH * H, W2lo + (size_t)l * TWOH * H,
            b2s + (size_t)l * H, x0, xb, N);
    }

    k_initout<<<1, 64, 0, stream>>>(bout, (float*)d_out);
    k_pool<<<512, 256, 0, stream>>>(x0, batch, Wout, (float*)d_out, N);
}

// Round 11
// 532.796 us; speedup vs baseline: 4.4581x; 1.0741x over previous
//
#include <hip/hip_runtime.h>

#define H 64
#define CIN 32
#define TWOH 128
#define NGRAPH 64

// bucketed CSR build
#define BSH 7
#define BNODE 128
#define NBLK_PART 256
#define BCAP 32
#define MAXNB 2048
#define OCAP 65536

typedef unsigned short bfraw;
typedef short v8s __attribute__((ext_vector_type(8)));
typedef float v4f __attribute__((ext_vector_type(4)));

__device__ __forceinline__ float bf2f(bfraw u) {
    return __uint_as_float(((unsigned)u) << 16);
}
__device__ __forceinline__ bfraw f2bf(float f) {
    unsigned u = __float_as_uint(f);
    unsigned r = (u + 0x7fffu + ((u >> 16) & 1u)) >> 16;  // RNE
    return (bfraw)r;
}
// split fp32 -> hi + lo bf16 (combined rel err ~2^-17)
__device__ __forceinline__ void f2bf2(float f, bfraw& hi, bfraw& lo) {
    hi = f2bf(f);
    lo = f2bf(f - bf2f(hi));
}

// ----- MFMA input GEMM: x0[N,64] = x[N,32] @ Win + bin; xb = bf16(relu(x0)) -----
extern "C" __global__ void __launch_bounds__(256) k_input_gemm(
    const float* __restrict__ x, const float* __restrict__ Win,
    const float* __restrict__ bin, float* __restrict__ x0,
    bfraw* __restrict__ xb, int N)
{
    const int lane = threadIdx.x & 63;
    const int row = lane & 15;
    const int kg  = lane >> 4;
    // B fragments: Win[32][64] split hi/lo, 1 k-chunk (K=32), 4 col-tiles
    v8s bhi[4], blo[4];
    #pragma unroll
    for (int ct = 0; ct < 4; ++ct) {
        v8s bh, bl;
        #pragma unroll
        for (int i = 0; i < 8; ++i) {
            const float w = Win[(kg * 8 + i) * H + ct * 16 + row];
            bfraw h, l; f2bf2(w, h, l);
            bh[i] = (short)h; bl[i] = (short)l;
        }
        bhi[ct] = bh; blo[ct] = bl;
    }
    float bcol[4];
    #pragma unroll
    for (int ct = 0; ct < 4; ++ct) bcol[ct] = bin[ct * 16 + row];

    const int wpb = blockDim.x >> 6;
    const int wid = blockIdx.x * wpb + (threadIdx.x >> 6);
    const int wstride = gridDim.x * wpb;
    const int tiles = (N + 15) >> 4;
    for (int t = wid; t < tiles; t += wstride) {
        const int tb = t << 4;
        int nA = tb + row; if (nA >= N) nA = N - 1;
        v8s ah, al;
        #pragma unroll
        for (int i = 0; i < 8; ++i) {
            const float v = x[(size_t)nA * CIN + kg * 8 + i];
            bfraw h, l; f2bf2(v, h, l);
            ah[i] = (short)h; al[i] = (short)l;
        }
        v4f c[4];
        #pragma unroll
        for (int ct = 0; ct < 4; ++ct) {
            v4f cc = (v4f){0.f, 0.f, 0.f, 0.f};
            cc = __builtin_amdgcn_mfma_f32_16x16x32_bf16(ah, bhi[ct], cc, 0, 0, 0);
            cc = __builtin_amdgcn_mfma_f32_16x16x32_bf16(ah, blo[ct], cc, 0, 0, 0);
            cc = __builtin_amdgcn_mfma_f32_16x16x32_bf16(al, bhi[ct], cc, 0, 0, 0);
            c[ct] = cc;
        }
        #pragma unroll
        for (int ct = 0; ct < 4; ++ct) {
            #pragma unroll
            for (int r = 0; r < 4; ++r) {
                const int node = tb + kg * 4 + r;
                if (node < N) {
                    const float v = c[ct][r] + bcol[ct];
                    const size_t idx = (size_t)node * H + ct * 16 + row;
                    x0[idx] = v;
                    xb[idx] = f2bf(fmaxf(v, 0.f));   // relu pre-folded
                }
            }
        }
    }
}

// ---------------- weight conversion to split bf16 (all layers, once) ----------------
extern "C" __global__ void k_cvtw(const float* __restrict__ W1s,
    const float* __restrict__ W2s, bfraw* __restrict__ W1hi,
    bfraw* __restrict__ W1lo, bfraw* __restrict__ W2hi,
    bfraw* __restrict__ W2lo, int total)  // total = L*H*TWOH
{
    int i = blockIdx.x * blockDim.x + threadIdx.x;
    const int st = gridDim.x * blockDim.x;
    for (; i < total; i += st) {
        bfraw h, l;
        f2bf2(W1s[i], h, l); W1hi[i] = h; W1lo[i] = l;
        f2bf2(W2s[i], h, l); W2hi[i] = h; W2lo[i] = l;
    }
}

// ---------------- block-private bucket partition (pass A) ----------------
__device__ __forceinline__ void bput(int s, int d, unsigned* __restrict__ lcnt,
    unsigned* __restrict__ myTmp, unsigned* __restrict__ deg,
    int* __restrict__ oflow, unsigned* __restrict__ ocnt)
{
    const int b = d >> BSH;
    const unsigned pos = atomicAdd(&lcnt[b], 1u);   // LDS atomic
    if (pos < BCAP) {
        myTmp[b * BCAP + pos] = (unsigned)s | ((unsigned)(d & (BNODE - 1)) << 20);
    } else {
        const unsigned o = atomicAdd(ocnt, 1u);
        if (o < OCAP) {
            oflow[2 * o] = s; oflow[2 * o + 1] = d;
            atomicAdd(&deg[d], 1u);
        }
    }
}

extern "C" __global__ void __launch_bounds__(256) k_bucket(
    const int* __restrict__ src, const int* __restrict__ dst,
    unsigned* __restrict__ bcnt, unsigned* __restrict__ btmp,
    unsigned* __restrict__ deg, int* __restrict__ oflow,
    unsigned* __restrict__ ocnt, int E, int NBck)
{
    __shared__ unsigned lcnt[MAXNB];  // 8 KB (NBck <= 2048)
    for (int i = threadIdx.x; i < NBck; i += blockDim.x) lcnt[i] = 0u;
    __syncthreads();
    unsigned* __restrict__ myTmp = btmp + (size_t)blockIdx.x * NBck * BCAP;
    const int tid0 = blockIdx.x * blockDim.x + threadIdx.x;
    const int st = gridDim.x * blockDim.x;
    const int E4 = E >> 2;
    const int4* s4 = (const int4*)src;
    const int4* d4 = (const int4*)dst;
    for (int j = tid0; j < E4; j += st) {
        const int4 sv = s4[j];
        const int4 dv = d4[j];
        bput(sv.x, dv.x, lcnt, myTmp, deg, oflow, ocnt);
        bput(sv.y, dv.y, lcnt, myTmp, deg, oflow, ocnt);
        bput(sv.z, dv.z, lcnt, myTmp, deg, oflow, ocnt);
        bput(sv.w, dv.w, lcnt, myTmp, deg, oflow, ocnt);
    }
    for (int j = (E4 << 2) + tid0; j < E; j += st)
        bput(src[j], dst[j], lcnt, myTmp, deg, oflow, ocnt);
    __syncthreads();
    unsigned* __restrict__ myCnt = bcnt + (size_t)blockIdx.x * NBck;
    for (int i = threadIdx.x; i < NBck; i += blockDim.x) {
        const unsigned c = lcnt[i];
        myCnt[i] = (c < BCAP) ? c : BCAP;
    }
}

// ---------------- per-bucket degree histogram ----------------
extern "C" __global__ void __launch_bounds__(256) k_bhist(
    const unsigned* __restrict__ bcnt, const unsigned* __restrict__ btmp,
    unsigned* __restrict__ deg, int N, int NBck)
{
    __shared__ unsigned hist[BNODE];
    const int b = blockIdx.x;
    for (int i = threadIdx.x; i < BNODE; i += blockDim.x) hist[i] = 0u;
    __syncthreads();
    for (int blk = threadIdx.x; blk < NBLK_PART; blk += blockDim.x) {
        const unsigned cnt = bcnt[(size_t)blk * NBck + b];
        const unsigned* p = btmp + ((size_t)blk * NBck + b) * BCAP;
        for (unsigned j = 0; j < cnt; ++j)
            atomicAdd(&hist[p[j] >> 20], 1u);
    }
    __syncthreads();
    const int base = b << BSH;
    for (int i = threadIdx.x; i < BNODE; i += blockDim.x)
        if (base + i < N) {
            const unsigned h = hist[i];
            if (h) atomicAdd(&deg[base + i], h);
        }
}

extern "C" __global__ void k_scan1(const unsigned* __restrict__ deg,
    unsigned* __restrict__ indptr, unsigned* __restrict__ bsum, int N)
{
    __shared__ unsigned s[256];
    const int tid = threadIdx.x;
    const int base = blockIdx.x * 1024 + tid * 4;
    unsigned d[4];
    #pragma unroll
    for (int j = 0; j < 4; ++j)
        d[j] = (base + j < N) ? ((deg[base + j] + 3u) & ~3u) : 0u;  // padded
    unsigned t = d[0] + d[1] + d[2] + d[3];
    s[tid] = t;
    __syncthreads();
    for (int o = 1; o < 256; o <<= 1) {
        unsigned v = (tid >= o) ? s[tid - o] : 0u;
        __syncthreads();
        s[tid] += v;
        __syncthreads();
    }
    unsigned run = (tid == 0) ? 0u : s[tid - 1];
    if (tid == 255) bsum[blockIdx.x] = s[255];
    #pragma unroll
    for (int j = 0; j < 4; ++j) {
        if (base + j < N) indptr[base + j] = run;
        run += d[j];
    }
}

extern "C" __global__ void k_scan2(unsigned* bsum, int nb,
    unsigned* __restrict__ indptr, int N)
{
    if (threadIdx.x == 0) {
        unsigned run = 0;
        for (int i = 0; i < nb; ++i) { unsigned v = bsum[i]; bsum[i] = run; run += v; }
        indptr[N] = run;  // total padded edges
    }
}

extern "C" __global__ void k_scan3(unsigned* __restrict__ indptr,
    const unsigned* __restrict__ bsum, unsigned* __restrict__ cursor, int N)
{
    const int base = blockIdx.x * 1024 + threadIdx.x * 4;
    const unsigned boff = bsum[blockIdx.x];
    #pragma unroll
    for (int j = 0; j < 4; ++j) {
        const int idx = base + j;
        if (idx < N) {
            const unsigned v = indptr[idx] + boff;
            indptr[idx] = v;
            cursor[idx] = v;
        }
    }
}

// ---------------- per-bucket scatter to final CSR (pass B) ----------------
extern "C" __global__ void __launch_bounds__(256) k_bscat(
    const unsigned* __restrict__ bcnt, const unsigned* __restrict__ btmp,
    const unsigned* __restrict__ indptr, unsigned* __restrict__ cursor,
    int* __restrict__ esrc, int N, int NBck)
{
    __shared__ unsigned lcur[BNODE];
    const int b = blockIdx.x;
    const int base = b << BSH;
    for (int i = threadIdx.x; i < BNODE; i += blockDim.x)
        lcur[i] = (base + i < N) ? indptr[base + i] : 0u;
    __syncthreads();
    for (int blk = threadIdx.x; blk < NBLK_PART; blk += blockDim.x) {
        const unsigned cnt = bcnt[(size_t)blk * NBck + b];
        const unsigned* p = btmp + ((size_t)blk * NBck + b) * BCAP;
        for (unsigned j = 0; j < cnt; ++j) {
            const unsigned e = p[j];
            const unsigned pos = atomicAdd(&lcur[e >> 20], 1u);
            esrc[pos] = (int)(e & 0xFFFFFu);
        }
    }
    __syncthreads();
    for (int i = threadIdx.x; i < BNODE; i += blockDim.x)
        if (base + i < N) cursor[base + i] = lcur[i];
}

// overflow edges (expected none) via global cursor
extern "C" __global__ void k_over(const int* __restrict__ oflow,
    const unsigned* __restrict__ ocnt, unsigned* __restrict__ cursor,
    int* __restrict__ esrc)
{
    unsigned n = *ocnt; if (n > OCAP) n = OCAP;
    int i = blockIdx.x * blockDim.x + threadIdx.x;
    const int st = gridDim.x * blockDim.x;
    for (; (unsigned)i < n; i += st) {
        const int s = oflow[2 * i], d = oflow[2 * i + 1];
        const unsigned pos = atomicAdd(&cursor[d], 1u);
        esrc[pos] = s;
    }
}

// fill padded slots with sentinel N (zero row)
extern "C" __global__ void k_pad(const unsigned* __restrict__ cursor,
    const unsigned* __restrict__ indptr, int* __restrict__ esrc, int N)
{
    int n = blockIdx.x * blockDim.x + threadIdx.x;
    const int st = gridDim.x * blockDim.x;
    for (; n < N; n += st) {
        const unsigned end = indptr[n + 1];
        for (unsigned p = cursor[n]; p < end; ++p) esrc[p] = N;
    }
}

// --- gather: hpre = (1+eps)*x0 + sum xb[src] (xb already relu'd); split bf16 ---
extern "C" __global__ void __launch_bounds__(256) k_agg(
    const float* __restrict__ x0, const bfraw* __restrict__ xb,
    const int* __restrict__ esrc, const unsigned* __restrict__ indptr,
    const float* __restrict__ epsp, bfraw* __restrict__ hprehi,
    bfraw* __restrict__ hprelo, int N)
{
    const int lane = threadIdx.x & 63;
    const int sub = lane >> 4;          // 0..3 : which edge of the group
    const int fi = (lane & 15) << 2;    // feature base (4 features)
    const int wpb = blockDim.x >> 6;
    int w = blockIdx.x * wpb + (threadIdx.x >> 6);
    const int wstride = gridDim.x * wpb;
    const float ep = 1.f + epsp[0];
    for (int n = w; n < N; n += wstride) {
        const unsigned s0 = indptr[n];
        const unsigned s1 = indptr[n + 1];   // padded: (s1-s0)%4==0
        float a0 = 0.f, a1 = 0.f, a2 = 0.f, a3 = 0.f;
        unsigned e = s0;
        for (; e + 16 <= s1; e += 16) {
            const int i0 = esrc[e + sub];
            const int i1 = esrc[e + 4 + sub];
            const int i2 = esrc[e + 8 + sub];
            const int i3 = esrc[e + 12 + sub];
            const ushort4 r0 = *(const ushort4*)&xb[(size_t)i0 * H + fi];
            const ushort4 r1 = *(const ushort4*)&xb[(size_t)i1 * H + fi];
            const ushort4 r2 = *(const ushort4*)&xb[(size_t)i2 * H + fi];
            const ushort4 r3 = *(const ushort4*)&xb[(size_t)i3 * H + fi];
            a0 += bf2f(r0.x) + bf2f(r1.x) + bf2f(r2.x) + bf2f(r3.x);
            a1 += bf2f(r0.y) + bf2f(r1.y) + bf2f(r2.y) + bf2f(r3.y);
            a2 += bf2f(r0.z) + bf2f(r1.z) + bf2f(r2.z) + bf2f(r3.z);
            a3 += bf2f(r0.w) + bf2f(r1.w) + bf2f(r2.w) + bf2f(r3.w);
        }
        for (; e < s1; e += 4) {
            const int i0 = esrc[e + sub];
            const ushort4 r0 = *(const ushort4*)&xb[(size_t)i0 * H + fi];
            a0 += bf2f(r0.x);
            a1 += bf2f(r0.y);
            a2 += bf2f(r0.z);
            a3 += bf2f(r0.w);
        }
        #pragma unroll
        for (int o = 16; o < 64; o <<= 1) {
            a0 += __shfl_xor(a0, o);
            a1 += __shfl_xor(a1, o);
            a2 += __shfl_xor(a2, o);
            a3 += __shfl_xor(a3, o);
        }
        if (sub == 0) {
            const float4 self = *(const float4*)&x0[(size_t)n * H + fi];
            const float h0 = ep * self.x + a0;
            const float h1v = ep * self.y + a1;
            const float h2 = ep * self.z + a2;
            const float h3 = ep * self.w + a3;
            ushort4 ohi, olo;
            f2bf2(h0, ohi.x, olo.x);
            f2bf2(h1v, ohi.y, olo.y);
            f2bf2(h2, ohi.z, olo.z);
            f2bf2(h3, ohi.w, olo.w);
            *(ushort4*)&hprehi[(size_t)n * H + fi] = ohi;
            *(ushort4*)&hprelo[(size_t)n * H + fi] = olo;
        }
    }
}

// ------------- MFMA GEMM1 + BN stats: h1[N,128] = hpre @ W1 + b1 -------------
// split precision: C = Ahi*Whi + Ahi*Wlo + Alo*Whi. Each wave: half the cols.
extern "C" __global__ void __launch_bounds__(256) k_gemm1(
    const bfraw* __restrict__ hprehi, const bfraw* __restrict__ hprelo,
    const bfraw* __restrict__ W1hi, const bfraw* __restrict__ W1lo,
    const float* __restrict__ b1, float* __restrict__ h1,
    double* __restrict__ gsum, double* __restrict__ gsq, int N)
{
    __shared__ float ss[TWOH], sq[TWOH];
    if (threadIdx.x < TWOH) { ss[threadIdx.x] = 0.f; sq[threadIdx.x] = 0.f; }
    __syncthreads();
    const int lane = threadIdx.x & 63;
    const int row = lane & 15;   // A row / B col / D col
    const int kg  = lane >> 4;   // k-group
    const int wpb = blockDim.x >> 6;
    const int wid = blockIdx.x * wpb + (threadIdx.x >> 6);
    const int wstride = gridDim.x * wpb;
    const int half = wid & 1;          // which 64 of the 128 cols
    const int cb = half * 4;           // col-tile base
    // preload B fragments: 2 k-chunks x 4 col-tiles, hi+lo
    v8s bhi[2][4], blo[2][4];
    #pragma unroll
    for (int kc = 0; kc < 2; ++kc)
        #pragma unroll
        for (int ct = 0; ct < 4; ++ct) {
            v8s bh, bl;
            #pragma unroll
            for (int i = 0; i < 8; ++i) {
                const int idx = (kc * 32 + kg * 8 + i) * TWOH + (cb + ct) * 16 + row;
                bh[i] = (short)W1hi[idx];
                bl[i] = (short)W1lo[idx];
            }
            bhi[kc][ct] = bh; blo[kc][ct] = bl;
        }
    float bcol[4];
    #pragma unroll
    for (int ct = 0; ct < 4; ++ct) bcol[ct] = b1[(cb + ct) * 16 + row];

    const int tiles = (N + 15) >> 4;
    const int tstride = wstride >> 1;
    float sacc[4], qacc[4];
    #pragma unroll
    for (int ct = 0; ct < 4; ++ct) { sacc[ct] = 0.f; qacc[ct] = 0.f; }

    for (int t = wid >> 1; t < tiles; t += tstride) {
        const int tb = t << 4;
        int nA = tb + row; if (nA >= N) nA = N - 1;
        const v8s a0h = *(const v8s*)&hprehi[(size_t)nA * H + kg * 8];
        const v8s a1h = *(const v8s*)&hprehi[(size_t)nA * H + 32 + kg * 8];
        const v8s a0l = *(const v8s*)&hprelo[(size_t)nA * H + kg * 8];
        const v8s a1l = *(const v8s*)&hprelo[(size_t)nA * H + 32 + kg * 8];
        v4f c[4];
        #pragma unroll
        for (int ct = 0; ct < 4; ++ct) {
            v4f cc = (v4f){0.f, 0.f, 0.f, 0.f};
            cc = __builtin_amdgcn_mfma_f32_16x16x32_bf16(a0h, bhi[0][ct], cc, 0, 0, 0);
            cc = __builtin_amdgcn_mfma_f32_16x16x32_bf16(a1h, bhi[1][ct], cc, 0, 0, 0);
            cc = __builtin_amdgcn_mfma_f32_16x16x32_bf16(a0h, blo[0][ct], cc, 0, 0, 0);
            cc = __builtin_amdgcn_mfma_f32_16x16x32_bf16(a1h, blo[1][ct], cc, 0, 0, 0);
            cc = __builtin_amdgcn_mfma_f32_16x16x32_bf16(a0l, bhi[0][ct], cc, 0, 0, 0);
            cc = __builtin_amdgcn_mfma_f32_16x16x32_bf16(a1l, bhi[1][ct], cc, 0, 0, 0);
            c[ct] = cc;
        }
        #pragma unroll
        for (int ct = 0; ct < 4; ++ct) {
            #pragma unroll
            for (int r = 0; r < 4; ++r) {
                const int node = tb + kg * 4 + r;  // D row
                if (node < N) {
                    const float v = c[ct][r] + bcol[ct];
                    h1[(size_t)node * TWOH + (cb + ct) * 16 + row] = v;
                    sacc[ct] += v;
                    qacc[ct] += v * v;
                }
            }
        }
    }
    #pragma unroll
    for (int ct = 0; ct < 4; ++ct) {
        float s = sacc[ct];
        s += __shfl_xor(s, 16); s += __shfl_xor(s, 32);
        float q = qacc[ct];
        q += __shfl_xor(q, 16); q += __shfl_xor(q, 32);
        if (kg == 0) {
            atomicAdd(&ss[(cb + ct) * 16 + row], s);
            atomicAdd(&sq[(cb + ct) * 16 + row], q);
        }
    }
    __syncthreads();
    if (threadIdx.x < TWOH) {
        atomicAdd(&gsum[threadIdx.x], (double)ss[threadIdx.x]);
        atomicAdd(&gsq[threadIdx.x], (double)sq[threadIdx.x]);
    }
}

// ---------------- BN finalize: scale/shift ----------------
extern "C" __global__ void k_bnfin(const double* __restrict__ gsum,
    const double* __restrict__ gsq, const float* __restrict__ gamma,
    const float* __restrict__ beta, float* __restrict__ scsh, int N)
{
    const int j = threadIdx.x;
    if (j < TWOH) {
        const double mu = gsum[j] / N;
        const double var = gsq[j] / N - mu * mu;
        const float sc = gamma[j] * rsqrtf(fmaxf((float)var, 0.f) + 1e-5f);
        scsh[j] = sc;
        scsh[TWOH + j] = beta[j] - (float)mu * sc;
    }
}

// --- MFMA GEMM2 + fused BN/ReLU + residual: x0 += relu(h1*sc+sh) @ W2 + b2 ---
extern "C" __global__ void __launch_bounds__(256) k_gemm2(
    const float* __restrict__ h1, const float* __restrict__ scsh,
    const bfraw* __restrict__ W2hi, const bfraw* __restrict__ W2lo,
    const float* __restrict__ b2, float* __restrict__ x0,
    bfraw* __restrict__ xb, int N)
{
    __shared__ float scl[TWOH], shl[TWOH];  // 1 KB
    for (int i = threadIdx.x; i < TWOH; i += blockDim.x) {
        scl[i] = scsh[i];
        shl[i] = scsh[TWOH + i];
    }
    __syncthreads();
    const int lane = threadIdx.x & 63;
    const int row = lane & 15;
    const int kg  = lane >> 4;
    const int wpb = blockDim.x >> 6;
    const int wid = blockIdx.x * wpb + (threadIdx.x >> 6);
    const int wstride = gridDim.x * wpb;
    const int half = wid & 1;       // which 32 of the 64 cols
    const int cb = half * 2;        // col-tile base
    // preload B fragments: 4 k-chunks x 2 col-tiles, hi+lo
    v8s bhi[4][2], blo[4][2];
    #pragma unroll
    for (int kc = 0; kc < 4; ++kc)
        #pragma unroll
        for (int ct = 0; ct < 2; ++ct) {
            v8s bh, bl;
            #pragma unroll
            for (int i = 0; i < 8; ++i) {
                const int idx = (kc * 32 + kg * 8 + i) * H + (cb + ct) * 16 + row;
                bh[i] = (short)W2hi[idx];
                bl[i] = (short)W2lo[idx];
            }
            bhi[kc][ct] = bh; blo[kc][ct] = bl;
        }
    float bcol[2];
    #pragma unroll
    for (int ct = 0; ct < 2; ++ct) bcol[ct] = b2[(cb + ct) * 16 + row];
    // per-lane BN constants for this lane's 32 features (8 per k-chunk)
    float lsc[4][8], lsh[4][8];
    #pragma unroll
    for (int kc = 0; kc < 4; ++kc) {
        const int fb = kc * 32 + kg * 8;
        #pragma unroll
        for (int i = 0; i < 8; ++i) { lsc[kc][i] = scl[fb + i]; lsh[kc][i] = shl[fb + i]; }
    }

    const int tiles = (N + 15) >> 4;
    const int tstride = wstride >> 1;

    for (int t = wid >> 1; t < tiles; t += tstride) {
        const int tb = t << 4;
        int nA = tb + row; if (nA >= N) nA = N - 1;
        v8s ah[4], al[4];
        #pragma unroll
        for (int kc = 0; kc < 4; ++kc) {
            const int fb = kc * 32 + kg * 8;
            const float4 h0 = *(const float4*)&h1[(size_t)nA * TWOH + fb];
            const float4 h4 = *(const float4*)&h1[(size_t)nA * TWOH + fb + 4];
            float yv[8] = {h0.x, h0.y, h0.z, h0.w, h4.x, h4.y, h4.z, h4.w};
            v8s vh, vl;
            #pragma unroll
            for (int i = 0; i < 8; ++i) {
                const float y = fmaxf(yv[i] * lsc[kc][i] + lsh[kc][i], 0.f);
                bfraw hi, lo;
                f2bf2(y, hi, lo);
                vh[i] = (short)hi;
                vl[i] = (short)lo;
            }
            ah[kc] = vh; al[kc] = vl;
        }
        v4f c[2];
        #pragma unroll
        for (int ct = 0; ct < 2; ++ct) {
            v4f cc = (v4f){0.f, 0.f, 0.f, 0.f};
            #pragma unroll
            for (int kc = 0; kc < 4; ++kc) {
                cc = __builtin_amdgcn_mfma_f32_16x16x32_bf16(ah[kc], bhi[kc][ct], cc, 0, 0, 0);
                cc = __builtin_amdgcn_mfma_f32_16x16x32_bf16(ah[kc], blo[kc][ct], cc, 0, 0, 0);
                cc = __builtin_amdgcn_mfma_f32_16x16x32_bf16(al[kc], bhi[kc][ct], cc, 0, 0, 0);
            }
            c[ct] = cc;
        }
        #pragma unroll
        for (int ct = 0; ct < 2; ++ct) {
            #pragma unroll
            for (int r = 0; r < 4; ++r) {
                const int node = tb + kg * 4 + r;
                if (node < N) {
                    const size_t idx = (size_t)node * H + (cb + ct) * 16 + row;
                    const float v = x0[idx] + c[ct][r] + bcol[ct];
                    x0[idx] = v;
                    xb[idx] = f2bf(fmaxf(v, 0.f));   // relu pre-folded
                }
            }
        }
    }
}

// ---------------- pooling + output ----------------
extern "C" __global__ void k_initout(const float* __restrict__ bout,
    float* __restrict__ out)
{
    if (threadIdx.x < NGRAPH) out[threadIdx.x] = bout[0];
}

// segment-sum pooling: batch is SORTED. Each wave owns a contiguous node slab;
// lane l accumulates feature l; flush (reduce+atomic) only at graph boundaries.
extern "C" __global__ void __launch_bounds__(256) k_pool(
    const float* __restrict__ x0, const int* __restrict__ batch,
    const float* __restrict__ Wout, float* __restrict__ out, int N)
{
    const int lane = threadIdx.x & 63;
    const int wpb = blockDim.x >> 6;
    const int gw = blockIdx.x * wpb + (threadIdx.x >> 6);
    const int nw = gridDim.x * wpb;
    const int per = (N + nw - 1) / nw;
    const int n0 = gw * per;
    int n1 = n0 + per; if (n1 > N) n1 = N;
    if (n0 >= N) return;
    const float wv = Wout[lane];
    int cur = batch[n0];
    float acc = 0.f;
    for (int n = n0; n < n1; ++n) {
        const int g = batch[n];
        if (g != cur) {
            float v = acc * wv;
            #pragma unroll
            for (int o = 32; o > 0; o >>= 1) v += __shfl_down(v, o);
            if (lane == 0) atomicAdd(&out[cur], v);
            cur = g;
            acc = 0.f;
        }
        acc += x0[(size_t)n * H + lane];
    }
    float v = acc * wv;
    #pragma unroll
    for (int o = 32; o > 0; o >>= 1) v += __shfl_down(v, o);
    if (lane == 0) atomicAdd(&out[cur], v);
}

// ---------------- host driver ----------------
extern "C" void kernel_launch(void* const* d_in, const int* in_sizes, int n_in,
                              void* d_out, int out_size, void* d_ws, size_t ws_size,
                              hipStream_t stream)
{
    const float* x     = (const float*)d_in[0];
    const int*   ei    = (const int*)d_in[1];   // int32 per harness conversion
    const int*   batch = (const int*)d_in[2];   // int32 per harness conversion
    const float* Win   = (const float*)d_in[3];
    const float* bin   = (const float*)d_in[4];
    const float* W1s   = (const float*)d_in[5];
    const float* b1s   = (const float*)d_in[6];
    const float* gam   = (const float*)d_in[7];
    const float* bet   = (const float*)d_in[8];
    const float* W2s   = (const float*)d_in[9];
    const float* b2s   = (const float*)d_in[10];
    const float* epss  = (const float*)d_in[11];
    const float* Wout  = (const float*)d_in[12];
    const float* bout  = (const float*)d_in[13];

    const int N = in_sizes[0] / CIN;
    const int E = in_sizes[1] / 2;
    const int L = in_sizes[11];
    const int* src = ei;
    const int* dst = ei + E;
    const int NB = (N + BNODE - 1) >> BSH;   // final buckets (<= MAXNB)

    // workspace layout
    char* ws = (char*)d_ws;
    size_t off = 0;
    auto take = [&](size_t bytes) {
        void* p = ws + off;
        off += (bytes + 255) & ~(size_t)255;
        return p;
    };
    float*    x0     = (float*)take((size_t)N * H * 4);
    bfraw*    xb     = (bfraw*)take((size_t)(N + 1) * H * 2);  // +1 zero row
    bfraw*    hprehi = (bfraw*)take((size_t)N * H * 2);
    bfraw*    hprelo = (bfraw*)take((size_t)N * H * 2);
    float*    h1     = (float*)take((size_t)N * TWOH * 4);
    unsigned* deg    = (unsigned*)take((size_t)N * 4);
    unsigned* indptr = (unsigned*)take((size_t)(N + 1) * 4);
    unsigned* cursor = (unsigned*)take((size_t)N * 4);
    int*      esrc   = (int*)take((size_t)(E + 4 * (N + 1)) * 4);  // padded
    unsigned* bsum   = (unsigned*)take(4096);
    double*   gsum   = (double*)take(TWOH * 8 * 2); // gsum + gsq contiguous
    double*   gsq    = gsum + TWOH;
    float*    scsh   = (float*)take(2 * TWOH * 4);
    bfraw*    W1hi   = (bfraw*)take((size_t)L * H * TWOH * 2);
    bfraw*    W1lo   = (bfraw*)take((size_t)L * H * TWOH * 2);
    bfraw*    W2hi   = (bfraw*)take((size_t)L * TWOH * H * 2);
    bfraw*    W2lo   = (bfraw*)take((size_t)L * TWOH * H * 2);
    unsigned* bcnt   = (unsigned*)take((size_t)NBLK_PART * NB * 4);
    unsigned* btmp   = (unsigned*)take((size_t)NBLK_PART * NB * BCAP * 4);
    int*      oflow  = (int*)take((size_t)OCAP * 2 * 4);
    unsigned* ocnt   = (unsigned*)take(256);
    (void)ws_size; (void)n_in; (void)out_size;

    hipMemsetAsync(deg, 0, (size_t)N * 4, stream);
    hipMemsetAsync(ocnt, 0, 4, stream);
    hipMemsetAsync(xb + (size_t)N * H, 0, H * 2, stream);  // sentinel zero row
    k_input_gemm<<<512, 256, 0, stream>>>(x, Win, bin, x0, xb, N);
    k_cvtw<<<256, 256, 0, stream>>>(W1s, W2s, W1hi, W1lo, W2hi, W2lo, L * H * TWOH);
    k_bucket<<<NBLK_PART, 256, 0, stream>>>(src, dst, bcnt, btmp, deg, oflow, ocnt, E, NB);
    k_bhist<<<NB, 256, 0, stream>>>(bcnt, btmp, deg, N, NB);
    const int nb = (N + 1023) / 1024;
    k_scan1<<<nb, 256, 0, stream>>>(deg, indptr, bsum, N);
    k_scan2<<<1, 64, 0, stream>>>(bsum, nb, indptr, N);
    k_scan3<<<nb, 256, 0, stream>>>(indptr, bsum, cursor, N);
    k_bscat<<<NB, 256, 0, stream>>>(bcnt, btmp, indptr, cursor, esrc, N, NB);
    k_over<<<32, 256, 0, stream>>>(oflow, ocnt, cursor, esrc);
    k_pad<<<512, 256, 0, stream>>>(cursor, indptr, esrc, N);

    for (int l = 0; l < L; ++l) {
        hipMemsetAsync(gsum, 0, TWOH * 8 * 2, stream);
        k_agg<<<4096, 256, 0, stream>>>(x0, xb, esrc, indptr, epss + l,
            hprehi, hprelo, N);
        k_gemm1<<<512, 256, 0, stream>>>(hprehi, hprelo,
            W1hi + (size_t)l * H * TWOH, W1lo + (size_t)l * H * TWOH,
            b1s + (size_t)l * TWOH, h1, gsum, gsq, N);
        k_bnfin<<<1, 128, 0, stream>>>(gsum, gsq, gam + (size_t)l * TWOH,
            bet + (size_t)l * TWOH, scsh, N);
        k_gemm2<<<512, 256, 0, stream>>>(h1, scsh,
            W2hi + (size_t)l * TWOH * H, W2lo + (size_t)l * TWOH * H,
            b2s + (size_t)l * H, x0, xb, N);
    }

    k_initout<<<1, 64, 0, stream>>>(bout, (float*)d_out);
    k_pool<<<512, 256, 0, stream>>>(x0, batch, Wout, (float*)d_out, N);
}